// Round 1
// baseline (2091.971 us; speedup 1.0000x reference)
//
#include <hip/hip_runtime.h>
#include <cstdint>

#define NB 8
#define NN 3072
#define HD 64
#define KK 16
#define NL 2

typedef unsigned long long u64;

__device__ __forceinline__ float elu_f(float x) { return x > 0.0f ? x : expm1f(x); }

__device__ __forceinline__ unsigned sortkey(float f) {
  unsigned u = __float_as_uint(f);
  unsigned m = ((unsigned)((int)u >> 31)) | 0x80000000u;
  return u ^ m;  // monotone float->uint map (handles tiny negative d2 from rounding)
}

__device__ __forceinline__ u64 shfl64(u64 v, int src) {
  int lo = __shfl((int)(unsigned)v, src, 64);
  int hi = __shfl((int)(unsigned)(v >> 32), src, 64);
  return ((u64)(unsigned)hi << 32) | (unsigned)lo;
}
__device__ __forceinline__ u64 shfl_xor64(u64 v, int mask) {
  int lo = __shfl_xor((int)(unsigned)v, mask, 64);
  int hi = __shfl_xor((int)(unsigned)(v >> 32), mask, 64);
  return ((u64)(unsigned)hi << 32) | (unsigned)lo;
}

// ---------------- embed: h = elu(x*datanorm @ W_in + b_in) ----------------
__global__ void k_embed(const float* __restrict__ x, const float* __restrict__ dn,
                        const float* __restrict__ Win, const float* __restrict__ bin,
                        float* __restrict__ h) {
  const int t = threadIdx.x;
  const int row = blockIdx.x * 4 + (t >> 6);
  const int d = t & 63;
  const float* xr = x + (size_t)row * 3;
  float a = bin[d];
#pragma unroll
  for (int c = 0; c < 3; ++c) a = fmaf(xr[c] * dn[c], Win[c * HD + d], a);
  h[(size_t)row * HD + d] = elu_f(a);
}

// ---------------- row squared norms ----------------
__global__ void k_norms(const float* __restrict__ h, float* __restrict__ xx) {
  const int t = threadIdx.x;
  const int row = blockIdx.x * 4 + (t >> 6);
  const int lane = t & 63;
  float v = h[(size_t)row * HD + lane];
  float s = v * v;
#pragma unroll
  for (int m = 32; m >= 1; m >>= 1) s += __shfl_xor(s, m, 64);
  if (lane == 0) xx[row] = s;
}

// ---------------- exact KNN (top-16 smallest d2, tie -> lower index) ----------------
// 1 wave per query row i; 16 rows/block; j-tiles (64x64 f32) double-buffered in LDS
// with XOR swizzle so per-lane float4 row reads spread uniformly over banks.
__global__ __launch_bounds__(1024, 4) void k_knn(const float* __restrict__ h,
                                                 const float* __restrict__ xx,
                                                 int* __restrict__ knn) {
  __shared__ float tile[2 * 64 * 64];  // 32 KB
  const int t = threadIdx.x;
  const int w = t >> 6, lane = t & 63;
  const int b = blockIdx.x / (NN / 16);
  const int i = (blockIdx.x % (NN / 16)) * 16 + w;
  const float* hb = h + (size_t)b * NN * HD;

  float4 hi[16];
  {
    const float4* hrow = (const float4*)(hb + (size_t)i * HD);
#pragma unroll
    for (int g = 0; g < 16; ++g) hi[g] = hrow[g];
  }
  const float xxi = xx[b * NN + i];

  u64 key = ~0ull;       // lanes 0..15 will hold the running top-16
  u64 kth = ~0ull;       // wave-uniform: current worst of the 16
  int maxlane = 0;       // wave-uniform: lane holding kth

  const int lr = t >> 4, lg = t & 15;  // loader: row 0..63, group 0..15
  const int NT = NN / 64;

  // prime buffer 0
  {
    float4 v = *(const float4*)(hb + (size_t)lr * HD + lg * 4);
    *(float4*)&tile[lr * 64 + ((lg ^ (lr & 15)) << 2)] = v;
  }
  for (int jt = 0; jt < NT; ++jt) {
    float4 nxt;
    if (jt + 1 < NT)
      nxt = *(const float4*)(hb + (size_t)((jt + 1) * 64 + lr) * HD + lg * 4);
    __syncthreads();  // one barrier per tile: prev stores visible, bufs disjoint
    const float* tb = tile + (jt & 1) * 4096;
    const int sw = lane & 15;
    float dot = 0.f;
#pragma unroll
    for (int g = 0; g < 16; ++g) {
      const float4 vj = *(const float4*)&tb[lane * 64 + ((g ^ sw) << 2)];
      dot = fmaf(hi[g].x, vj.x, dot);
      dot = fmaf(hi[g].y, vj.y, dot);
      dot = fmaf(hi[g].z, vj.z, dot);
      dot = fmaf(hi[g].w, vj.w, dot);
    }
    const int j = jt * 64 + lane;
    const float d2 = (xxi + xx[b * NN + j]) - 2.0f * dot;  // same formula as reference
    const u64 ck = ((u64)sortkey(d2) << 32) | (unsigned)j;
    u64 qual = __ballot(ck < kth);
    while (qual) {
      const int s = __builtin_ctzll(qual);
      qual &= qual - 1;
      const u64 c = shfl64(ck, s);
      if (c < kth) {  // re-check: kth shrinks as we insert
        if (lane == maxlane) key = c;
        u64 r = key;
#pragma unroll
        for (int m = 1; m < 16; m <<= 1) {
          const u64 o = shfl_xor64(r, m);
          r = (o > r) ? o : r;
        }
        kth = shfl64(r, 0);  // group-0 (lanes 0..15) max, broadcast to wave
        maxlane = (int)__builtin_ctzll(__ballot(key == kth));
      }
    }
    if (jt + 1 < NT)
      *(float4*)&tile[((jt + 1) & 1) * 4096 + lr * 64 + ((lg ^ (lr & 15)) << 2)] = nxt;
  }
  if (lane < 16) knn[((size_t)b * NN + i) * KK + lane] = (int)(unsigned)(key & 0xffffffffu);
}

// ---------------- edge MLP + aggregation for 4 points (64 edges) per block -------
// msg = [x_i | x_j - x_i]; split GEMM1: base1 = x_i@W1[:64]+b1 (per point),
// then per-edge diff @ W1[64:]. m1=elu(.); m2=elu(m1@W2+b2); h_out = sum_k m2.
__global__ __launch_bounds__(256, 3) void k_msg(const float* __restrict__ h,
                                                const int* __restrict__ knn,
                                                const float* __restrict__ W1,
                                                const float* __restrict__ b1,
                                                const float* __restrict__ W2,
                                                const float* __restrict__ b2,
                                                float* __restrict__ hout) {
  __shared__ float base1[4 * 128];   // 2 KB
  __shared__ float msgT[64 * 64];    // 16 KB (diff part, [c][e]); reused as `red`
  __shared__ float m1s[64 * 128];    // 32 KB, column-group XOR swizzled
  const int t = threadIdx.x;
  const int b = blockIdx.x / (NN / 4);
  const int p0 = (blockIdx.x % (NN / 4)) * 4;
  const float* hb = h + (size_t)b * NN * HD;

  // stage 0: base1[lp][o] = b1[o] + sum_c h[p][c]*W1[c][o]
  {
    const int o = t & 127, lp2 = t >> 7;
#pragma unroll
    for (int rep = 0; rep < 2; ++rep) {
      const int lp = lp2 * 2 + rep;
      const float* hp = hb + (size_t)(p0 + lp) * HD;
      float a = b1[o];
      for (int c = 0; c < 64; ++c) a = fmaf(hp[c], W1[c * 128 + o], a);
      base1[lp * 128 + o] = a;
    }
  }
  // stage 0b: msgT[c][e] = h_j[c] - h_i[c]
  {
    const int e = t >> 2, cq = t & 3;
    const int lp = e >> 4, kk = e & 15;
    const int p = p0 + lp;
    const int j = knn[((size_t)b * NN + p) * KK + kk];
    const float* hp = hb + (size_t)p * HD;
    const float* hj = hb + (size_t)j * HD;
#pragma unroll
    for (int q = 0; q < 4; ++q) {
      const int c = cq * 16 + q * 4;
      const float4 vi = *(const float4*)(hp + c);
      const float4 vj = *(const float4*)(hj + c);
      msgT[(c + 0) * 64 + e] = vj.x - vi.x;
      msgT[(c + 1) * 64 + e] = vj.y - vi.y;
      msgT[(c + 2) * 64 + e] = vj.z - vi.z;
      msgT[(c + 3) * 64 + e] = vj.w - vi.w;
    }
  }
  __syncthreads();
  // GEMM1: 64x128 += msgT^T(64x64) @ W1[64:](64x128); thread tile 4e x 8o
  {
    const int o0 = (t & 15) * 8;
    const int e0 = (t >> 4) * 4;
    const int lp = e0 >> 4;
    float acc[4][8];
#pragma unroll
    for (int ee = 0; ee < 4; ++ee)
#pragma unroll
      for (int oo = 0; oo < 8; ++oo) acc[ee][oo] = base1[lp * 128 + o0 + oo];
    for (int c = 0; c < 64; ++c) {
      const float4 am = *(const float4*)&msgT[c * 64 + e0];
      const float4 w0 = *(const float4*)(W1 + (size_t)(64 + c) * 128 + o0);
      const float4 w1 = *(const float4*)(W1 + (size_t)(64 + c) * 128 + o0 + 4);
      const float av[4] = {am.x, am.y, am.z, am.w};
      const float wv[8] = {w0.x, w0.y, w0.z, w0.w, w1.x, w1.y, w1.z, w1.w};
#pragma unroll
      for (int ee = 0; ee < 4; ++ee)
#pragma unroll
        for (int oo = 0; oo < 8; ++oo) acc[ee][oo] = fmaf(av[ee], wv[oo], acc[ee][oo]);
    }
#pragma unroll
    for (int ee = 0; ee < 4; ++ee) {
      const int e = e0 + ee;
      const int sw = e & 15;
      float4 v0, v1;
      v0.x = elu_f(acc[ee][0]); v0.y = elu_f(acc[ee][1]);
      v0.z = elu_f(acc[ee][2]); v0.w = elu_f(acc[ee][3]);
      v1.x = elu_f(acc[ee][4]); v1.y = elu_f(acc[ee][5]);
      v1.z = elu_f(acc[ee][6]); v1.w = elu_f(acc[ee][7]);
      *(float4*)&m1s[e * 128 + (((o0 >> 2) ^ sw) << 2)] = v0;
      *(float4*)&m1s[e * 128 + ((((o0 + 4) >> 2) ^ sw) << 2)] = v1;
    }
  }
  __syncthreads();
  // GEMM2: 64x64 = m1(64x128) @ W2(128x64); thread tile 4e x 4o; fused elu+k-sum
  {
    const int o0 = (t & 15) * 4;
    const int e0 = (t >> 4) * 4;
    float acc2[4][4];
#pragma unroll
    for (int ee = 0; ee < 4; ++ee) {
      acc2[ee][0] = b2[o0 + 0]; acc2[ee][1] = b2[o0 + 1];
      acc2[ee][2] = b2[o0 + 2]; acc2[ee][3] = b2[o0 + 3];
    }
    for (int c = 0; c < 128; ++c) {
      const float4 wv = *(const float4*)(W2 + (size_t)c * 64 + o0);
#pragma unroll
      for (int ee = 0; ee < 4; ++ee) {
        const int e = e0 + ee;
        const float a = m1s[e * 128 + (((c >> 2) ^ (e & 15)) << 2) + (c & 3)];
        acc2[ee][0] = fmaf(a, wv.x, acc2[ee][0]);
        acc2[ee][1] = fmaf(a, wv.y, acc2[ee][1]);
        acc2[ee][2] = fmaf(a, wv.z, acc2[ee][2]);
        acc2[ee][3] = fmaf(a, wv.w, acc2[ee][3]);
      }
    }
    float* red = msgT;  // msgT no longer read after the GEMM1 barrier
    float4 s;
    s.x = elu_f(acc2[0][0]) + elu_f(acc2[1][0]) + elu_f(acc2[2][0]) + elu_f(acc2[3][0]);
    s.y = elu_f(acc2[0][1]) + elu_f(acc2[1][1]) + elu_f(acc2[2][1]) + elu_f(acc2[3][1]);
    s.z = elu_f(acc2[0][2]) + elu_f(acc2[1][2]) + elu_f(acc2[2][2]) + elu_f(acc2[3][2]);
    s.w = elu_f(acc2[0][3]) + elu_f(acc2[1][3]) + elu_f(acc2[2][3]) + elu_f(acc2[3][3]);
    const int g = t >> 4;  // e-group 0..15
    *(float4*)&red[g * 72 + o0] = s;
  }
  __syncthreads();
  {
    const float* red = msgT;
    const int lp = t >> 6, o = t & 63;
    const float v = red[(lp * 4 + 0) * 72 + o] + red[(lp * 4 + 1) * 72 + o] +
                    red[(lp * 4 + 2) * 72 + o] + red[(lp * 4 + 3) * 72 + o];
    hout[((size_t)b * NN + p0 + lp) * HD + o] = v;
  }
}

// ---------------- max-pool + head MLP, one block per batch ----------------
__global__ void k_head(const float* __restrict__ h, const float* __restrict__ Wo1,
                       const float* __restrict__ bo1, const float* __restrict__ Wo2,
                       const float* __restrict__ bo2, const float* __restrict__ Wo3,
                       const float* __restrict__ bo3, float* __restrict__ out) {
  __shared__ float pool4[4 * 64];
  __shared__ float pooled[64];
  __shared__ float o1[64];
  __shared__ float o2s[64];
  const int t = threadIdx.x;
  const int b = blockIdx.x;
  const int q = t >> 6, d = t & 63;
  const float* hb = h + (size_t)b * NN * HD;
  float m = -3.402823466e+38f;
  for (int n = q; n < NN; n += 4) m = fmaxf(m, hb[(size_t)n * HD + d]);
  pool4[q * 64 + d] = m;
  __syncthreads();
  if (t < 64) {
    pooled[t] = fmaxf(fmaxf(pool4[t], pool4[64 + t]),
                      fmaxf(pool4[128 + t], pool4[192 + t]));
  }
  __syncthreads();
  if (t < 64) {
    float a = bo1[t];
    for (int c = 0; c < 64; ++c) a = fmaf(pooled[c], Wo1[c * 64 + t], a);
    o1[t] = elu_f(a);
  }
  __syncthreads();
  if (t < 64) {
    float a = bo2[t];
    for (int c = 0; c < 64; ++c) a = fmaf(o1[c], Wo2[c * 64 + t], a);
    o2s[t] = elu_f(a);
  }
  __syncthreads();
  if (t < 64) {
    float v = o2s[t] * Wo3[t];
#pragma unroll
    for (int mm = 32; mm >= 1; mm >>= 1) v += __shfl_xor(v, mm, 64);
    if (t == 0) out[b] = v + bo3[0];
  }
}

extern "C" void kernel_launch(void* const* d_in, const int* in_sizes, int n_in,
                              void* d_out, int out_size, void* d_ws, size_t ws_size,
                              hipStream_t stream) {
  const float* x   = (const float*)d_in[0];
  const float* dn  = (const float*)d_in[1];
  const float* Win = (const float*)d_in[2];
  const float* bin = (const float*)d_in[3];
  const float* W1  = (const float*)d_in[4];
  const float* b1  = (const float*)d_in[5];
  const float* W2  = (const float*)d_in[6];
  const float* b2  = (const float*)d_in[7];
  const float* Wo1 = (const float*)d_in[8];
  const float* bo1 = (const float*)d_in[9];
  const float* Wo2 = (const float*)d_in[10];
  const float* bo2 = (const float*)d_in[11];
  const float* Wo3 = (const float*)d_in[12];
  const float* bo3 = (const float*)d_in[13];
  float* out = (float*)d_out;

  char* ws = (char*)d_ws;
  const size_t hbytes = (size_t)NB * NN * HD * 4;  // 6291456
  float* h0 = (float*)ws;
  float* h1 = (float*)(ws + hbytes);
  float* xx = (float*)(ws + 2 * hbytes);
  int* knn  = (int*)(ws + 2 * hbytes + (size_t)NB * NN * 4);
  // total ws use ~14.3 MB

  const int rows = NB * NN;
  k_embed<<<rows / 4, 256, 0, stream>>>(x, dn, Win, bin, h0);
  float* hin = h0;
  float* hbuf = h1;
  for (int l = 0; l < NL; ++l) {
    k_norms<<<rows / 4, 256, 0, stream>>>(hin, xx);
    k_knn<<<rows / 16, 1024, 0, stream>>>(hin, xx, knn);
    k_msg<<<rows / 4, 256, 0, stream>>>(hin, knn, W1 + (size_t)l * 128 * 128,
                                        b1 + l * 128, W2 + (size_t)l * 128 * 64,
                                        b2 + l * 64, hbuf);
    float* tmp = hin; hin = hbuf; hbuf = tmp;
  }
  k_head<<<NB, 256, 0, stream>>>(hin, Wo1, bo1, Wo2, bo2, Wo3, bo3, out);
}

// Round 2
// 1752.268 us; speedup vs baseline: 1.1939x; 1.1939x over previous
//
#include <hip/hip_runtime.h>
#include <cstdint>

#define NB 8
#define NN 3072
#define HD 64
#define KK 16
#define NL 2

typedef unsigned long long u64;
typedef __attribute__((ext_vector_type(8))) short short8;
typedef __attribute__((ext_vector_type(4))) float f32x4;

__device__ __forceinline__ float elu_f(float x) { return x > 0.0f ? x : expm1f(x); }

__device__ __forceinline__ unsigned sortkey(float f) {
  unsigned u = __float_as_uint(f);
  unsigned m = ((unsigned)((int)u >> 31)) | 0x80000000u;
  return u ^ m;  // monotone float->uint map (handles tiny negative d2 from rounding)
}

__device__ __forceinline__ u64 shfl64(u64 v, int src) {
  int lo = __shfl((int)(unsigned)v, src, 64);
  int hi = __shfl((int)(unsigned)(v >> 32), src, 64);
  return ((u64)(unsigned)hi << 32) | (unsigned)lo;
}
__device__ __forceinline__ u64 shfl_xor64(u64 v, int mask) {
  int lo = __shfl_xor((int)(unsigned)v, mask, 64);
  int hi = __shfl_xor((int)(unsigned)(v >> 32), mask, 64);
  return ((u64)(unsigned)hi << 32) | (unsigned)lo;
}

// ---------------- embed: h = elu(x*datanorm @ W_in + b_in) ----------------
__global__ void k_embed(const float* __restrict__ x, const float* __restrict__ dn,
                        const float* __restrict__ Win, const float* __restrict__ bin,
                        float* __restrict__ h) {
  const int t = threadIdx.x;
  const int row = blockIdx.x * 4 + (t >> 6);
  const int d = t & 63;
  const float* xr = x + (size_t)row * 3;
  float a = bin[d];
#pragma unroll
  for (int c = 0; c < 3; ++c) a = fmaf(xr[c] * dn[c], Win[c * HD + d], a);
  h[(size_t)row * HD + d] = elu_f(a);
}

// ---------------- row squared norms ----------------
__global__ void k_norms(const float* __restrict__ h, float* __restrict__ xx) {
  const int t = threadIdx.x;
  const int row = blockIdx.x * 4 + (t >> 6);
  const int lane = t & 63;
  float v = h[(size_t)row * HD + lane];
  float s = v * v;
#pragma unroll
  for (int m = 32; m >= 1; m >>= 1) s += __shfl_xor(s, m, 64);
  if (lane == 0) xx[row] = s;
}

// ---------------- split h (fp32) into bf16 hi/lo packed in MFMA fragment order ----
// Packed layout per 128-row block: [rt16(8)][kc(2)][quad(4)][row16(16)][8 elems]
// so a wave's 16x16x32 fragment read is 64 consecutive 16B chunks (conflict-free).
__global__ void k_split(const float* __restrict__ h, unsigned short* __restrict__ hhi,
                        unsigned short* __restrict__ hlo) {
  const int C = blockIdx.x * 256 + threadIdx.x;  // one 8-elem chunk per thread
  const int Rg = C >> 10;                        // 128-row block index
  const int within = C & 1023;
  const int rt16 = within >> 7;
  const int kc = (within >> 6) & 1;
  const int quad = (within >> 4) & 3;
  const int row = within & 15;
  const int r = Rg * 128 + rt16 * 16 + row;
  const int k0 = kc * 32 + quad * 8;
  const float* src = h + (size_t)r * HD + k0;
  unsigned hh[8], ll[8];
#pragma unroll
  for (int j = 0; j < 8; ++j) {
    const float f = src[j];
    const unsigned u = __float_as_uint(f);
    const unsigned hb = (u + 0x7fffu + ((u >> 16) & 1u)) >> 16;  // RNE f32->bf16
    const float hif = __uint_as_float(hb << 16);
    const float lo = f - hif;
    const unsigned ul = __float_as_uint(lo);
    const unsigned lb = (ul + 0x7fffu + ((ul >> 16) & 1u)) >> 16;
    hh[j] = hb; ll[j] = lb;
  }
  uint4 oh, ol;
  oh.x = hh[0] | (hh[1] << 16); oh.y = hh[2] | (hh[3] << 16);
  oh.z = hh[4] | (hh[5] << 16); oh.w = hh[6] | (hh[7] << 16);
  ol.x = ll[0] | (ll[1] << 16); ol.y = ll[2] | (ll[3] << 16);
  ol.z = ll[4] | (ll[5] << 16); ol.w = ll[6] | (ll[7] << 16);
  *(uint4*)(hhi + (size_t)C * 8) = oh;
  *(uint4*)(hlo + (size_t)C * 8) = ol;
}

// ---------------- Gram matrix dot[b][q][c] via split-bf16 MFMA -------------------
// dot = hi*hi + hi*lo + lo*hi (lo*lo ~ 2^-18 relative, dropped). 128x128 per block,
// 4 waves each 64x64 via 16 position-tiles of mfma_f32_16x16x32_bf16.
__global__ __launch_bounds__(256, 2) void k_gram(const unsigned short* __restrict__ hhi,
                                                 const unsigned short* __restrict__ hlo,
                                                 float* __restrict__ dot, int b0) {
  __shared__ unsigned short Ah[8192], Al[8192], Bh[8192], Bl[8192];  // 64 KB
  const int t = threadIdx.x;
  const int bl = blockIdx.x / 576;
  const int rem = blockIdx.x % 576;
  const int qt = rem / 24, ct = rem % 24;
  const int bg = b0 + bl;
  {
    const uint4* sah = (const uint4*)(hhi + ((size_t)bg * 24 + qt) * 8192);
    const uint4* sal = (const uint4*)(hlo + ((size_t)bg * 24 + qt) * 8192);
    const uint4* sbh = (const uint4*)(hhi + ((size_t)bg * 24 + ct) * 8192);
    const uint4* sbl = (const uint4*)(hlo + ((size_t)bg * 24 + ct) * 8192);
    uint4* dah = (uint4*)Ah; uint4* dal = (uint4*)Al;
    uint4* dbh = (uint4*)Bh; uint4* dbl = (uint4*)Bl;
#pragma unroll
    for (int i = 0; i < 4; ++i) {
      const int idx = t + 256 * i;
      dah[idx] = sah[idx]; dal[idx] = sal[idx];
      dbh[idx] = sbh[idx]; dbl[idx] = sbl[idx];
    }
  }
  __syncthreads();
  const int w = t >> 6, ln = t & 63;
  const int wa = w >> 1, wb = w & 1;
  const int lane16 = ln & 15, quad = ln >> 4;

  short8 af[4][2][2], bf[4][2][2];  // [mt][kc][hi/lo]
#pragma unroll
  for (int mt = 0; mt < 4; ++mt) {
#pragma unroll
    for (int kc = 0; kc < 2; ++kc) {
      const int offA = (((wa * 4 + mt) * 2 + kc) * 64 + ln) * 8;
      const int offB = (((wb * 4 + mt) * 2 + kc) * 64 + ln) * 8;
      af[mt][kc][0] = *(const short8*)&Ah[offA];
      af[mt][kc][1] = *(const short8*)&Al[offA];
      bf[mt][kc][0] = *(const short8*)&Bh[offB];
      bf[mt][kc][1] = *(const short8*)&Bl[offB];
    }
  }
  f32x4 acc[4][4];
#pragma unroll
  for (int mt = 0; mt < 4; ++mt)
#pragma unroll
    for (int nt = 0; nt < 4; ++nt) acc[mt][nt] = (f32x4){0.f, 0.f, 0.f, 0.f};
#pragma unroll
  for (int kc = 0; kc < 2; ++kc)
#pragma unroll
    for (int mt = 0; mt < 4; ++mt)
#pragma unroll
      for (int nt = 0; nt < 4; ++nt) {
        acc[mt][nt] = __builtin_amdgcn_mfma_f32_16x16x32_bf16(
            af[mt][kc][0], bf[nt][kc][0], acc[mt][nt], 0, 0, 0);
        acc[mt][nt] = __builtin_amdgcn_mfma_f32_16x16x32_bf16(
            af[mt][kc][0], bf[nt][kc][1], acc[mt][nt], 0, 0, 0);
        acc[mt][nt] = __builtin_amdgcn_mfma_f32_16x16x32_bf16(
            af[mt][kc][1], bf[nt][kc][0], acc[mt][nt], 0, 0, 0);
      }
#pragma unroll
  for (int mt = 0; mt < 4; ++mt)
#pragma unroll
    for (int nt = 0; nt < 4; ++nt) {
      const int q = qt * 128 + wa * 64 + mt * 16 + quad * 4;
      const int c = ct * 128 + wb * 64 + nt * 16 + lane16;
      float* drow = dot + ((size_t)bl * NN + q) * NN + c;
#pragma unroll
      for (int r = 0; r < 4; ++r) drow[(size_t)r * NN] = acc[mt][nt][r];
    }
}

// ---------------- top-16 selection from materialized dot rows --------------------
// 1 wave per query; streams 48 coalesced 64-candidate tiles; exact top-16
// (tie -> lower index) via threshold-ballot insertion.
__global__ __launch_bounds__(256) void k_select(const float* __restrict__ dot,
                                                const float* __restrict__ xx,
                                                int* __restrict__ knn, int b0) {
  const int t = threadIdx.x;
  const int w = t >> 6, lane = t & 63;
  const int qi = blockIdx.x * 4 + w;
  const int bl = qi / NN, q = qi % NN;
  const int bg = b0 + bl;
  const float xxq = xx[(size_t)bg * NN + q];
  const float* drow = dot + ((size_t)bl * NN + q) * NN;
  const float* xxb = xx + (size_t)bg * NN;

  u64 key = ~0ull;
  u64 kth = ~0ull;
  int maxlane = 0;
  for (int jt = 0; jt < NN / 64; ++jt) {
    const int j = jt * 64 + lane;
    const float dv = drow[j];
    const float d2 = (xxq + xxb[j]) - 2.0f * dv;
    const u64 ck = ((u64)sortkey(d2) << 32) | (unsigned)j;
    u64 qual = __ballot(ck < kth);
    while (qual) {
      const int s = __builtin_ctzll(qual);
      qual &= qual - 1;
      const u64 c = shfl64(ck, s);
      if (c < kth) {
        if (lane == maxlane) key = c;
        u64 r = key;
#pragma unroll
        for (int m = 1; m < 16; m <<= 1) {
          const u64 o = shfl_xor64(r, m);
          r = (o > r) ? o : r;
        }
        kth = shfl64(r, 0);
        maxlane = (int)__builtin_ctzll(__ballot(key == kth));
      }
    }
  }
  if (lane < 16) knn[((size_t)bg * NN + q) * KK + lane] = (int)(unsigned)(key & 0xffffffffu);
}

// ---------------- fallback exact KNN (ws too small for dot buffer) ---------------
__global__ __launch_bounds__(1024, 4) void k_knn(const float* __restrict__ h,
                                                 const float* __restrict__ xx,
                                                 int* __restrict__ knn) {
  __shared__ float tile[2 * 64 * 64];
  const int t = threadIdx.x;
  const int w = t >> 6, lane = t & 63;
  const int b = blockIdx.x / (NN / 16);
  const int i = (blockIdx.x % (NN / 16)) * 16 + w;
  const float* hb = h + (size_t)b * NN * HD;
  float4 hi[16];
  {
    const float4* hrow = (const float4*)(hb + (size_t)i * HD);
#pragma unroll
    for (int g = 0; g < 16; ++g) hi[g] = hrow[g];
  }
  const float xxi = xx[b * NN + i];
  u64 key = ~0ull, kth = ~0ull;
  int maxlane = 0;
  const int lr = t >> 4, lg = t & 15;
  const int NT = NN / 64;
  {
    float4 v = *(const float4*)(hb + (size_t)lr * HD + lg * 4);
    *(float4*)&tile[lr * 64 + ((lg ^ (lr & 15)) << 2)] = v;
  }
  for (int jt = 0; jt < NT; ++jt) {
    float4 nxt;
    if (jt + 1 < NT)
      nxt = *(const float4*)(hb + (size_t)((jt + 1) * 64 + lr) * HD + lg * 4);
    __syncthreads();
    const float* tb = tile + (jt & 1) * 4096;
    const int sw = lane & 15;
    float dotv = 0.f;
#pragma unroll
    for (int g = 0; g < 16; ++g) {
      const float4 vj = *(const float4*)&tb[lane * 64 + ((g ^ sw) << 2)];
      dotv = fmaf(hi[g].x, vj.x, dotv);
      dotv = fmaf(hi[g].y, vj.y, dotv);
      dotv = fmaf(hi[g].z, vj.z, dotv);
      dotv = fmaf(hi[g].w, vj.w, dotv);
    }
    const int j = jt * 64 + lane;
    const float d2 = (xxi + xx[b * NN + j]) - 2.0f * dotv;
    const u64 ck = ((u64)sortkey(d2) << 32) | (unsigned)j;
    u64 qual = __ballot(ck < kth);
    while (qual) {
      const int s = __builtin_ctzll(qual);
      qual &= qual - 1;
      const u64 c = shfl64(ck, s);
      if (c < kth) {
        if (lane == maxlane) key = c;
        u64 r = key;
#pragma unroll
        for (int m = 1; m < 16; m <<= 1) {
          const u64 o = shfl_xor64(r, m);
          r = (o > r) ? o : r;
        }
        kth = shfl64(r, 0);
        maxlane = (int)__builtin_ctzll(__ballot(key == kth));
      }
    }
    if (jt + 1 < NT)
      *(float4*)&tile[((jt + 1) & 1) * 4096 + lr * 64 + ((lg ^ (lr & 15)) << 2)] = nxt;
  }
  if (lane < 16) knn[((size_t)b * NN + i) * KK + lane] = (int)(unsigned)(key & 0xffffffffu);
}

// ---------------- edge MLP + aggregation for 4 points (64 edges) per block -------
__global__ __launch_bounds__(256, 3) void k_msg(const float* __restrict__ h,
                                                const int* __restrict__ knn,
                                                const float* __restrict__ W1,
                                                const float* __restrict__ b1,
                                                const float* __restrict__ W2,
                                                const float* __restrict__ b2,
                                                float* __restrict__ hout) {
  __shared__ float base1[4 * 128];
  __shared__ float msgT[64 * 64];
  __shared__ float m1s[64 * 128];
  const int t = threadIdx.x;
  const int b = blockIdx.x / (NN / 4);
  const int p0 = (blockIdx.x % (NN / 4)) * 4;
  const float* hb = h + (size_t)b * NN * HD;
  {
    const int o = t & 127, lp2 = t >> 7;
#pragma unroll
    for (int rep = 0; rep < 2; ++rep) {
      const int lp = lp2 * 2 + rep;
      const float* hp = hb + (size_t)(p0 + lp) * HD;
      float a = b1[o];
      for (int c = 0; c < 64; ++c) a = fmaf(hp[c], W1[c * 128 + o], a);
      base1[lp * 128 + o] = a;
    }
  }
  {
    const int e = t >> 2, cq = t & 3;
    const int lp = e >> 4, kk = e & 15;
    const int p = p0 + lp;
    const int j = knn[((size_t)b * NN + p) * KK + kk];
    const float* hp = hb + (size_t)p * HD;
    const float* hj = hb + (size_t)j * HD;
#pragma unroll
    for (int q = 0; q < 4; ++q) {
      const int c = cq * 16 + q * 4;
      const float4 vi = *(const float4*)(hp + c);
      const float4 vj = *(const float4*)(hj + c);
      msgT[(c + 0) * 64 + e] = vj.x - vi.x;
      msgT[(c + 1) * 64 + e] = vj.y - vi.y;
      msgT[(c + 2) * 64 + e] = vj.z - vi.z;
      msgT[(c + 3) * 64 + e] = vj.w - vi.w;
    }
  }
  __syncthreads();
  {
    const int o0 = (t & 15) * 8;
    const int e0 = (t >> 4) * 4;
    const int lp = e0 >> 4;
    float acc[4][8];
#pragma unroll
    for (int ee = 0; ee < 4; ++ee)
#pragma unroll
      for (int oo = 0; oo < 8; ++oo) acc[ee][oo] = base1[lp * 128 + o0 + oo];
    for (int c = 0; c < 64; ++c) {
      const float4 am = *(const float4*)&msgT[c * 64 + e0];
      const float4 w0 = *(const float4*)(W1 + (size_t)(64 + c) * 128 + o0);
      const float4 w1 = *(const float4*)(W1 + (size_t)(64 + c) * 128 + o0 + 4);
      const float av[4] = {am.x, am.y, am.z, am.w};
      const float wv[8] = {w0.x, w0.y, w0.z, w0.w, w1.x, w1.y, w1.z, w1.w};
#pragma unroll
      for (int ee = 0; ee < 4; ++ee)
#pragma unroll
        for (int oo = 0; oo < 8; ++oo) acc[ee][oo] = fmaf(av[ee], wv[oo], acc[ee][oo]);
    }
#pragma unroll
    for (int ee = 0; ee < 4; ++ee) {
      const int e = e0 + ee;
      const int sw = e & 15;
      float4 v0, v1;
      v0.x = elu_f(acc[ee][0]); v0.y = elu_f(acc[ee][1]);
      v0.z = elu_f(acc[ee][2]); v0.w = elu_f(acc[ee][3]);
      v1.x = elu_f(acc[ee][4]); v1.y = elu_f(acc[ee][5]);
      v1.z = elu_f(acc[ee][6]); v1.w = elu_f(acc[ee][7]);
      *(float4*)&m1s[e * 128 + (((o0 >> 2) ^ sw) << 2)] = v0;
      *(float4*)&m1s[e * 128 + ((((o0 + 4) >> 2) ^ sw) << 2)] = v1;
    }
  }
  __syncthreads();
  {
    const int o0 = (t & 15) * 4;
    const int e0 = (t >> 4) * 4;
    float acc2[4][4];
#pragma unroll
    for (int ee = 0; ee < 4; ++ee) {
      acc2[ee][0] = b2[o0 + 0]; acc2[ee][1] = b2[o0 + 1];
      acc2[ee][2] = b2[o0 + 2]; acc2[ee][3] = b2[o0 + 3];
    }
    for (int c = 0; c < 128; ++c) {
      const float4 wv = *(const float4*)(W2 + (size_t)c * 64 + o0);
#pragma unroll
      for (int ee = 0; ee < 4; ++ee) {
        const int e = e0 + ee;
        const float a = m1s[e * 128 + (((c >> 2) ^ (e & 15)) << 2) + (c & 3)];
        acc2[ee][0] = fmaf(a, wv.x, acc2[ee][0]);
        acc2[ee][1] = fmaf(a, wv.y, acc2[ee][1]);
        acc2[ee][2] = fmaf(a, wv.z, acc2[ee][2]);
        acc2[ee][3] = fmaf(a, wv.w, acc2[ee][3]);
      }
    }
    float* red = msgT;
    float4 s;
    s.x = elu_f(acc2[0][0]) + elu_f(acc2[1][0]) + elu_f(acc2[2][0]) + elu_f(acc2[3][0]);
    s.y = elu_f(acc2[0][1]) + elu_f(acc2[1][1]) + elu_f(acc2[2][1]) + elu_f(acc2[3][1]);
    s.z = elu_f(acc2[0][2]) + elu_f(acc2[1][2]) + elu_f(acc2[2][2]) + elu_f(acc2[3][2]);
    s.w = elu_f(acc2[0][3]) + elu_f(acc2[1][3]) + elu_f(acc2[2][3]) + elu_f(acc2[3][3]);
    const int g = t >> 4;
    *(float4*)&red[g * 72 + o0] = s;
  }
  __syncthreads();
  {
    const float* red = msgT;
    const int lp = t >> 6, o = t & 63;
    const float v = red[(lp * 4 + 0) * 72 + o] + red[(lp * 4 + 1) * 72 + o] +
                    red[(lp * 4 + 2) * 72 + o] + red[(lp * 4 + 3) * 72 + o];
    hout[((size_t)b * NN + p0 + lp) * HD + o] = v;
  }
}

// ---------------- max-pool + head MLP, one block per batch ----------------
__global__ void k_head(const float* __restrict__ h, const float* __restrict__ Wo1,
                       const float* __restrict__ bo1, const float* __restrict__ Wo2,
                       const float* __restrict__ bo2, const float* __restrict__ Wo3,
                       const float* __restrict__ bo3, float* __restrict__ out) {
  __shared__ float pool4[4 * 64];
  __shared__ float pooled[64];
  __shared__ float o1[64];
  __shared__ float o2s[64];
  const int t = threadIdx.x;
  const int b = blockIdx.x;
  const int q = t >> 6, d = t & 63;
  const float* hb = h + (size_t)b * NN * HD;
  float m = -3.402823466e+38f;
  for (int n = q; n < NN; n += 4) m = fmaxf(m, hb[(size_t)n * HD + d]);
  pool4[q * 64 + d] = m;
  __syncthreads();
  if (t < 64) {
    pooled[t] = fmaxf(fmaxf(pool4[t], pool4[64 + t]),
                      fmaxf(pool4[128 + t], pool4[192 + t]));
  }
  __syncthreads();
  if (t < 64) {
    float a = bo1[t];
    for (int c = 0; c < 64; ++c) a = fmaf(pooled[c], Wo1[c * 64 + t], a);
    o1[t] = elu_f(a);
  }
  __syncthreads();
  if (t < 64) {
    float a = bo2[t];
    for (int c = 0; c < 64; ++c) a = fmaf(o1[c], Wo2[c * 64 + t], a);
    o2s[t] = elu_f(a);
  }
  __syncthreads();
  if (t < 64) {
    float v = o2s[t] * Wo3[t];
#pragma unroll
    for (int mm = 32; mm >= 1; mm >>= 1) v += __shfl_xor(v, mm, 64);
    if (t == 0) out[b] = v + bo3[0];
  }
}

extern "C" void kernel_launch(void* const* d_in, const int* in_sizes, int n_in,
                              void* d_out, int out_size, void* d_ws, size_t ws_size,
                              hipStream_t stream) {
  const float* x   = (const float*)d_in[0];
  const float* dn  = (const float*)d_in[1];
  const float* Win = (const float*)d_in[2];
  const float* bin = (const float*)d_in[3];
  const float* W1  = (const float*)d_in[4];
  const float* b1  = (const float*)d_in[5];
  const float* W2  = (const float*)d_in[6];
  const float* b2  = (const float*)d_in[7];
  const float* Wo1 = (const float*)d_in[8];
  const float* bo1 = (const float*)d_in[9];
  const float* Wo2 = (const float*)d_in[10];
  const float* bo2 = (const float*)d_in[11];
  const float* Wo3 = (const float*)d_in[12];
  const float* bo3 = (const float*)d_in[13];
  float* out = (float*)d_out;

  char* p = (char*)d_ws;
  const size_t hbytes = (size_t)NB * NN * HD * 4;  // 6291456
  float* h0 = (float*)p; p += hbytes;
  float* h1 = (float*)p; p += hbytes;
  float* xx = (float*)p; p += (size_t)NB * NN * 4;
  int* knn  = (int*)p;   p += (size_t)NB * NN * KK * 4;
  unsigned short* hhi = (unsigned short*)p; p += (size_t)NB * NN * HD * 2;
  unsigned short* hlo = (unsigned short*)p; p += (size_t)NB * NN * HD * 2;
  float* dotb = (float*)p;
  const size_t used = (size_t)(p - (char*)d_ws);        // ~20.5 MB
  const size_t per_batch = (size_t)NN * NN * 4;         // 37.75 MB
  int nc = 0;
  if (ws_size > used) {
    size_t cap = (ws_size - used) / per_batch;
    nc = cap > 8 ? 8 : (int)cap;
  }

  const int rows = NB * NN;
  k_embed<<<rows / 4, 256, 0, stream>>>(x, dn, Win, bin, h0);
  float* hin = h0;
  float* hbuf = h1;
  for (int l = 0; l < NL; ++l) {
    k_norms<<<rows / 4, 256, 0, stream>>>(hin, xx);
    if (nc >= 1) {
      k_split<<<rows * HD / 8 / 256, 256, 0, stream>>>(hin, hhi, hlo);
      for (int c0 = 0; c0 < NB; c0 += nc) {
        const int ncc = (NB - c0) < nc ? (NB - c0) : nc;
        k_gram<<<ncc * 576, 256, 0, stream>>>(hhi, hlo, dotb, c0);
        k_select<<<ncc * (NN / 4), 256, 0, stream>>>(dotb, xx, knn, c0);
      }
    } else {
      k_knn<<<rows / 16, 1024, 0, stream>>>(hin, xx, knn);
    }
    k_msg<<<rows / 4, 256, 0, stream>>>(hin, knn, W1 + (size_t)l * 128 * 128,
                                        b1 + l * 128, W2 + (size_t)l * 128 * 64,
                                        b2 + l * 64, hbuf);
    float* tmp = hin; hin = hbuf; hbuf = tmp;
  }
  k_head<<<NB, 256, 0, stream>>>(hin, Wo1, bo1, Wo2, bo2, Wo3, bo3, out);
}

// Round 3
// 994.816 us; speedup vs baseline: 2.1029x; 1.7614x over previous
//
#include <hip/hip_runtime.h>
#include <cstdint>

#define NB 8
#define NN 3072
#define HD 64
#define KK 16
#define NL 2

typedef unsigned long long u64;
typedef __attribute__((ext_vector_type(8))) short short8;
typedef __attribute__((ext_vector_type(4))) float f32x4;

__device__ __forceinline__ float elu_f(float x) { return x > 0.0f ? x : expm1f(x); }

__device__ __forceinline__ unsigned sortkey(float f) {
  unsigned u = __float_as_uint(f);
  unsigned m = ((unsigned)((int)u >> 31)) | 0x80000000u;
  return u ^ m;  // monotone float->uint map
}

__device__ __forceinline__ u64 shfl64(u64 v, int src) {
  int lo = __shfl((int)(unsigned)v, src, 64);
  int hi = __shfl((int)(unsigned)(v >> 32), src, 64);
  return ((u64)(unsigned)hi << 32) | (unsigned)lo;
}
__device__ __forceinline__ u64 shfl_xor64(u64 v, int mask) {
  int lo = __shfl_xor((int)(unsigned)v, mask, 64);
  int hi = __shfl_xor((int)(unsigned)(v >> 32), mask, 64);
  return ((u64)(unsigned)hi << 32) | (unsigned)lo;
}

__device__ __forceinline__ void split_bf16(float f, unsigned& hb, unsigned& lb) {
  unsigned u = __float_as_uint(f);
  hb = (u + 0x7fffu + ((u >> 16) & 1u)) >> 16;  // RNE f32->bf16
  float hif = __uint_as_float(hb << 16);
  float lo = f - hif;
  unsigned ul = __float_as_uint(lo);
  lb = (ul + 0x7fffu + ((ul >> 16) & 1u)) >> 16;
}

// sorts a bitonic 16-sequence ascending (standard bitonic merge network)
__device__ __forceinline__ void bmerge16(u64* v) {
#pragma unroll
  for (int d = 8; d >= 1; d >>= 1) {
#pragma unroll
    for (int i = 0; i < 16; ++i) {
      if (!(i & d)) {
        u64 a = v[i], b = v[i | d];
        bool c = a <= b;
        v[i] = c ? a : b;
        v[i | d] = c ? b : a;
      }
    }
  }
}

// ---------------- embed: h = elu(x*datanorm @ W_in + b_in) ----------------
__global__ void k_embed(const float* __restrict__ x, const float* __restrict__ dn,
                        const float* __restrict__ Win, const float* __restrict__ bin,
                        float* __restrict__ h) {
  const int t = threadIdx.x;
  const int row = blockIdx.x * 4 + (t >> 6);
  const int d = t & 63;
  const float* xr = x + (size_t)row * 3;
  float a = bin[d];
#pragma unroll
  for (int c = 0; c < 3; ++c) a = fmaf(xr[c] * dn[c], Win[c * HD + d], a);
  h[(size_t)row * HD + d] = elu_f(a);
}

// ---------------- row squared norms ----------------
__global__ void k_norms(const float* __restrict__ h, float* __restrict__ xx) {
  const int t = threadIdx.x;
  const int row = blockIdx.x * 4 + (t >> 6);
  const int lane = t & 63;
  float v = h[(size_t)row * HD + lane];
  float s = v * v;
#pragma unroll
  for (int m = 32; m >= 1; m >>= 1) s += __shfl_xor(s, m, 64);
  if (lane == 0) xx[row] = s;
}

// ---------------- split h (fp32) into bf16 hi/lo packed in MFMA fragment order ----
__global__ void k_split(const float* __restrict__ h, unsigned short* __restrict__ hhi,
                        unsigned short* __restrict__ hlo) {
  const int C = blockIdx.x * 256 + threadIdx.x;  // one 8-elem chunk per thread
  const int Rg = C >> 10;                        // 128-row block index
  const int within = C & 1023;
  const int rt16 = within >> 7;
  const int kc = (within >> 6) & 1;
  const int quad = (within >> 4) & 3;
  const int row = within & 15;
  const int r = Rg * 128 + rt16 * 16 + row;
  const int k0 = kc * 32 + quad * 8;
  const float* src = h + (size_t)r * HD + k0;
  unsigned hh[8], ll[8];
#pragma unroll
  for (int j = 0; j < 8; ++j) split_bf16(src[j], hh[j], ll[j]);
  uint4 oh, ol;
  oh.x = hh[0] | (hh[1] << 16); oh.y = hh[2] | (hh[3] << 16);
  oh.z = hh[4] | (hh[5] << 16); oh.w = hh[6] | (hh[7] << 16);
  ol.x = ll[0] | (ll[1] << 16); ol.y = ll[2] | (ll[3] << 16);
  ol.z = ll[4] | (ll[5] << 16); ol.w = ll[6] | (ll[7] << 16);
  *(uint4*)(hhi + (size_t)C * 8) = oh;
  *(uint4*)(hlo + (size_t)C * 8) = ol;
}

// ---------------- pack W1[64:128] and W2 into MFMA B-fragment order, bf16 hi/lo ----
__global__ void k_packw(const float* __restrict__ W1, const float* __restrict__ W2,
                        unsigned short* __restrict__ w1h, unsigned short* __restrict__ w1l,
                        unsigned short* __restrict__ w2h, unsigned short* __restrict__ w2l) {
  const int cid = blockIdx.x * 256 + threadIdx.x;  // 4096 chunks
  const int l = cid >> 11;
  const int r = cid & 2047;
  const int isw2 = r >> 10;
  const int c = r & 1023;
  const int lane = c & 63;
  unsigned hh[8], ll[8];
  if (!isw2) {
    const int nt = c >> 7, kc = (c >> 6) & 1;
    const int k0 = 64 + kc * 32 + (lane >> 4) * 8;
    const int n = nt * 16 + (lane & 15);
#pragma unroll
    for (int j = 0; j < 8; ++j) split_bf16(W1[(size_t)l * 16384 + (k0 + j) * 128 + n], hh[j], ll[j]);
    unsigned short* dh = w1h + ((size_t)l * 1024 + c) * 8;
    unsigned short* dl = w1l + ((size_t)l * 1024 + c) * 8;
#pragma unroll
    for (int j = 0; j < 8; ++j) { dh[j] = (unsigned short)hh[j]; dl[j] = (unsigned short)ll[j]; }
  } else {
    const int nt = c >> 8, kc = (c >> 6) & 3;
    const int k0 = kc * 32 + (lane >> 4) * 8;
    const int n = nt * 16 + (lane & 15);
#pragma unroll
    for (int j = 0; j < 8; ++j) split_bf16(W2[(size_t)l * 8192 + (k0 + j) * 64 + n], hh[j], ll[j]);
    unsigned short* dh = w2h + ((size_t)l * 1024 + c) * 8;
    unsigned short* dl = w2l + ((size_t)l * 1024 + c) * 8;
#pragma unroll
    for (int j = 0; j < 8; ++j) { dh[j] = (unsigned short)hh[j]; dl[j] = (unsigned short)ll[j]; }
  }
}

// ---------------- Gram matrix dot[b][q][c] via split-bf16 MFMA -------------------
__global__ __launch_bounds__(256, 2) void k_gram(const unsigned short* __restrict__ hhi,
                                                 const unsigned short* __restrict__ hlo,
                                                 float* __restrict__ dot, int b0) {
  __shared__ unsigned short Ah[8192], Al[8192], Bh[8192], Bl[8192];  // 64 KB
  const int t = threadIdx.x;
  const int bl = blockIdx.x / 576;
  const int rem = blockIdx.x % 576;
  const int qt = rem / 24, ct = rem % 24;
  const int bg = b0 + bl;
  {
    const uint4* sah = (const uint4*)(hhi + ((size_t)bg * 24 + qt) * 8192);
    const uint4* sal = (const uint4*)(hlo + ((size_t)bg * 24 + qt) * 8192);
    const uint4* sbh = (const uint4*)(hhi + ((size_t)bg * 24 + ct) * 8192);
    const uint4* sbl = (const uint4*)(hlo + ((size_t)bg * 24 + ct) * 8192);
    uint4* dah = (uint4*)Ah; uint4* dal = (uint4*)Al;
    uint4* dbh = (uint4*)Bh; uint4* dbl = (uint4*)Bl;
#pragma unroll
    for (int i = 0; i < 4; ++i) {
      const int idx = t + 256 * i;
      dah[idx] = sah[idx]; dal[idx] = sal[idx];
      dbh[idx] = sbh[idx]; dbl[idx] = sbl[idx];
    }
  }
  __syncthreads();
  const int w = t >> 6, ln = t & 63;
  const int wa = w >> 1, wb = w & 1;
  const int lane16 = ln & 15, quad = ln >> 4;

  short8 af[4][2][2], bf[4][2][2];
#pragma unroll
  for (int mt = 0; mt < 4; ++mt) {
#pragma unroll
    for (int kc = 0; kc < 2; ++kc) {
      const int offA = (((wa * 4 + mt) * 2 + kc) * 64 + ln) * 8;
      const int offB = (((wb * 4 + mt) * 2 + kc) * 64 + ln) * 8;
      af[mt][kc][0] = *(const short8*)&Ah[offA];
      af[mt][kc][1] = *(const short8*)&Al[offA];
      bf[mt][kc][0] = *(const short8*)&Bh[offB];
      bf[mt][kc][1] = *(const short8*)&Bl[offB];
    }
  }
  f32x4 acc[4][4];
#pragma unroll
  for (int mt = 0; mt < 4; ++mt)
#pragma unroll
    for (int nt = 0; nt < 4; ++nt) acc[mt][nt] = (f32x4){0.f, 0.f, 0.f, 0.f};
#pragma unroll
  for (int kc = 0; kc < 2; ++kc)
#pragma unroll
    for (int mt = 0; mt < 4; ++mt)
#pragma unroll
      for (int nt = 0; nt < 4; ++nt) {
        acc[mt][nt] = __builtin_amdgcn_mfma_f32_16x16x32_bf16(
            af[mt][kc][0], bf[nt][kc][0], acc[mt][nt], 0, 0, 0);
        acc[mt][nt] = __builtin_amdgcn_mfma_f32_16x16x32_bf16(
            af[mt][kc][0], bf[nt][kc][1], acc[mt][nt], 0, 0, 0);
        acc[mt][nt] = __builtin_amdgcn_mfma_f32_16x16x32_bf16(
            af[mt][kc][1], bf[nt][kc][0], acc[mt][nt], 0, 0, 0);
      }
#pragma unroll
  for (int mt = 0; mt < 4; ++mt)
#pragma unroll
    for (int nt = 0; nt < 4; ++nt) {
      const int q = qt * 128 + wa * 64 + mt * 16 + quad * 4;
      const int c = ct * 128 + wb * 64 + nt * 16 + lane16;
      float* drow = dot + ((size_t)bl * NN + q) * NN + c;
#pragma unroll
      for (int r = 0; r < 4; ++r) drow[(size_t)r * NN] = acc[mt][nt][r];
    }
}

// ---------------- top-16 selection: per-lane local top-8 + bitonic merge tree ----
// Exact top-16 (tie -> lower index): key = (sortkey(d2)<<32)|j, strict-< everywhere.
__global__ __launch_bounds__(256) void k_select(const float* __restrict__ dot,
                                                const float* __restrict__ xx,
                                                int* __restrict__ knn, int b0) {
  const int t = threadIdx.x;
  const int w = t >> 6, lane = t & 63;
  const int qi = blockIdx.x * 4 + w;
  const int bl = qi / NN, q = qi % NN;
  const int bg = b0 + bl;
  const float xxq = xx[(size_t)bg * NN + q];
  const float* drow = dot + ((size_t)bl * NN + q) * NN;
  const float* xxb = xx + (size_t)bg * NN;

  // phase A: per-lane sorted top-8 over this lane's 48 candidates
  u64 s[8];
#pragma unroll
  for (int i = 0; i < 8; ++i) s[i] = ~0ull;
#pragma unroll 4
  for (int jt = 0; jt < NN / 64; ++jt) {
    const int j = jt * 64 + lane;
    const float d2 = (xxq + xxb[j]) - 2.0f * drow[j];
    const u64 key = ((u64)sortkey(d2) << 32) | (unsigned)j;
    if (key < s[7]) {
      bool c[8];
#pragma unroll
      for (int i = 0; i < 8; ++i) c[i] = s[i] < key;
#pragma unroll
      for (int i = 7; i > 0; --i) s[i] = c[i] ? s[i] : (c[i - 1] ? key : s[i - 1]);
      s[0] = c[0] ? s[0] : key;
    }
  }
  // phase B: merge 64 sorted-8 lists -> global sorted top-16 (all lanes identical)
  u64 v[16];
#pragma unroll
  for (int i = 0; i < 8; ++i) {
    v[i] = s[i];
    v[15 - i] = shfl_xor64(s[i], 1);  // partner list reversed -> bitonic 16
  }
  bmerge16(v);
#pragma unroll
  for (int lvl = 1; lvl < 6; ++lvl) {
    const int mask = 1 << lvl;
    u64 p[16];
#pragma unroll
    for (int i = 0; i < 16; ++i) p[i] = shfl_xor64(v[i], mask);
    u64 nv[16];
#pragma unroll
    for (int i = 0; i < 16; ++i) {
      const u64 a = v[i], b = p[15 - i];
      nv[i] = a < b ? a : b;  // lower half of bitonic merge -> bitonic 16
    }
    bmerge16(nv);
#pragma unroll
    for (int i = 0; i < 16; ++i) v[i] = nv[i];
  }
  if (lane == 0) {
    int* kout = knn + ((size_t)bg * NN + q) * KK;
#pragma unroll
    for (int k = 0; k < 16; ++k) kout[k] = (int)(unsigned)(v[k] & 0xffffffffu);
  }
}

// ---------------- fallback exact KNN (ws too small for dot buffer) ---------------
__global__ __launch_bounds__(1024, 4) void k_knn(const float* __restrict__ h,
                                                 const float* __restrict__ xx,
                                                 int* __restrict__ knn) {
  __shared__ float tile[2 * 64 * 64];
  const int t = threadIdx.x;
  const int w = t >> 6, lane = t & 63;
  const int b = blockIdx.x / (NN / 16);
  const int i = (blockIdx.x % (NN / 16)) * 16 + w;
  const float* hb = h + (size_t)b * NN * HD;
  float4 hi[16];
  {
    const float4* hrow = (const float4*)(hb + (size_t)i * HD);
#pragma unroll
    for (int g = 0; g < 16; ++g) hi[g] = hrow[g];
  }
  const float xxi = xx[b * NN + i];
  u64 key = ~0ull, kth = ~0ull;
  int maxlane = 0;
  const int lr = t >> 4, lg = t & 15;
  const int NT = NN / 64;
  {
    float4 v = *(const float4*)(hb + (size_t)lr * HD + lg * 4);
    *(float4*)&tile[lr * 64 + ((lg ^ (lr & 15)) << 2)] = v;
  }
  for (int jt = 0; jt < NT; ++jt) {
    float4 nxt;
    if (jt + 1 < NT)
      nxt = *(const float4*)(hb + (size_t)((jt + 1) * 64 + lr) * HD + lg * 4);
    __syncthreads();
    const float* tb = tile + (jt & 1) * 4096;
    const int sw = lane & 15;
    float dotv = 0.f;
#pragma unroll
    for (int g = 0; g < 16; ++g) {
      const float4 vj = *(const float4*)&tb[lane * 64 + ((g ^ sw) << 2)];
      dotv = fmaf(hi[g].x, vj.x, dotv);
      dotv = fmaf(hi[g].y, vj.y, dotv);
      dotv = fmaf(hi[g].z, vj.z, dotv);
      dotv = fmaf(hi[g].w, vj.w, dotv);
    }
    const int j = jt * 64 + lane;
    const float d2 = (xxi + xx[b * NN + j]) - 2.0f * dotv;
    const u64 ck = ((u64)sortkey(d2) << 32) | (unsigned)j;
    u64 qual = __ballot(ck < kth);
    while (qual) {
      const int sl = __builtin_ctzll(qual);
      qual &= qual - 1;
      const u64 c = shfl64(ck, sl);
      if (c < kth) {
        if (lane == maxlane) key = c;
        u64 r = key;
#pragma unroll
        for (int m = 1; m < 16; m <<= 1) {
          const u64 o = shfl_xor64(r, m);
          r = (o > r) ? o : r;
        }
        kth = shfl64(r, 0);
        maxlane = (int)__builtin_ctzll(__ballot(key == kth));
      }
    }
    if (jt + 1 < NT)
      *(float4*)&tile[((jt + 1) & 1) * 4096 + lr * 64 + ((lg ^ (lr & 15)) << 2)] = nxt;
  }
  if (lane < 16) knn[((size_t)b * NN + i) * KK + lane] = (int)(unsigned)(key & 0xffffffffu);
}

// ---------------- edge MLP via split-bf16 MFMA: 4 points (64 edges) per block ----
// m1 = elu(base1[p] + (x_j-x_i)@W1[64:]);  h_out[p] = sum_k elu(m1@W2 + b2)
__global__ __launch_bounds__(256, 1) void k_msg2(
    const float* __restrict__ h, const int* __restrict__ knn,
    const float* __restrict__ W1l, const float* __restrict__ b1l,
    const float* __restrict__ b2l,
    const unsigned short* __restrict__ w1h, const unsigned short* __restrict__ w1l,
    const unsigned short* __restrict__ w2h, const unsigned short* __restrict__ w2l,
    float* __restrict__ hout) {
  __shared__ unsigned short A1h[4096], A1l[4096];  // 16 KB: [mt4][kc2][lane64][8]
  __shared__ float hloc[4 * 64];                   // 1 KB
  __shared__ float base1L[4 * 128];                // 2 KB
  __shared__ float m1c[64 * 132];                  // 33.8 KB (+4 pad per row)
  const int t = threadIdx.x;
  const int b = blockIdx.x / (NN / 4);
  const int p0 = (blockIdx.x % (NN / 4)) * 4;
  const float* hb = h + (size_t)b * NN * HD;

  // load the 4 h_i rows
  if (t < 64) {
    const int p = t >> 4, c4 = t & 15;
    *(float4*)&hloc[p * 64 + c4 * 4] = *(const float4*)(hb + (size_t)(p0 + p) * HD + c4 * 4);
  }
  __syncthreads();

  // stage 0: base1[p][o] = b1[o] + x_i @ W1[0:64]  (fp32 exact)
  {
    const int o = t & 127, ph = t >> 7;
    float a0 = b1l[o], a1 = b1l[o];
    for (int c = 0; c < 64; ++c) {
      const float wv = W1l[c * 128 + o];
      a0 = fmaf(hloc[(ph * 2 + 0) * 64 + c], wv, a0);
      a1 = fmaf(hloc[(ph * 2 + 1) * 64 + c], wv, a1);
    }
    base1L[(ph * 2 + 0) * 128 + o] = a0;
    base1L[(ph * 2 + 1) * 128 + o] = a1;
  }
  // gather diffs -> A-fragment order, split bf16 hi/lo
  {
    const int e = t >> 2, qs = t & 3;
    const int p = e >> 4, m = e & 15;
    const int j = knn[((size_t)b * NN + p0 + p) * KK + m];
    const float* hj = hb + (size_t)j * HD + qs * 16;
    const int kc = qs >> 1;
#pragma unroll
    for (int half = 0; half < 2; ++half) {
      const int c0 = qs * 16 + half * 8;
      const int quad = (c0 >> 3) & 3;
      const float4 va = *(const float4*)(hj + half * 8);
      const float4 vb = *(const float4*)(hj + half * 8 + 4);
      const float4 ia = *(const float4*)&hloc[p * 64 + c0];
      const float4 ib = *(const float4*)&hloc[p * 64 + c0 + 4];
      float d[8] = {va.x - ia.x, va.y - ia.y, va.z - ia.z, va.w - ia.w,
                    vb.x - ib.x, vb.y - ib.y, vb.z - ib.z, vb.w - ib.w};
      unsigned hh[8], ll[8];
#pragma unroll
      for (int jj = 0; jj < 8; ++jj) split_bf16(d[jj], hh[jj], ll[jj]);
      const int off = ((p * 2 + kc) * 64 + quad * 16 + m) * 8;
      uint4 oh, ol;
      oh.x = hh[0] | (hh[1] << 16); oh.y = hh[2] | (hh[3] << 16);
      oh.z = hh[4] | (hh[5] << 16); oh.w = hh[6] | (hh[7] << 16);
      ol.x = ll[0] | (ll[1] << 16); ol.y = ll[2] | (ll[3] << 16);
      ol.z = ll[4] | (ll[5] << 16); ol.w = ll[6] | (ll[7] << 16);
      *(uint4*)&A1h[off] = oh;
      *(uint4*)&A1l[off] = ol;
    }
  }
  __syncthreads();

  const int w = t >> 6, lane = t & 63;
  const int lane16 = lane & 15, quad = lane >> 4;

  // GEMM1: 16 edges (m-tile = point w) x 128 outs, K=64
  f32x4 acc1[8];
#pragma unroll
  for (int nt = 0; nt < 8; ++nt) {
    const float bv = base1L[w * 128 + nt * 16 + lane16];
    acc1[nt] = (f32x4){bv, bv, bv, bv};
  }
  short8 a1[2][2];
#pragma unroll
  for (int kc = 0; kc < 2; ++kc) {
    const int off = ((w * 2 + kc) * 64 + lane) * 8;
    a1[kc][0] = *(const short8*)&A1h[off];
    a1[kc][1] = *(const short8*)&A1l[off];
  }
#pragma unroll
  for (int kc = 0; kc < 2; ++kc)
#pragma unroll
    for (int nt = 0; nt < 8; ++nt) {
      const int off = ((nt * 2 + kc) * 64 + lane) * 8;
      const short8 bh = *(const short8*)(w1h + off);
      const short8 bl = *(const short8*)(w1l + off);
      acc1[nt] = __builtin_amdgcn_mfma_f32_16x16x32_bf16(a1[kc][0], bh, acc1[nt], 0, 0, 0);
      acc1[nt] = __builtin_amdgcn_mfma_f32_16x16x32_bf16(a1[kc][1], bh, acc1[nt], 0, 0, 0);
      acc1[nt] = __builtin_amdgcn_mfma_f32_16x16x32_bf16(a1[kc][0], bl, acc1[nt], 0, 0, 0);
    }
  // m1 = elu(acc1) -> LDS (fp32, row pad +4)
#pragma unroll
  for (int nt = 0; nt < 8; ++nt)
#pragma unroll
    for (int r = 0; r < 4; ++r)
      m1c[(w * 16 + quad * 4 + r) * 132 + nt * 16 + lane16] = elu_f(acc1[nt][r]);
  __syncthreads();

  // GEMM2: 16 edges x 64 outs, K=128; A = m1 (split on the fly)
  f32x4 acc2[4];
#pragma unroll
  for (int nt = 0; nt < 4; ++nt) {
    const float bv = b2l[nt * 16 + lane16];
    acc2[nt] = (f32x4){bv, bv, bv, bv};
  }
  short8 a2h[4], a2l[4];
#pragma unroll
  for (int kc = 0; kc < 4; ++kc) {
    const float* src = &m1c[(w * 16 + lane16) * 132 + kc * 32 + quad * 8];
    const float4 x0 = *(const float4*)src;
    const float4 x1 = *(const float4*)(src + 4);
    const float xv[8] = {x0.x, x0.y, x0.z, x0.w, x1.x, x1.y, x1.z, x1.w};
    unsigned hh[8], ll[8];
#pragma unroll
    for (int jj = 0; jj < 8; ++jj) split_bf16(xv[jj], hh[jj], ll[jj]);
    short8 sh, sl;
#pragma unroll
    for (int jj = 0; jj < 8; ++jj) { sh[jj] = (short)hh[jj]; sl[jj] = (short)ll[jj]; }
    a2h[kc] = sh; a2l[kc] = sl;
  }
#pragma unroll
  for (int kc = 0; kc < 4; ++kc)
#pragma unroll
    for (int nt = 0; nt < 4; ++nt) {
      const int off = ((nt * 4 + kc) * 64 + lane) * 8;
      const short8 bh = *(const short8*)(w2h + off);
      const short8 bl = *(const short8*)(w2l + off);
      acc2[nt] = __builtin_amdgcn_mfma_f32_16x16x32_bf16(a2h[kc], bh, acc2[nt], 0, 0, 0);
      acc2[nt] = __builtin_amdgcn_mfma_f32_16x16x32_bf16(a2l[kc], bh, acc2[nt], 0, 0, 0);
      acc2[nt] = __builtin_amdgcn_mfma_f32_16x16x32_bf16(a2h[kc], bl, acc2[nt], 0, 0, 0);
    }
  // epilogue: elu then sum over the 16 edges of point w
#pragma unroll
  for (int nt = 0; nt < 4; ++nt) {
    float s = elu_f(acc2[nt][0]) + elu_f(acc2[nt][1]) + elu_f(acc2[nt][2]) + elu_f(acc2[nt][3]);
    s += __shfl_xor(s, 16, 64);
    s += __shfl_xor(s, 32, 64);
    if (quad == 0) hout[((size_t)b * NN + p0 + w) * HD + nt * 16 + lane16] = s;
  }
}

// ---------------- max-pool + head MLP, one block per batch ----------------
__global__ void k_head(const float* __restrict__ h, const float* __restrict__ Wo1,
                       const float* __restrict__ bo1, const float* __restrict__ Wo2,
                       const float* __restrict__ bo2, const float* __restrict__ Wo3,
                       const float* __restrict__ bo3, float* __restrict__ out) {
  __shared__ float pool4[4 * 64];
  __shared__ float pooled[64];
  __shared__ float o1[64];
  __shared__ float o2s[64];
  const int t = threadIdx.x;
  const int b = blockIdx.x;
  const int q = t >> 6, d = t & 63;
  const float* hb = h + (size_t)b * NN * HD;
  float m = -3.402823466e+38f;
  for (int n = q; n < NN; n += 4) m = fmaxf(m, hb[(size_t)n * HD + d]);
  pool4[q * 64 + d] = m;
  __syncthreads();
  if (t < 64) {
    pooled[t] = fmaxf(fmaxf(pool4[t], pool4[64 + t]),
                      fmaxf(pool4[128 + t], pool4[192 + t]));
  }
  __syncthreads();
  if (t < 64) {
    float a = bo1[t];
    for (int c = 0; c < 64; ++c) a = fmaf(pooled[c], Wo1[c * 64 + t], a);
    o1[t] = elu_f(a);
  }
  __syncthreads();
  if (t < 64) {
    float a = bo2[t];
    for (int c = 0; c < 64; ++c) a = fmaf(o1[c], Wo2[c * 64 + t], a);
    o2s[t] = elu_f(a);
  }
  __syncthreads();
  if (t < 64) {
    float v = o2s[t] * Wo3[t];
#pragma unroll
    for (int mm = 32; mm >= 1; mm >>= 1) v += __shfl_xor(v, mm, 64);
    if (t == 0) out[b] = v + bo3[0];
  }
}

extern "C" void kernel_launch(void* const* d_in, const int* in_sizes, int n_in,
                              void* d_out, int out_size, void* d_ws, size_t ws_size,
                              hipStream_t stream) {
  const float* x   = (const float*)d_in[0];
  const float* dn  = (const float*)d_in[1];
  const float* Win = (const float*)d_in[2];
  const float* bin = (const float*)d_in[3];
  const float* W1  = (const float*)d_in[4];
  const float* b1  = (const float*)d_in[5];
  const float* W2  = (const float*)d_in[6];
  const float* b2  = (const float*)d_in[7];
  const float* Wo1 = (const float*)d_in[8];
  const float* bo1 = (const float*)d_in[9];
  const float* Wo2 = (const float*)d_in[10];
  const float* bo2 = (const float*)d_in[11];
  const float* Wo3 = (const float*)d_in[12];
  const float* bo3 = (const float*)d_in[13];
  float* out = (float*)d_out;

  char* p = (char*)d_ws;
  const size_t hbytes = (size_t)NB * NN * HD * 4;  // 6291456
  float* h0 = (float*)p; p += hbytes;
  float* h1 = (float*)p; p += hbytes;
  float* xx = (float*)p; p += (size_t)NB * NN * 4;
  int* knn  = (int*)p;   p += (size_t)NB * NN * KK * 4;
  unsigned short* hhi = (unsigned short*)p; p += (size_t)NB * NN * HD * 2;
  unsigned short* hlo = (unsigned short*)p; p += (size_t)NB * NN * HD * 2;
  unsigned short* w1h = (unsigned short*)p; p += (size_t)NL * 8192 * 2;
  unsigned short* w1l = (unsigned short*)p; p += (size_t)NL * 8192 * 2;
  unsigned short* w2h = (unsigned short*)p; p += (size_t)NL * 8192 * 2;
  unsigned short* w2l = (unsigned short*)p; p += (size_t)NL * 8192 * 2;
  float* dotb = (float*)p;
  const size_t used = (size_t)(p - (char*)d_ws);        // ~20.6 MB
  const size_t per_batch = (size_t)NN * NN * 4;         // 37.75 MB
  int nc = 0;
  if (ws_size > used) {
    size_t cap = (ws_size - used) / per_batch;
    nc = cap > 8 ? 8 : (int)cap;
  }

  const int rows = NB * NN;
  k_embed<<<rows / 4, 256, 0, stream>>>(x, dn, Win, bin, h0);
  k_packw<<<16, 256, 0, stream>>>(W1, W2, w1h, w1l, w2h, w2l);
  float* hin = h0;
  float* hbuf = h1;
  for (int l = 0; l < NL; ++l) {
    k_norms<<<rows / 4, 256, 0, stream>>>(hin, xx);
    if (nc >= 1) {
      k_split<<<rows * HD / 8 / 256, 256, 0, stream>>>(hin, hhi, hlo);
      for (int c0 = 0; c0 < NB; c0 += nc) {
        const int ncc = (NB - c0) < nc ? (NB - c0) : nc;
        k_gram<<<ncc * 576, 256, 0, stream>>>(hhi, hlo, dotb, c0);
        k_select<<<ncc * (NN / 4), 256, 0, stream>>>(dotb, xx, knn, c0);
      }
    } else {
      k_knn<<<rows / 16, 1024, 0, stream>>>(hin, xx, knn);
    }
    k_msg2<<<rows / 4, 256, 0, stream>>>(hin, knn, W1 + (size_t)l * 128 * 128,
                                         b1 + l * 128, b2 + l * 64,
                                         w1h + (size_t)l * 8192, w1l + (size_t)l * 8192,
                                         w2h + (size_t)l * 8192, w2l + (size_t)l * 8192,
                                         hbuf);
    float* tmp = hin; hin = hbuf; hbuf = tmp;
  }
  k_head<<<NB, 256, 0, stream>>>(hin, Wo1, bo1, Wo2, bo2, Wo3, bo3, out);
}

// Round 4
// 764.282 us; speedup vs baseline: 2.7372x; 1.3016x over previous
//
#include <hip/hip_runtime.h>
#include <cstdint>

#define NB 8
#define NN 3072
#define HD 64
#define KK 16
#define NL 2

typedef unsigned long long u64;
typedef __attribute__((ext_vector_type(8))) short short8;
typedef __attribute__((ext_vector_type(4))) float f32x4;

__device__ __forceinline__ float elu_f(float x) { return x > 0.0f ? x : expm1f(x); }

__device__ __forceinline__ unsigned sortkey(float f) {
  unsigned u = __float_as_uint(f);
  unsigned m = ((unsigned)((int)u >> 31)) | 0x80000000u;
  return u ^ m;  // monotone float->uint map
}

__device__ __forceinline__ u64 shfl64(u64 v, int src) {
  int lo = __shfl((int)(unsigned)v, src, 64);
  int hi = __shfl((int)(unsigned)(v >> 32), src, 64);
  return ((u64)(unsigned)hi << 32) | (unsigned)lo;
}
__device__ __forceinline__ u64 shfl_xor64(u64 v, int mask) {
  int lo = __shfl_xor((int)(unsigned)v, mask, 64);
  int hi = __shfl_xor((int)(unsigned)(v >> 32), mask, 64);
  return ((u64)(unsigned)hi << 32) | (unsigned)lo;
}

__device__ __forceinline__ void split_bf16(float f, unsigned& hb, unsigned& lb) {
  unsigned u = __float_as_uint(f);
  hb = (u + 0x7fffu + ((u >> 16) & 1u)) >> 16;  // RNE f32->bf16
  float hif = __uint_as_float(hb << 16);
  float lo = f - hif;
  unsigned ul = __float_as_uint(lo);
  lb = (ul + 0x7fffu + ((ul >> 16) & 1u)) >> 16;
}

// ---------------- embed: h = elu(x*datanorm @ W_in + b_in) ----------------
__global__ void k_embed(const float* __restrict__ x, const float* __restrict__ dn,
                        const float* __restrict__ Win, const float* __restrict__ bin,
                        float* __restrict__ h) {
  const int t = threadIdx.x;
  const int row = blockIdx.x * 4 + (t >> 6);
  const int d = t & 63;
  const float* xr = x + (size_t)row * 3;
  float a = bin[d];
#pragma unroll
  for (int c = 0; c < 3; ++c) a = fmaf(xr[c] * dn[c], Win[c * HD + d], a);
  h[(size_t)row * HD + d] = elu_f(a);
}

// ---------------- row squared norms ----------------
__global__ void k_norms(const float* __restrict__ h, float* __restrict__ xx) {
  const int t = threadIdx.x;
  const int row = blockIdx.x * 4 + (t >> 6);
  const int lane = t & 63;
  float v = h[(size_t)row * HD + lane];
  float s = v * v;
#pragma unroll
  for (int m = 32; m >= 1; m >>= 1) s += __shfl_xor(s, m, 64);
  if (lane == 0) xx[row] = s;
}

// ---------------- split h (fp32) into bf16 hi/lo packed in MFMA fragment order ----
__global__ void k_split(const float* __restrict__ h, unsigned short* __restrict__ hhi,
                        unsigned short* __restrict__ hlo) {
  const int C = blockIdx.x * 256 + threadIdx.x;  // one 8-elem chunk per thread
  const int Rg = C >> 10;                        // 128-row block index
  const int within = C & 1023;
  const int rt16 = within >> 7;
  const int kc = (within >> 6) & 1;
  const int quad = (within >> 4) & 3;
  const int row = within & 15;
  const int r = Rg * 128 + rt16 * 16 + row;
  const int k0 = kc * 32 + quad * 8;
  const float* src = h + (size_t)r * HD + k0;
  unsigned hh[8], ll[8];
#pragma unroll
  for (int j = 0; j < 8; ++j) split_bf16(src[j], hh[j], ll[j]);
  uint4 oh, ol;
  oh.x = hh[0] | (hh[1] << 16); oh.y = hh[2] | (hh[3] << 16);
  oh.z = hh[4] | (hh[5] << 16); oh.w = hh[6] | (hh[7] << 16);
  ol.x = ll[0] | (ll[1] << 16); ol.y = ll[2] | (ll[3] << 16);
  ol.z = ll[4] | (ll[5] << 16); ol.w = ll[6] | (ll[7] << 16);
  *(uint4*)(hhi + (size_t)C * 8) = oh;
  *(uint4*)(hlo + (size_t)C * 8) = ol;
}

// ---------------- pack W1[64:128] and W2 into MFMA B-fragment order, bf16 hi/lo ----
__global__ void k_packw(const float* __restrict__ W1, const float* __restrict__ W2,
                        unsigned short* __restrict__ w1h, unsigned short* __restrict__ w1l,
                        unsigned short* __restrict__ w2h, unsigned short* __restrict__ w2l) {
  const int cid = blockIdx.x * 256 + threadIdx.x;  // 4096 chunks
  const int l = cid >> 11;
  const int r = cid & 2047;
  const int isw2 = r >> 10;
  const int c = r & 1023;
  const int lane = c & 63;
  unsigned hh[8], ll[8];
  if (!isw2) {
    const int nt = c >> 7, kc = (c >> 6) & 1;
    const int k0 = 64 + kc * 32 + (lane >> 4) * 8;
    const int n = nt * 16 + (lane & 15);
#pragma unroll
    for (int j = 0; j < 8; ++j) split_bf16(W1[(size_t)l * 16384 + (k0 + j) * 128 + n], hh[j], ll[j]);
    unsigned short* dh = w1h + ((size_t)l * 1024 + c) * 8;
    unsigned short* dl = w1l + ((size_t)l * 1024 + c) * 8;
#pragma unroll
    for (int j = 0; j < 8; ++j) { dh[j] = (unsigned short)hh[j]; dl[j] = (unsigned short)ll[j]; }
  } else {
    const int nt = c >> 8, kc = (c >> 6) & 3;
    const int k0 = kc * 32 + (lane >> 4) * 8;
    const int n = nt * 16 + (lane & 15);
#pragma unroll
    for (int j = 0; j < 8; ++j) split_bf16(W2[(size_t)l * 8192 + (k0 + j) * 64 + n], hh[j], ll[j]);
    unsigned short* dh = w2h + ((size_t)l * 1024 + c) * 8;
    unsigned short* dl = w2l + ((size_t)l * 1024 + c) * 8;
#pragma unroll
    for (int j = 0; j < 8; ++j) { dh[j] = (unsigned short)hh[j]; dl[j] = (unsigned short)ll[j]; }
  }
}

// ---------------- Gram matrix dot[b][q][c] via split-bf16 MFMA -------------------
__global__ __launch_bounds__(256, 2) void k_gram(const unsigned short* __restrict__ hhi,
                                                 const unsigned short* __restrict__ hlo,
                                                 float* __restrict__ dot, int b0) {
  __shared__ unsigned short Ah[8192], Al[8192], Bh[8192], Bl[8192];  // 64 KB
  const int t = threadIdx.x;
  const int bl = blockIdx.x / 576;
  const int rem = blockIdx.x % 576;
  const int qt = rem / 24, ct = rem % 24;
  const int bg = b0 + bl;
  {
    const uint4* sah = (const uint4*)(hhi + ((size_t)bg * 24 + qt) * 8192);
    const uint4* sal = (const uint4*)(hlo + ((size_t)bg * 24 + qt) * 8192);
    const uint4* sbh = (const uint4*)(hhi + ((size_t)bg * 24 + ct) * 8192);
    const uint4* sbl = (const uint4*)(hlo + ((size_t)bg * 24 + ct) * 8192);
    uint4* dah = (uint4*)Ah; uint4* dal = (uint4*)Al;
    uint4* dbh = (uint4*)Bh; uint4* dbl = (uint4*)Bl;
#pragma unroll
    for (int i = 0; i < 4; ++i) {
      const int idx = t + 256 * i;
      dah[idx] = sah[idx]; dal[idx] = sal[idx];
      dbh[idx] = sbh[idx]; dbl[idx] = sbl[idx];
    }
  }
  __syncthreads();
  const int w = t >> 6, ln = t & 63;
  const int wa = w >> 1, wb = w & 1;
  const int lane16 = ln & 15, quad = ln >> 4;

  short8 af[4][2][2], bf[4][2][2];
#pragma unroll
  for (int mt = 0; mt < 4; ++mt) {
#pragma unroll
    for (int kc = 0; kc < 2; ++kc) {
      const int offA = (((wa * 4 + mt) * 2 + kc) * 64 + ln) * 8;
      const int offB = (((wb * 4 + mt) * 2 + kc) * 64 + ln) * 8;
      af[mt][kc][0] = *(const short8*)&Ah[offA];
      af[mt][kc][1] = *(const short8*)&Al[offA];
      bf[mt][kc][0] = *(const short8*)&Bh[offB];
      bf[mt][kc][1] = *(const short8*)&Bl[offB];
    }
  }
  f32x4 acc[4][4];
#pragma unroll
  for (int mt = 0; mt < 4; ++mt)
#pragma unroll
    for (int nt = 0; nt < 4; ++nt) acc[mt][nt] = (f32x4){0.f, 0.f, 0.f, 0.f};
#pragma unroll
  for (int kc = 0; kc < 2; ++kc)
#pragma unroll
    for (int mt = 0; mt < 4; ++mt)
#pragma unroll
      for (int nt = 0; nt < 4; ++nt) {
        acc[mt][nt] = __builtin_amdgcn_mfma_f32_16x16x32_bf16(
            af[mt][kc][0], bf[nt][kc][0], acc[mt][nt], 0, 0, 0);
        acc[mt][nt] = __builtin_amdgcn_mfma_f32_16x16x32_bf16(
            af[mt][kc][0], bf[nt][kc][1], acc[mt][nt], 0, 0, 0);
        acc[mt][nt] = __builtin_amdgcn_mfma_f32_16x16x32_bf16(
            af[mt][kc][1], bf[nt][kc][0], acc[mt][nt], 0, 0, 0);
      }
#pragma unroll
  for (int mt = 0; mt < 4; ++mt)
#pragma unroll
    for (int nt = 0; nt < 4; ++nt) {
      const int q = qt * 128 + wa * 64 + mt * 16 + quad * 4;
      const int c = ct * 128 + wb * 64 + nt * 16 + lane16;
      float* drow = dot + ((size_t)bl * NN + q) * NN + c;
#pragma unroll
      for (int r = 0; r < 4; ++r) drow[(size_t)r * NN] = acc[mt][nt][r];
    }
}

// ---------------- top-16 selection v3: exact two-pass threshold ------------------
// 4 queries per wave (16 lanes each). Pass 1: per-lane min2 of d2' = xx[j]-2*dot.
// T = 8th-smallest of the 16 per-lane m2 (>=8 lanes give >=2 cands <= T => >=16).
// Pass 2: compact survivors (u64 key = sortkey<<32|j) to LDS. Rank-by-count, exact.
__global__ __launch_bounds__(256) void k_select(const float* __restrict__ dot,
                                                const float* __restrict__ xx,
                                                int* __restrict__ knn, int b0) {
  __shared__ u64 sbuf[16 * 128];  // 16 KB survivors
  __shared__ int scnt[16];
  const int t = threadIdx.x;
  const int w = t >> 6, lane = t & 63;
  const int g = lane >> 4, li = lane & 15;
  const int qslot = w * 4 + g;  // 0..15, private LDS region per query
  const int qi = blockIdx.x * 16 + qslot;
  const int bl = qi / NN, q = qi % NN;
  const int bg = b0 + bl;
  const float* drow = dot + ((size_t)bl * NN + q) * NN;
  const float* xxb = xx + (size_t)bg * NN;

  // pass 1: per-lane two smallest (values only, no divergence)
  float m1 = 3.402823466e+38f, m2 = 3.402823466e+38f;
  for (int it = 0; it < NN / 64; ++it) {
    const int j = it * 64 + li * 4;
    const float4 dv = *(const float4*)(drow + j);
    const float4 xv = *(const float4*)(xxb + j);
    float d[4] = {fmaf(-2.f, dv.x, xv.x), fmaf(-2.f, dv.y, xv.y),
                  fmaf(-2.f, dv.z, xv.z), fmaf(-2.f, dv.w, xv.w)};
#pragma unroll
    for (int c = 0; c < 4; ++c) {
      const float mx = fmaxf(m1, d[c]);
      m1 = fminf(m1, d[c]);
      m2 = fminf(m2, mx);
    }
  }
  // in-group bitonic sort of the 16 m2 values; T = 8th smallest
  float v = m2;
#pragma unroll
  for (int k = 2; k <= 16; k <<= 1) {
#pragma unroll
    for (int jm = k >> 1; jm >= 1; jm >>= 1) {
      const float pv = __shfl_xor(v, jm, 64);
      const bool up = ((li & k) == 0);
      const bool lower = ((li & jm) == 0);
      v = ((lower == up) ? fminf(v, pv) : fmaxf(v, pv));
    }
  }
  const float T = __shfl(v, 7, 16);

  if (li == 0) scnt[qslot] = 0;  // same-wave LDS ops are ordered

  // pass 2: compact survivors (row is L2-warm from pass 1)
  for (int it = 0; it < NN / 64; ++it) {
    const int j = it * 64 + li * 4;
    const float4 dv = *(const float4*)(drow + j);
    const float4 xv = *(const float4*)(xxb + j);
    float d[4] = {fmaf(-2.f, dv.x, xv.x), fmaf(-2.f, dv.y, xv.y),
                  fmaf(-2.f, dv.z, xv.z), fmaf(-2.f, dv.w, xv.w)};
#pragma unroll
    for (int c = 0; c < 4; ++c) {
      if (d[c] <= T) {
        const int idx = atomicAdd(&scnt[qslot], 1);
        if (idx < 128)
          sbuf[qslot * 128 + idx] = ((u64)sortkey(d[c]) << 32) | (unsigned)(j + c);
      }
    }
  }
  int cnt = scnt[qslot];
  cnt = cnt > 128 ? 128 : cnt;

  // rank-by-count: lane li owns survivors li, li+16, ... (<=8)
  u64 s[8];
  int rank[8];
#pragma unroll
  for (int i = 0; i < 8; ++i) {
    const int pos = li + i * 16;
    s[i] = (pos < cnt) ? sbuf[qslot * 128 + pos] : ~0ull;
    rank[i] = 0;
  }
  for (int c = 0; c < cnt; ++c) {
    const u64 sv = sbuf[qslot * 128 + c];  // 16-lane broadcast read
#pragma unroll
    for (int i = 0; i < 8; ++i) rank[i] += (sv < s[i]) ? 1 : 0;
  }
  int* kout = knn + ((size_t)bg * NN + q) * KK;
#pragma unroll
  for (int i = 0; i < 8; ++i) {
    if (s[i] != ~0ull && rank[i] < KK) kout[rank[i]] = (int)(unsigned)(s[i] & 0xffffffffu);
  }
}

// ---------------- fallback exact KNN (ws too small for dot buffer) ---------------
__global__ __launch_bounds__(1024, 4) void k_knn(const float* __restrict__ h,
                                                 const float* __restrict__ xx,
                                                 int* __restrict__ knn) {
  __shared__ float tile[2 * 64 * 64];
  const int t = threadIdx.x;
  const int w = t >> 6, lane = t & 63;
  const int b = blockIdx.x / (NN / 16);
  const int i = (blockIdx.x % (NN / 16)) * 16 + w;
  const float* hb = h + (size_t)b * NN * HD;
  float4 hi[16];
  {
    const float4* hrow = (const float4*)(hb + (size_t)i * HD);
#pragma unroll
    for (int g = 0; g < 16; ++g) hi[g] = hrow[g];
  }
  const float xxi = xx[b * NN + i];
  u64 key = ~0ull, kth = ~0ull;
  int maxlane = 0;
  const int lr = t >> 4, lg = t & 15;
  const int NT = NN / 64;
  {
    float4 v = *(const float4*)(hb + (size_t)lr * HD + lg * 4);
    *(float4*)&tile[lr * 64 + ((lg ^ (lr & 15)) << 2)] = v;
  }
  for (int jt = 0; jt < NT; ++jt) {
    float4 nxt;
    if (jt + 1 < NT)
      nxt = *(const float4*)(hb + (size_t)((jt + 1) * 64 + lr) * HD + lg * 4);
    __syncthreads();
    const float* tb = tile + (jt & 1) * 4096;
    const int sw = lane & 15;
    float dotv = 0.f;
#pragma unroll
    for (int g = 0; g < 16; ++g) {
      const float4 vj = *(const float4*)&tb[lane * 64 + ((g ^ sw) << 2)];
      dotv = fmaf(hi[g].x, vj.x, dotv);
      dotv = fmaf(hi[g].y, vj.y, dotv);
      dotv = fmaf(hi[g].z, vj.z, dotv);
      dotv = fmaf(hi[g].w, vj.w, dotv);
    }
    const int j = jt * 64 + lane;
    const float d2 = (xxi + xx[b * NN + j]) - 2.0f * dotv;
    const u64 ck = ((u64)sortkey(d2) << 32) | (unsigned)j;
    u64 qual = __ballot(ck < kth);
    while (qual) {
      const int sl = __builtin_ctzll(qual);
      qual &= qual - 1;
      const u64 c = shfl64(ck, sl);
      if (c < kth) {
        if (lane == maxlane) key = c;
        u64 r = key;
#pragma unroll
        for (int m = 1; m < 16; m <<= 1) {
          const u64 o = shfl_xor64(r, m);
          r = (o > r) ? o : r;
        }
        kth = shfl64(r, 0);
        maxlane = (int)__builtin_ctzll(__ballot(key == kth));
      }
    }
    if (jt + 1 < NT)
      *(float4*)&tile[((jt + 1) & 1) * 4096 + lr * 64 + ((lg ^ (lr & 15)) << 2)] = nxt;
  }
  if (lane < 16) knn[((size_t)b * NN + i) * KK + lane] = (int)(unsigned)(key & 0xffffffffu);
}

// ---------------- edge MLP via split-bf16 MFMA: 4 points (64 edges) per block ----
__global__ __launch_bounds__(256, 1) void k_msg2(
    const float* __restrict__ h, const int* __restrict__ knn,
    const float* __restrict__ W1l, const float* __restrict__ b1l,
    const float* __restrict__ b2l,
    const unsigned short* __restrict__ w1h, const unsigned short* __restrict__ w1l,
    const unsigned short* __restrict__ w2h, const unsigned short* __restrict__ w2l,
    float* __restrict__ hout) {
  __shared__ unsigned short A1h[4096], A1l[4096];  // 16 KB: [mt4][kc2][lane64][8]
  __shared__ float hloc[4 * 64];                   // 1 KB
  __shared__ float base1L[4 * 128];                // 2 KB
  __shared__ float m1c[64 * 132];                  // 33.8 KB (+4 pad per row)
  const int t = threadIdx.x;
  const int b = blockIdx.x / (NN / 4);
  const int p0 = (blockIdx.x % (NN / 4)) * 4;
  const float* hb = h + (size_t)b * NN * HD;

  if (t < 64) {
    const int p = t >> 4, c4 = t & 15;
    *(float4*)&hloc[p * 64 + c4 * 4] = *(const float4*)(hb + (size_t)(p0 + p) * HD + c4 * 4);
  }
  __syncthreads();

  {
    const int o = t & 127, ph = t >> 7;
    float a0 = b1l[o], a1 = b1l[o];
    for (int c = 0; c < 64; ++c) {
      const float wv = W1l[c * 128 + o];
      a0 = fmaf(hloc[(ph * 2 + 0) * 64 + c], wv, a0);
      a1 = fmaf(hloc[(ph * 2 + 1) * 64 + c], wv, a1);
    }
    base1L[(ph * 2 + 0) * 128 + o] = a0;
    base1L[(ph * 2 + 1) * 128 + o] = a1;
  }
  {
    const int e = t >> 2, qs = t & 3;
    const int p = e >> 4, m = e & 15;
    const int j = knn[((size_t)b * NN + p0 + p) * KK + m];
    const float* hj = hb + (size_t)j * HD + qs * 16;
    const int kc = qs >> 1;
#pragma unroll
    for (int half = 0; half < 2; ++half) {
      const int c0 = qs * 16 + half * 8;
      const int quad = (c0 >> 3) & 3;
      const float4 va = *(const float4*)(hj + half * 8);
      const float4 vb = *(const float4*)(hj + half * 8 + 4);
      const float4 ia = *(const float4*)&hloc[p * 64 + c0];
      const float4 ib = *(const float4*)&hloc[p * 64 + c0 + 4];
      float d[8] = {va.x - ia.x, va.y - ia.y, va.z - ia.z, va.w - ia.w,
                    vb.x - ib.x, vb.y - ib.y, vb.z - ib.z, vb.w - ib.w};
      unsigned hh[8], ll[8];
#pragma unroll
      for (int jj = 0; jj < 8; ++jj) split_bf16(d[jj], hh[jj], ll[jj]);
      const int off = ((p * 2 + kc) * 64 + quad * 16 + m) * 8;
      uint4 oh, ol;
      oh.x = hh[0] | (hh[1] << 16); oh.y = hh[2] | (hh[3] << 16);
      oh.z = hh[4] | (hh[5] << 16); oh.w = hh[6] | (hh[7] << 16);
      ol.x = ll[0] | (ll[1] << 16); ol.y = ll[2] | (ll[3] << 16);
      ol.z = ll[4] | (ll[5] << 16); ol.w = ll[6] | (ll[7] << 16);
      *(uint4*)&A1h[off] = oh;
      *(uint4*)&A1l[off] = ol;
    }
  }
  __syncthreads();

  const int w = t >> 6, lane = t & 63;
  const int lane16 = lane & 15, quad = lane >> 4;

  f32x4 acc1[8];
#pragma unroll
  for (int nt = 0; nt < 8; ++nt) {
    const float bv = base1L[w * 128 + nt * 16 + lane16];
    acc1[nt] = (f32x4){bv, bv, bv, bv};
  }
  short8 a1[2][2];
#pragma unroll
  for (int kc = 0; kc < 2; ++kc) {
    const int off = ((w * 2 + kc) * 64 + lane) * 8;
    a1[kc][0] = *(const short8*)&A1h[off];
    a1[kc][1] = *(const short8*)&A1l[off];
  }
#pragma unroll
  for (int kc = 0; kc < 2; ++kc)
#pragma unroll
    for (int nt = 0; nt < 8; ++nt) {
      const int off = ((nt * 2 + kc) * 64 + lane) * 8;
      const short8 bh = *(const short8*)(w1h + off);
      const short8 bl = *(const short8*)(w1l + off);
      acc1[nt] = __builtin_amdgcn_mfma_f32_16x16x32_bf16(a1[kc][0], bh, acc1[nt], 0, 0, 0);
      acc1[nt] = __builtin_amdgcn_mfma_f32_16x16x32_bf16(a1[kc][1], bh, acc1[nt], 0, 0, 0);
      acc1[nt] = __builtin_amdgcn_mfma_f32_16x16x32_bf16(a1[kc][0], bl, acc1[nt], 0, 0, 0);
    }
#pragma unroll
  for (int nt = 0; nt < 8; ++nt)
#pragma unroll
    for (int r = 0; r < 4; ++r)
      m1c[(w * 16 + quad * 4 + r) * 132 + nt * 16 + lane16] = elu_f(acc1[nt][r]);
  __syncthreads();

  f32x4 acc2[4];
#pragma unroll
  for (int nt = 0; nt < 4; ++nt) {
    const float bv = b2l[nt * 16 + lane16];
    acc2[nt] = (f32x4){bv, bv, bv, bv};
  }
  short8 a2h[4], a2l[4];
#pragma unroll
  for (int kc = 0; kc < 4; ++kc) {
    const float* src = &m1c[(w * 16 + lane16) * 132 + kc * 32 + quad * 8];
    const float4 x0 = *(const float4*)src;
    const float4 x1 = *(const float4*)(src + 4);
    const float xv[8] = {x0.x, x0.y, x0.z, x0.w, x1.x, x1.y, x1.z, x1.w};
    unsigned hh[8], ll[8];
#pragma unroll
    for (int jj = 0; jj < 8; ++jj) split_bf16(xv[jj], hh[jj], ll[jj]);
    short8 sh, sl;
#pragma unroll
    for (int jj = 0; jj < 8; ++jj) { sh[jj] = (short)hh[jj]; sl[jj] = (short)ll[jj]; }
    a2h[kc] = sh; a2l[kc] = sl;
  }
#pragma unroll
  for (int kc = 0; kc < 4; ++kc)
#pragma unroll
    for (int nt = 0; nt < 4; ++nt) {
      const int off = ((nt * 4 + kc) * 64 + lane) * 8;
      const short8 bh = *(const short8*)(w2h + off);
      const short8 bl = *(const short8*)(w2l + off);
      acc2[nt] = __builtin_amdgcn_mfma_f32_16x16x32_bf16(a2h[kc], bh, acc2[nt], 0, 0, 0);
      acc2[nt] = __builtin_amdgcn_mfma_f32_16x16x32_bf16(a2l[kc], bh, acc2[nt], 0, 0, 0);
      acc2[nt] = __builtin_amdgcn_mfma_f32_16x16x32_bf16(a2h[kc], bl, acc2[nt], 0, 0, 0);
    }
#pragma unroll
  for (int nt = 0; nt < 4; ++nt) {
    float s = elu_f(acc2[nt][0]) + elu_f(acc2[nt][1]) + elu_f(acc2[nt][2]) + elu_f(acc2[nt][3]);
    s += __shfl_xor(s, 16, 64);
    s += __shfl_xor(s, 32, 64);
    if (quad == 0) hout[((size_t)b * NN + p0 + w) * HD + nt * 16 + lane16] = s;
  }
}

// ---------------- max-pool + head MLP, one block per batch ----------------
__global__ void k_head(const float* __restrict__ h, const float* __restrict__ Wo1,
                       const float* __restrict__ bo1, const float* __restrict__ Wo2,
                       const float* __restrict__ bo2, const float* __restrict__ Wo3,
                       const float* __restrict__ bo3, float* __restrict__ out) {
  __shared__ float pool4[4 * 64];
  __shared__ float pooled[64];
  __shared__ float o1[64];
  __shared__ float o2s[64];
  const int t = threadIdx.x;
  const int b = blockIdx.x;
  const int q = t >> 6, d = t & 63;
  const float* hb = h + (size_t)b * NN * HD;
  float m = -3.402823466e+38f;
  for (int n = q; n < NN; n += 4) m = fmaxf(m, hb[(size_t)n * HD + d]);
  pool4[q * 64 + d] = m;
  __syncthreads();
  if (t < 64) {
    pooled[t] = fmaxf(fmaxf(pool4[t], pool4[64 + t]),
                      fmaxf(pool4[128 + t], pool4[192 + t]));
  }
  __syncthreads();
  if (t < 64) {
    float a = bo1[t];
    for (int c = 0; c < 64; ++c) a = fmaf(pooled[c], Wo1[c * 64 + t], a);
    o1[t] = elu_f(a);
  }
  __syncthreads();
  if (t < 64) {
    float a = bo2[t];
    for (int c = 0; c < 64; ++c) a = fmaf(o1[c], Wo2[c * 64 + t], a);
    o2s[t] = elu_f(a);
  }
  __syncthreads();
  if (t < 64) {
    float v = o2s[t] * Wo3[t];
#pragma unroll
    for (int mm = 32; mm >= 1; mm >>= 1) v += __shfl_xor(v, mm, 64);
    if (t == 0) out[b] = v + bo3[0];
  }
}

extern "C" void kernel_launch(void* const* d_in, const int* in_sizes, int n_in,
                              void* d_out, int out_size, void* d_ws, size_t ws_size,
                              hipStream_t stream) {
  const float* x   = (const float*)d_in[0];
  const float* dn  = (const float*)d_in[1];
  const float* Win = (const float*)d_in[2];
  const float* bin = (const float*)d_in[3];
  const float* W1  = (const float*)d_in[4];
  const float* b1  = (const float*)d_in[5];
  const float* W2  = (const float*)d_in[6];
  const float* b2  = (const float*)d_in[7];
  const float* Wo1 = (const float*)d_in[8];
  const float* bo1 = (const float*)d_in[9];
  const float* Wo2 = (const float*)d_in[10];
  const float* bo2 = (const float*)d_in[11];
  const float* Wo3 = (const float*)d_in[12];
  const float* bo3 = (const float*)d_in[13];
  float* out = (float*)d_out;

  char* p = (char*)d_ws;
  const size_t hbytes = (size_t)NB * NN * HD * 4;  // 6291456
  float* h0 = (float*)p; p += hbytes;
  float* h1 = (float*)p; p += hbytes;
  float* xx = (float*)p; p += (size_t)NB * NN * 4;
  int* knn  = (int*)p;   p += (size_t)NB * NN * KK * 4;
  unsigned short* hhi = (unsigned short*)p; p += (size_t)NB * NN * HD * 2;
  unsigned short* hlo = (unsigned short*)p; p += (size_t)NB * NN * HD * 2;
  unsigned short* w1h = (unsigned short*)p; p += (size_t)NL * 8192 * 2;
  unsigned short* w1l = (unsigned short*)p; p += (size_t)NL * 8192 * 2;
  unsigned short* w2h = (unsigned short*)p; p += (size_t)NL * 8192 * 2;
  unsigned short* w2l = (unsigned short*)p; p += (size_t)NL * 8192 * 2;
  float* dotb = (float*)p;
  const size_t used = (size_t)(p - (char*)d_ws);        // ~20.6 MB
  const size_t per_batch = (size_t)NN * NN * 4;         // 37.75 MB
  int nc = 0;
  if (ws_size > used) {
    size_t cap = (ws_size - used) / per_batch;
    nc = cap > 8 ? 8 : (int)cap;
  }

  const int rows = NB * NN;
  k_embed<<<rows / 4, 256, 0, stream>>>(x, dn, Win, bin, h0);
  k_packw<<<16, 256, 0, stream>>>(W1, W2, w1h, w1l, w2h, w2l);
  float* hin = h0;
  float* hbuf = h1;
  for (int l = 0; l < NL; ++l) {
    k_norms<<<rows / 4, 256, 0, stream>>>(hin, xx);
    if (nc >= 1) {
      k_split<<<rows * HD / 8 / 256, 256, 0, stream>>>(hin, hhi, hlo);
      for (int c0 = 0; c0 < NB; c0 += nc) {
        const int ncc = (NB - c0) < nc ? (NB - c0) : nc;
        k_gram<<<ncc * 576, 256, 0, stream>>>(hhi, hlo, dotb, c0);
        k_select<<<ncc * (NN / 16), 256, 0, stream>>>(dotb, xx, knn, c0);
      }
    } else {
      k_knn<<<rows / 16, 1024, 0, stream>>>(hin, xx, knn);
    }
    k_msg2<<<rows / 4, 256, 0, stream>>>(hin, knn, W1 + (size_t)l * 128 * 128,
                                         b1 + l * 128, b2 + l * 64,
                                         w1h + (size_t)l * 8192, w1l + (size_t)l * 8192,
                                         w2h + (size_t)l * 8192, w2l + (size_t)l * 8192,
                                         hbuf);
    float* tmp = hin; hin = hbuf; hbuf = tmp;
  }
  k_head<<<NB, 256, 0, stream>>>(hin, Wo1, bo1, Wo2, bo2, Wo3, bo3, out);
}

// Round 5
// 666.092 us; speedup vs baseline: 3.1407x; 1.1474x over previous
//
#include <hip/hip_runtime.h>
#include <cstdint>

#define NB 8
#define NN 3072
#define HD 64
#define KK 16
#define NL 2

typedef unsigned long long u64;
typedef __attribute__((ext_vector_type(8))) short short8;
typedef __attribute__((ext_vector_type(4))) float f32x4;

__device__ __forceinline__ float elu_f(float x) { return x > 0.0f ? x : expm1f(x); }

__device__ __forceinline__ unsigned sortkey(float f) {
  unsigned u = __float_as_uint(f);
  unsigned m = ((unsigned)((int)u >> 31)) | 0x80000000u;
  return u ^ m;  // monotone float->uint map
}

__device__ __forceinline__ u64 shfl64(u64 v, int src) {
  int lo = __shfl((int)(unsigned)v, src, 64);
  int hi = __shfl((int)(unsigned)(v >> 32), src, 64);
  return ((u64)(unsigned)hi << 32) | (unsigned)lo;
}
__device__ __forceinline__ u64 shfl_xor64(u64 v, int mask) {
  int lo = __shfl_xor((int)(unsigned)v, mask, 64);
  int hi = __shfl_xor((int)(unsigned)(v >> 32), mask, 64);
  return ((u64)(unsigned)hi << 32) | (unsigned)lo;
}

__device__ __forceinline__ void split_bf16(float f, unsigned& hb, unsigned& lb) {
  unsigned u = __float_as_uint(f);
  hb = (u + 0x7fffu + ((u >> 16) & 1u)) >> 16;  // RNE f32->bf16
  float hif = __uint_as_float(hb << 16);
  float lo = f - hif;
  unsigned ul = __float_as_uint(lo);
  lb = (ul + 0x7fffu + ((ul >> 16) & 1u)) >> 16;
}

// ---------------- embed: h = elu(x*datanorm @ W_in + b_in) ----------------
__global__ void k_embed(const float* __restrict__ x, const float* __restrict__ dn,
                        const float* __restrict__ Win, const float* __restrict__ bin,
                        float* __restrict__ h) {
  const int t = threadIdx.x;
  const int row = blockIdx.x * 4 + (t >> 6);
  const int d = t & 63;
  const float* xr = x + (size_t)row * 3;
  float a = bin[d];
#pragma unroll
  for (int c = 0; c < 3; ++c) a = fmaf(xr[c] * dn[c], Win[c * HD + d], a);
  h[(size_t)row * HD + d] = elu_f(a);
}

// ---------------- row squared norms ----------------
__global__ void k_norms(const float* __restrict__ h, float* __restrict__ xx) {
  const int t = threadIdx.x;
  const int row = blockIdx.x * 4 + (t >> 6);
  const int lane = t & 63;
  float v = h[(size_t)row * HD + lane];
  float s = v * v;
#pragma unroll
  for (int m = 32; m >= 1; m >>= 1) s += __shfl_xor(s, m, 64);
  if (lane == 0) xx[row] = s;
}

// ---------------- split h (fp32) into bf16 hi/lo packed in MFMA fragment order ----
__global__ void k_split(const float* __restrict__ h, unsigned short* __restrict__ hhi,
                        unsigned short* __restrict__ hlo) {
  const int C = blockIdx.x * 256 + threadIdx.x;  // one 8-elem chunk per thread
  const int Rg = C >> 10;                        // 128-row block index
  const int within = C & 1023;
  const int rt16 = within >> 7;
  const int kc = (within >> 6) & 1;
  const int quad = (within >> 4) & 3;
  const int row = within & 15;
  const int r = Rg * 128 + rt16 * 16 + row;
  const int k0 = kc * 32 + quad * 8;
  const float* src = h + (size_t)r * HD + k0;
  unsigned hh[8], ll[8];
#pragma unroll
  for (int j = 0; j < 8; ++j) split_bf16(src[j], hh[j], ll[j]);
  uint4 oh, ol;
  oh.x = hh[0] | (hh[1] << 16); oh.y = hh[2] | (hh[3] << 16);
  oh.z = hh[4] | (hh[5] << 16); oh.w = hh[6] | (hh[7] << 16);
  ol.x = ll[0] | (ll[1] << 16); ol.y = ll[2] | (ll[3] << 16);
  ol.z = ll[4] | (ll[5] << 16); ol.w = ll[6] | (ll[7] << 16);
  *(uint4*)(hhi + (size_t)C * 8) = oh;
  *(uint4*)(hlo + (size_t)C * 8) = ol;
}

// ---------------- pack W1[64:128] and W2 into MFMA B-fragment order, bf16 hi/lo ----
__global__ void k_packw(const float* __restrict__ W1, const float* __restrict__ W2,
                        unsigned short* __restrict__ w1h, unsigned short* __restrict__ w1l,
                        unsigned short* __restrict__ w2h, unsigned short* __restrict__ w2l) {
  const int cid = blockIdx.x * 256 + threadIdx.x;  // 4096 chunks
  const int l = cid >> 11;
  const int r = cid & 2047;
  const int isw2 = r >> 10;
  const int c = r & 1023;
  const int lane = c & 63;
  unsigned hh[8], ll[8];
  if (!isw2) {
    const int nt = c >> 7, kc = (c >> 6) & 1;
    const int k0 = 64 + kc * 32 + (lane >> 4) * 8;
    const int n = nt * 16 + (lane & 15);
#pragma unroll
    for (int j = 0; j < 8; ++j) split_bf16(W1[(size_t)l * 16384 + (k0 + j) * 128 + n], hh[j], ll[j]);
    unsigned short* dh = w1h + ((size_t)l * 1024 + c) * 8;
    unsigned short* dl = w1l + ((size_t)l * 1024 + c) * 8;
#pragma unroll
    for (int j = 0; j < 8; ++j) { dh[j] = (unsigned short)hh[j]; dl[j] = (unsigned short)ll[j]; }
  } else {
    const int nt = c >> 8, kc = (c >> 6) & 3;
    const int k0 = kc * 32 + (lane >> 4) * 8;
    const int n = nt * 16 + (lane & 15);
#pragma unroll
    for (int j = 0; j < 8; ++j) split_bf16(W2[(size_t)l * 8192 + (k0 + j) * 64 + n], hh[j], ll[j]);
    unsigned short* dh = w2h + ((size_t)l * 1024 + c) * 8;
    unsigned short* dl = w2l + ((size_t)l * 1024 + c) * 8;
#pragma unroll
    for (int j = 0; j < 8; ++j) { dh[j] = (unsigned short)hh[j]; dl[j] = (unsigned short)ll[j]; }
  }
}

// ---------------- Gram + d2' epilogue: dot[b][q][c] = xx[c] - 2*(h_q . h_c) ------
__global__ __launch_bounds__(256, 2) void k_gram(const unsigned short* __restrict__ hhi,
                                                 const unsigned short* __restrict__ hlo,
                                                 const float* __restrict__ xx,
                                                 float* __restrict__ dot, int b0) {
  __shared__ unsigned short Ah[8192], Al[8192], Bh[8192], Bl[8192];  // 64 KB
  const int t = threadIdx.x;
  const int bl = blockIdx.x / 576;
  const int rem = blockIdx.x % 576;
  const int qt = rem / 24, ct = rem % 24;
  const int bg = b0 + bl;
  {
    const uint4* sah = (const uint4*)(hhi + ((size_t)bg * 24 + qt) * 8192);
    const uint4* sal = (const uint4*)(hlo + ((size_t)bg * 24 + qt) * 8192);
    const uint4* sbh = (const uint4*)(hhi + ((size_t)bg * 24 + ct) * 8192);
    const uint4* sbl = (const uint4*)(hlo + ((size_t)bg * 24 + ct) * 8192);
    uint4* dah = (uint4*)Ah; uint4* dal = (uint4*)Al;
    uint4* dbh = (uint4*)Bh; uint4* dbl = (uint4*)Bl;
#pragma unroll
    for (int i = 0; i < 4; ++i) {
      const int idx = t + 256 * i;
      dah[idx] = sah[idx]; dal[idx] = sal[idx];
      dbh[idx] = sbh[idx]; dbl[idx] = sbl[idx];
    }
  }
  __syncthreads();
  const int w = t >> 6, ln = t & 63;
  const int wa = w >> 1, wb = w & 1;
  const int lane16 = ln & 15, quad = ln >> 4;

  short8 af[4][2][2], bf[4][2][2];
#pragma unroll
  for (int mt = 0; mt < 4; ++mt) {
#pragma unroll
    for (int kc = 0; kc < 2; ++kc) {
      const int offA = (((wa * 4 + mt) * 2 + kc) * 64 + ln) * 8;
      const int offB = (((wb * 4 + mt) * 2 + kc) * 64 + ln) * 8;
      af[mt][kc][0] = *(const short8*)&Ah[offA];
      af[mt][kc][1] = *(const short8*)&Al[offA];
      bf[mt][kc][0] = *(const short8*)&Bh[offB];
      bf[mt][kc][1] = *(const short8*)&Bl[offB];
    }
  }
  f32x4 acc[4][4];
#pragma unroll
  for (int mt = 0; mt < 4; ++mt)
#pragma unroll
    for (int nt = 0; nt < 4; ++nt) acc[mt][nt] = (f32x4){0.f, 0.f, 0.f, 0.f};
#pragma unroll
  for (int kc = 0; kc < 2; ++kc)
#pragma unroll
    for (int mt = 0; mt < 4; ++mt)
#pragma unroll
      for (int nt = 0; nt < 4; ++nt) {
        acc[mt][nt] = __builtin_amdgcn_mfma_f32_16x16x32_bf16(
            af[mt][kc][0], bf[nt][kc][0], acc[mt][nt], 0, 0, 0);
        acc[mt][nt] = __builtin_amdgcn_mfma_f32_16x16x32_bf16(
            af[mt][kc][0], bf[nt][kc][1], acc[mt][nt], 0, 0, 0);
        acc[mt][nt] = __builtin_amdgcn_mfma_f32_16x16x32_bf16(
            af[mt][kc][1], bf[nt][kc][0], acc[mt][nt], 0, 0, 0);
      }
  float xxc[4];
#pragma unroll
  for (int nt = 0; nt < 4; ++nt)
    xxc[nt] = xx[(size_t)bg * NN + ct * 128 + wb * 64 + nt * 16 + lane16];
#pragma unroll
  for (int mt = 0; mt < 4; ++mt)
#pragma unroll
    for (int nt = 0; nt < 4; ++nt) {
      const int q = qt * 128 + wa * 64 + mt * 16 + quad * 4;
      const int c = ct * 128 + wb * 64 + nt * 16 + lane16;
      float* drow = dot + ((size_t)bl * NN + q) * NN + c;
#pragma unroll
      for (int r = 0; r < 4; ++r)
        drow[(size_t)r * NN] = fmaf(-2.0f, acc[mt][nt][r], xxc[nt]);
    }
}

// ---------------- top-16 selection: exact two-pass threshold on d2' --------------
__global__ __launch_bounds__(256) void k_select(const float* __restrict__ dot,
                                                int* __restrict__ knn, int b0) {
  __shared__ u64 sbuf[16 * 128];  // 16 KB survivors
  __shared__ int scnt[16];
  const int t = threadIdx.x;
  const int w = t >> 6, lane = t & 63;
  const int g = lane >> 4, li = lane & 15;
  const int qslot = w * 4 + g;  // 0..15, private LDS region per query
  const int qi = blockIdx.x * 16 + qslot;
  const int bl = qi / NN, q = qi % NN;
  const int bg = b0 + bl;
  const float* drow = dot + ((size_t)bl * NN + q) * NN;

  // pass 1: per-lane two smallest (values only, no divergence)
  float m1 = 3.402823466e+38f, m2 = 3.402823466e+38f;
  for (int it = 0; it < NN / 64; ++it) {
    const int j = it * 64 + li * 4;
    const float4 dv = *(const float4*)(drow + j);
    const float d[4] = {dv.x, dv.y, dv.z, dv.w};
#pragma unroll
    for (int c = 0; c < 4; ++c) {
      const float mx = fmaxf(m1, d[c]);
      m1 = fminf(m1, d[c]);
      m2 = fminf(m2, mx);
    }
  }
  // in-group bitonic sort of the 16 m2 values; T = 8th smallest
  float v = m2;
#pragma unroll
  for (int k = 2; k <= 16; k <<= 1) {
#pragma unroll
    for (int jm = k >> 1; jm >= 1; jm >>= 1) {
      const float pv = __shfl_xor(v, jm, 64);
      const bool up = ((li & k) == 0);
      const bool lower = ((li & jm) == 0);
      v = ((lower == up) ? fminf(v, pv) : fmaxf(v, pv));
    }
  }
  const float T = __shfl(v, 7, 16);

  if (li == 0) scnt[qslot] = 0;  // same-wave LDS ops are ordered

  // pass 2: compact survivors (row is L2-warm from pass 1)
  for (int it = 0; it < NN / 64; ++it) {
    const int j = it * 64 + li * 4;
    const float4 dv = *(const float4*)(drow + j);
    const float d[4] = {dv.x, dv.y, dv.z, dv.w};
#pragma unroll
    for (int c = 0; c < 4; ++c) {
      if (d[c] <= T) {
        const int idx = atomicAdd(&scnt[qslot], 1);
        if (idx < 128)
          sbuf[qslot * 128 + idx] = ((u64)sortkey(d[c]) << 32) | (unsigned)(j + c);
      }
    }
  }
  int cnt = scnt[qslot];
  cnt = cnt > 128 ? 128 : cnt;

  // rank-by-count: lane li owns survivors li, li+16, ... (<=8)
  u64 s[8];
  int rank[8];
#pragma unroll
  for (int i = 0; i < 8; ++i) {
    const int pos = li + i * 16;
    s[i] = (pos < cnt) ? sbuf[qslot * 128 + pos] : ~0ull;
    rank[i] = 0;
  }
  for (int c = 0; c < cnt; ++c) {
    const u64 sv = sbuf[qslot * 128 + c];  // 16-lane broadcast read
#pragma unroll
    for (int i = 0; i < 8; ++i) rank[i] += (sv < s[i]) ? 1 : 0;
  }
  int* kout = knn + ((size_t)bg * NN + q) * KK;
#pragma unroll
  for (int i = 0; i < 8; ++i) {
    if (s[i] != ~0ull && rank[i] < KK) kout[rank[i]] = (int)(unsigned)(s[i] & 0xffffffffu);
  }
}

// ---------------- fallback exact KNN (ws too small for dot buffer) ---------------
__global__ __launch_bounds__(1024, 4) void k_knn(const float* __restrict__ h,
                                                 const float* __restrict__ xx,
                                                 int* __restrict__ knn) {
  __shared__ float tile[2 * 64 * 64];
  const int t = threadIdx.x;
  const int w = t >> 6, lane = t & 63;
  const int b = blockIdx.x / (NN / 16);
  const int i = (blockIdx.x % (NN / 16)) * 16 + w;
  const float* hb = h + (size_t)b * NN * HD;
  float4 hi[16];
  {
    const float4* hrow = (const float4*)(hb + (size_t)i * HD);
#pragma unroll
    for (int g = 0; g < 16; ++g) hi[g] = hrow[g];
  }
  const float xxi = xx[b * NN + i];
  u64 key = ~0ull, kth = ~0ull;
  int maxlane = 0;
  const int lr = t >> 4, lg = t & 15;
  const int NT = NN / 64;
  {
    float4 v = *(const float4*)(hb + (size_t)lr * HD + lg * 4);
    *(float4*)&tile[lr * 64 + ((lg ^ (lr & 15)) << 2)] = v;
  }
  for (int jt = 0; jt < NT; ++jt) {
    float4 nxt;
    if (jt + 1 < NT)
      nxt = *(const float4*)(hb + (size_t)((jt + 1) * 64 + lr) * HD + lg * 4);
    __syncthreads();
    const float* tb = tile + (jt & 1) * 4096;
    const int sw = lane & 15;
    float dotv = 0.f;
#pragma unroll
    for (int g = 0; g < 16; ++g) {
      const float4 vj = *(const float4*)&tb[lane * 64 + ((g ^ sw) << 2)];
      dotv = fmaf(hi[g].x, vj.x, dotv);
      dotv = fmaf(hi[g].y, vj.y, dotv);
      dotv = fmaf(hi[g].z, vj.z, dotv);
      dotv = fmaf(hi[g].w, vj.w, dotv);
    }
    const int j = jt * 64 + lane;
    const float d2 = (xxi + xx[b * NN + j]) - 2.0f * dotv;
    const u64 ck = ((u64)sortkey(d2) << 32) | (unsigned)j;
    u64 qual = __ballot(ck < kth);
    while (qual) {
      const int sl = __builtin_ctzll(qual);
      qual &= qual - 1;
      const u64 c = shfl64(ck, sl);
      if (c < kth) {
        if (lane == maxlane) key = c;
        u64 r = key;
#pragma unroll
        for (int m = 1; m < 16; m <<= 1) {
          const u64 o = shfl_xor64(r, m);
          r = (o > r) ? o : r;
        }
        kth = shfl64(r, 0);
        maxlane = (int)__builtin_ctzll(__ballot(key == kth));
      }
    }
    if (jt + 1 < NT)
      *(float4*)&tile[((jt + 1) & 1) * 4096 + lr * 64 + ((lg ^ (lr & 15)) << 2)] = nxt;
  }
  if (lane < 16) knn[((size_t)b * NN + i) * KK + lane] = (int)(unsigned)(key & 0xffffffffu);
}

// ---------------- edge MLP via split-bf16 MFMA: 4 points (64 edges) per block ----
__global__ __launch_bounds__(256, 1) void k_msg2(
    const float* __restrict__ h, const int* __restrict__ knn,
    const float* __restrict__ W1l, const float* __restrict__ b1l,
    const float* __restrict__ b2l,
    const unsigned short* __restrict__ w1h, const unsigned short* __restrict__ w1l,
    const unsigned short* __restrict__ w2h, const unsigned short* __restrict__ w2l,
    float* __restrict__ hout) {
  __shared__ unsigned short A1h[4096], A1l[4096];  // 16 KB: [mt4][kc2][lane64][8]
  __shared__ float hloc[4 * 64];                   // 1 KB
  __shared__ float base1L[4 * 128];                // 2 KB
  __shared__ float m1c[64 * 132];                  // 33.8 KB (+4 pad per row)
  const int t = threadIdx.x;
  const int b = blockIdx.x / (NN / 4);
  const int p0 = (blockIdx.x % (NN / 4)) * 4;
  const float* hb = h + (size_t)b * NN * HD;

  if (t < 64) {
    const int p = t >> 4, c4 = t & 15;
    *(float4*)&hloc[p * 64 + c4 * 4] = *(const float4*)(hb + (size_t)(p0 + p) * HD + c4 * 4);
  }
  __syncthreads();

  {
    const int o = t & 127, ph = t >> 7;
    float a0 = b1l[o], a1 = b1l[o];
    for (int c = 0; c < 64; ++c) {
      const float wv = W1l[c * 128 + o];
      a0 = fmaf(hloc[(ph * 2 + 0) * 64 + c], wv, a0);
      a1 = fmaf(hloc[(ph * 2 + 1) * 64 + c], wv, a1);
    }
    base1L[(ph * 2 + 0) * 128 + o] = a0;
    base1L[(ph * 2 + 1) * 128 + o] = a1;
  }
  {
    const int e = t >> 2, qs = t & 3;
    const int p = e >> 4, m = e & 15;
    const int j = knn[((size_t)b * NN + p0 + p) * KK + m];
    const float* hj = hb + (size_t)j * HD + qs * 16;
    const int kc = qs >> 1;
#pragma unroll
    for (int half = 0; half < 2; ++half) {
      const int c0 = qs * 16 + half * 8;
      const int quad = (c0 >> 3) & 3;
      const float4 va = *(const float4*)(hj + half * 8);
      const float4 vb = *(const float4*)(hj + half * 8 + 4);
      const float4 ia = *(const float4*)&hloc[p * 64 + c0];
      const float4 ib = *(const float4*)&hloc[p * 64 + c0 + 4];
      float d[8] = {va.x - ia.x, va.y - ia.y, va.z - ia.z, va.w - ia.w,
                    vb.x - ib.x, vb.y - ib.y, vb.z - ib.z, vb.w - ib.w};
      unsigned hh[8], ll[8];
#pragma unroll
      for (int jj = 0; jj < 8; ++jj) split_bf16(d[jj], hh[jj], ll[jj]);
      const int off = ((p * 2 + kc) * 64 + quad * 16 + m) * 8;
      uint4 oh, ol;
      oh.x = hh[0] | (hh[1] << 16); oh.y = hh[2] | (hh[3] << 16);
      oh.z = hh[4] | (hh[5] << 16); oh.w = hh[6] | (hh[7] << 16);
      ol.x = ll[0] | (ll[1] << 16); ol.y = ll[2] | (ll[3] << 16);
      ol.z = ll[4] | (ll[5] << 16); ol.w = ll[6] | (ll[7] << 16);
      *(uint4*)&A1h[off] = oh;
      *(uint4*)&A1l[off] = ol;
    }
  }
  __syncthreads();

  const int w = t >> 6, lane = t & 63;
  const int lane16 = lane & 15, quad = lane >> 4;

  f32x4 acc1[8];
#pragma unroll
  for (int nt = 0; nt < 8; ++nt) {
    const float bv = base1L[w * 128 + nt * 16 + lane16];
    acc1[nt] = (f32x4){bv, bv, bv, bv};
  }
  short8 a1[2][2];
#pragma unroll
  for (int kc = 0; kc < 2; ++kc) {
    const int off = ((w * 2 + kc) * 64 + lane) * 8;
    a1[kc][0] = *(const short8*)&A1h[off];
    a1[kc][1] = *(const short8*)&A1l[off];
  }
#pragma unroll
  for (int kc = 0; kc < 2; ++kc)
#pragma unroll
    for (int nt = 0; nt < 8; ++nt) {
      const int off = ((nt * 2 + kc) * 64 + lane) * 8;
      const short8 bh = *(const short8*)(w1h + off);
      const short8 bl = *(const short8*)(w1l + off);
      acc1[nt] = __builtin_amdgcn_mfma_f32_16x16x32_bf16(a1[kc][0], bh, acc1[nt], 0, 0, 0);
      acc1[nt] = __builtin_amdgcn_mfma_f32_16x16x32_bf16(a1[kc][1], bh, acc1[nt], 0, 0, 0);
      acc1[nt] = __builtin_amdgcn_mfma_f32_16x16x32_bf16(a1[kc][0], bl, acc1[nt], 0, 0, 0);
    }
#pragma unroll
  for (int nt = 0; nt < 8; ++nt)
#pragma unroll
    for (int r = 0; r < 4; ++r)
      m1c[(w * 16 + quad * 4 + r) * 132 + nt * 16 + lane16] = elu_f(acc1[nt][r]);
  __syncthreads();

  f32x4 acc2[4];
#pragma unroll
  for (int nt = 0; nt < 4; ++nt) {
    const float bv = b2l[nt * 16 + lane16];
    acc2[nt] = (f32x4){bv, bv, bv, bv};
  }
  short8 a2h[4], a2l[4];
#pragma unroll
  for (int kc = 0; kc < 4; ++kc) {
    const float* src = &m1c[(w * 16 + lane16) * 132 + kc * 32 + quad * 8];
    const float4 x0 = *(const float4*)src;
    const float4 x1 = *(const float4*)(src + 4);
    const float xv[8] = {x0.x, x0.y, x0.z, x0.w, x1.x, x1.y, x1.z, x1.w};
    unsigned hh[8], ll[8];
#pragma unroll
    for (int jj = 0; jj < 8; ++jj) split_bf16(xv[jj], hh[jj], ll[jj]);
    short8 sh, sl;
#pragma unroll
    for (int jj = 0; jj < 8; ++jj) { sh[jj] = (short)hh[jj]; sl[jj] = (short)ll[jj]; }
    a2h[kc] = sh; a2l[kc] = sl;
  }
#pragma unroll
  for (int kc = 0; kc < 4; ++kc)
#pragma unroll
    for (int nt = 0; nt < 4; ++nt) {
      const int off = ((nt * 4 + kc) * 64 + lane) * 8;
      const short8 bh = *(const short8*)(w2h + off);
      const short8 bl = *(const short8*)(w2l + off);
      acc2[nt] = __builtin_amdgcn_mfma_f32_16x16x32_bf16(a2h[kc], bh, acc2[nt], 0, 0, 0);
      acc2[nt] = __builtin_amdgcn_mfma_f32_16x16x32_bf16(a2l[kc], bh, acc2[nt], 0, 0, 0);
      acc2[nt] = __builtin_amdgcn_mfma_f32_16x16x32_bf16(a2h[kc], bl, acc2[nt], 0, 0, 0);
    }
#pragma unroll
  for (int nt = 0; nt < 4; ++nt) {
    float s = elu_f(acc2[nt][0]) + elu_f(acc2[nt][1]) + elu_f(acc2[nt][2]) + elu_f(acc2[nt][3]);
    s += __shfl_xor(s, 16, 64);
    s += __shfl_xor(s, 32, 64);
    if (quad == 0) hout[((size_t)b * NN + p0 + w) * HD + nt * 16 + lane16] = s;
  }
}

// ---------------- parallel max-pool: 24 segments of 128 rows per batch -----------
__global__ void k_pool(const float* __restrict__ h, float* __restrict__ part) {
  __shared__ float red[4][64];
  const int t = threadIdx.x;
  const int gidx = blockIdx.x;  // 0..NB*24-1
  const int b = gidx / 24, seg = gidx % 24;
  const int q = t >> 6, d = t & 63;
  const float* hb = h + ((size_t)b * NN + seg * 128) * HD;
  float m = -3.402823466e+38f;
  for (int n = q; n < 128; n += 4) m = fmaxf(m, hb[(size_t)n * HD + d]);
  red[q][d] = m;
  __syncthreads();
  if (t < 64)
    part[(size_t)gidx * HD + t] =
        fmaxf(fmaxf(red[0][t], red[1][t]), fmaxf(red[2][t], red[3][t]));
}

// ---------------- final reduce + head MLP, one block per batch ----------------
__global__ void k_head2(const float* __restrict__ part, const float* __restrict__ Wo1,
                        const float* __restrict__ bo1, const float* __restrict__ Wo2,
                        const float* __restrict__ bo2, const float* __restrict__ Wo3,
                        const float* __restrict__ bo3, float* __restrict__ out) {
  __shared__ float pooled[64];
  __shared__ float o1[64];
  __shared__ float o2s[64];
  const int t = threadIdx.x;
  const int b = blockIdx.x;
  if (t < 64) {
    float m = -3.402823466e+38f;
    for (int g = 0; g < 24; ++g) m = fmaxf(m, part[((size_t)b * 24 + g) * HD + t]);
    pooled[t] = m;
  }
  __syncthreads();
  if (t < 64) {
    float a = bo1[t];
    for (int c = 0; c < 64; ++c) a = fmaf(pooled[c], Wo1[c * 64 + t], a);
    o1[t] = elu_f(a);
  }
  __syncthreads();
  if (t < 64) {
    float a = bo2[t];
    for (int c = 0; c < 64; ++c) a = fmaf(o1[c], Wo2[c * 64 + t], a);
    o2s[t] = elu_f(a);
  }
  __syncthreads();
  if (t < 64) {
    float v = o2s[t] * Wo3[t];
#pragma unroll
    for (int mm = 32; mm >= 1; mm >>= 1) v += __shfl_xor(v, mm, 64);
    if (t == 0) out[b] = v + bo3[0];
  }
}

extern "C" void kernel_launch(void* const* d_in, const int* in_sizes, int n_in,
                              void* d_out, int out_size, void* d_ws, size_t ws_size,
                              hipStream_t stream) {
  const float* x   = (const float*)d_in[0];
  const float* dn  = (const float*)d_in[1];
  const float* Win = (const float*)d_in[2];
  const float* bin = (const float*)d_in[3];
  const float* W1  = (const float*)d_in[4];
  const float* b1  = (const float*)d_in[5];
  const float* W2  = (const float*)d_in[6];
  const float* b2  = (const float*)d_in[7];
  const float* Wo1 = (const float*)d_in[8];
  const float* bo1 = (const float*)d_in[9];
  const float* Wo2 = (const float*)d_in[10];
  const float* bo2 = (const float*)d_in[11];
  const float* Wo3 = (const float*)d_in[12];
  const float* bo3 = (const float*)d_in[13];
  float* out = (float*)d_out;

  char* p = (char*)d_ws;
  const size_t hbytes = (size_t)NB * NN * HD * 4;  // 6291456
  float* h0 = (float*)p; p += hbytes;
  float* h1 = (float*)p; p += hbytes;
  float* xx = (float*)p; p += (size_t)NB * NN * 4;
  int* knn  = (int*)p;   p += (size_t)NB * NN * KK * 4;
  unsigned short* hhi = (unsigned short*)p; p += (size_t)NB * NN * HD * 2;
  unsigned short* hlo = (unsigned short*)p; p += (size_t)NB * NN * HD * 2;
  unsigned short* w1h = (unsigned short*)p; p += (size_t)NL * 8192 * 2;
  unsigned short* w1l = (unsigned short*)p; p += (size_t)NL * 8192 * 2;
  unsigned short* w2h = (unsigned short*)p; p += (size_t)NL * 8192 * 2;
  unsigned short* w2l = (unsigned short*)p; p += (size_t)NL * 8192 * 2;
  float* part = (float*)p; p += (size_t)NB * 24 * HD * 4;
  float* dotb = (float*)p;
  const size_t used = (size_t)(p - (char*)d_ws);        // ~20.7 MB
  const size_t per_batch = (size_t)NN * NN * 4;         // 37.75 MB
  int nc = 0;
  if (ws_size > used) {
    size_t cap = (ws_size - used) / per_batch;
    nc = cap > 8 ? 8 : (int)cap;
  }

  const int rows = NB * NN;
  k_embed<<<rows / 4, 256, 0, stream>>>(x, dn, Win, bin, h0);
  k_packw<<<16, 256, 0, stream>>>(W1, W2, w1h, w1l, w2h, w2l);
  float* hin = h0;
  float* hbuf = h1;
  for (int l = 0; l < NL; ++l) {
    k_norms<<<rows / 4, 256, 0, stream>>>(hin, xx);
    if (nc >= 1) {
      k_split<<<rows * HD / 8 / 256, 256, 0, stream>>>(hin, hhi, hlo);
      for (int c0 = 0; c0 < NB; c0 += nc) {
        const int ncc = (NB - c0) < nc ? (NB - c0) : nc;
        k_gram<<<ncc * 576, 256, 0, stream>>>(hhi, hlo, xx, dotb, c0);
        k_select<<<ncc * (NN / 16), 256, 0, stream>>>(dotb, knn, c0);
      }
    } else {
      k_knn<<<rows / 16, 1024, 0, stream>>>(hin, xx, knn);
    }
    k_msg2<<<rows / 4, 256, 0, stream>>>(hin, knn, W1 + (size_t)l * 128 * 128,
                                         b1 + l * 128, b2 + l * 64,
                                         w1h + (size_t)l * 8192, w1l + (size_t)l * 8192,
                                         w2h + (size_t)l * 8192, w2l + (size_t)l * 8192,
                                         hbuf);
    float* tmp = hin; hin = hbuf; hbuf = tmp;
  }
  k_pool<<<NB * 24, 256, 0, stream>>>(hin, part);
  k_head2<<<NB, 256, 0, stream>>>(part, Wo1, bo1, Wo2, bo2, Wo3, bo3, out);
}

// Round 6
// 565.755 us; speedup vs baseline: 3.6977x; 1.1774x over previous
//
#include <hip/hip_runtime.h>
#include <cstdint>

#define NB 8
#define NN 3072
#define HD 64
#define KK 16
#define NL 2

typedef unsigned long long u64;
typedef __attribute__((ext_vector_type(8))) short short8;
typedef __attribute__((ext_vector_type(4))) float f32x4;

__device__ __forceinline__ float elu_f(float x) {
  return x > 0.0f ? x : __expf(x) - 1.0f;  // v_exp-based; abs err ~1e-7
}

__device__ __forceinline__ unsigned sortkey(float f) {
  unsigned u = __float_as_uint(f);
  unsigned m = ((unsigned)((int)u >> 31)) | 0x80000000u;
  return u ^ m;  // monotone float->uint map
}

__device__ __forceinline__ u64 shfl64(u64 v, int src) {
  int lo = __shfl((int)(unsigned)v, src, 64);
  int hi = __shfl((int)(unsigned)(v >> 32), src, 64);
  return ((u64)(unsigned)hi << 32) | (unsigned)lo;
}
__device__ __forceinline__ u64 shfl_xor64(u64 v, int mask) {
  int lo = __shfl_xor((int)(unsigned)v, mask, 64);
  int hi = __shfl_xor((int)(unsigned)(v >> 32), mask, 64);
  return ((u64)(unsigned)hi << 32) | (unsigned)lo;
}

__device__ __forceinline__ void split_bf16(float f, unsigned& hb, unsigned& lb) {
  unsigned u = __float_as_uint(f);
  hb = (u + 0x7fffu + ((u >> 16) & 1u)) >> 16;  // RNE f32->bf16
  float hif = __uint_as_float(hb << 16);
  float lo = f - hif;
  unsigned ul = __float_as_uint(lo);
  lb = (ul + 0x7fffu + ((ul >> 16) & 1u)) >> 16;
}

__device__ __forceinline__ unsigned short bf16rne(float f) {
  unsigned u = __float_as_uint(f);
  return (unsigned short)((u + 0x7fffu + ((u >> 16) & 1u)) >> 16);
}

// ---------------- embed: h = elu(x*datanorm @ W_in + b_in) ----------------
__global__ void k_embed(const float* __restrict__ x, const float* __restrict__ dn,
                        const float* __restrict__ Win, const float* __restrict__ bin,
                        float* __restrict__ h) {
  const int t = threadIdx.x;
  const int row = blockIdx.x * 4 + (t >> 6);
  const int d = t & 63;
  const float* xr = x + (size_t)row * 3;
  float a = bin[d];
#pragma unroll
  for (int c = 0; c < 3; ++c) a = fmaf(xr[c] * dn[c], Win[c * HD + d], a);
  h[(size_t)row * HD + d] = elu_f(a);
}

// ---------------- row squared norms ----------------
__global__ void k_norms(const float* __restrict__ h, float* __restrict__ xx) {
  const int t = threadIdx.x;
  const int row = blockIdx.x * 4 + (t >> 6);
  const int lane = t & 63;
  float v = h[(size_t)row * HD + lane];
  float s = v * v;
#pragma unroll
  for (int m = 32; m >= 1; m >>= 1) s += __shfl_xor(s, m, 64);
  if (lane == 0) xx[row] = s;
}

// ---------------- split h (fp32) into bf16 hi/lo packed in MFMA fragment order ----
__global__ void k_split(const float* __restrict__ h, unsigned short* __restrict__ hhi,
                        unsigned short* __restrict__ hlo) {
  const int C = blockIdx.x * 256 + threadIdx.x;  // one 8-elem chunk per thread
  const int Rg = C >> 10;                        // 128-row block index
  const int within = C & 1023;
  const int rt16 = within >> 7;
  const int kc = (within >> 6) & 1;
  const int quad = (within >> 4) & 3;
  const int row = within & 15;
  const int r = Rg * 128 + rt16 * 16 + row;
  const int k0 = kc * 32 + quad * 8;
  const float* src = h + (size_t)r * HD + k0;
  unsigned hh[8], ll[8];
#pragma unroll
  for (int j = 0; j < 8; ++j) split_bf16(src[j], hh[j], ll[j]);
  uint4 oh, ol;
  oh.x = hh[0] | (hh[1] << 16); oh.y = hh[2] | (hh[3] << 16);
  oh.z = hh[4] | (hh[5] << 16); oh.w = hh[6] | (hh[7] << 16);
  ol.x = ll[0] | (ll[1] << 16); ol.y = ll[2] | (ll[3] << 16);
  ol.z = ll[4] | (ll[5] << 16); ol.w = ll[6] | (ll[7] << 16);
  *(uint4*)(hhi + (size_t)C * 8) = oh;
  *(uint4*)(hlo + (size_t)C * 8) = ol;
}

// ---- pack weights into MFMA B-fragment order: W1[0:64] hi+lo, W1[64:128] hi, W2 hi
__global__ void k_packw(const float* __restrict__ W1, const float* __restrict__ W2,
                        unsigned short* __restrict__ w0h, unsigned short* __restrict__ w0l,
                        unsigned short* __restrict__ w1h, unsigned short* __restrict__ w2h) {
  const int cid = blockIdx.x * 256 + threadIdx.x;  // 6144 chunks
  const int l = cid / 3072;
  const int r = cid % 3072;
  const int lane = r & 63;
  if (r < 1024) {  // W1 base part (K=0..63), hi+lo
    const int c = r;
    const int nt = c >> 7, kc = (c >> 6) & 1;
    const int k0 = kc * 32 + (lane >> 4) * 8;
    const int n = nt * 16 + (lane & 15);
    unsigned hh[8], ll[8];
#pragma unroll
    for (int j = 0; j < 8; ++j) split_bf16(W1[(size_t)l * 16384 + (k0 + j) * 128 + n], hh[j], ll[j]);
    unsigned short* dh = w0h + ((size_t)l * 1024 + c) * 8;
    unsigned short* dl = w0l + ((size_t)l * 1024 + c) * 8;
#pragma unroll
    for (int j = 0; j < 8; ++j) { dh[j] = (unsigned short)hh[j]; dl[j] = (unsigned short)ll[j]; }
  } else if (r < 2048) {  // W1 diff part (K=64..127), hi only
    const int c = r - 1024;
    const int nt = c >> 7, kc = (c >> 6) & 1;
    const int k0 = 64 + kc * 32 + (lane >> 4) * 8;
    const int n = nt * 16 + (lane & 15);
    unsigned short* dh = w1h + ((size_t)l * 1024 + c) * 8;
#pragma unroll
    for (int j = 0; j < 8; ++j) dh[j] = bf16rne(W1[(size_t)l * 16384 + (k0 + j) * 128 + n]);
  } else {  // W2, hi only
    const int c = r - 2048;
    const int nt = c >> 8, kc = (c >> 6) & 3;
    const int k0 = kc * 32 + (lane >> 4) * 8;
    const int n = nt * 16 + (lane & 15);
    unsigned short* dh = w2h + ((size_t)l * 1024 + c) * 8;
#pragma unroll
    for (int j = 0; j < 8; ++j) dh[j] = bf16rne(W2[(size_t)l * 8192 + (k0 + j) * 64 + n]);
  }
}

// ---------------- Gram + d2' epilogue, coalesced stores --------------------------
__global__ __launch_bounds__(256, 2) void k_gram(const unsigned short* __restrict__ hhi,
                                                 const unsigned short* __restrict__ hlo,
                                                 const float* __restrict__ xx,
                                                 float* __restrict__ dot, int b0) {
  __shared__ __align__(16) unsigned char smem[65536];  // staging (64KB) / epilogue (33.8KB)
  unsigned short* Ah = (unsigned short*)smem;
  unsigned short* Al = Ah + 8192;
  unsigned short* Bh = Al + 8192;
  unsigned short* Bl = Bh + 8192;
  float* ep = (float*)smem;  // 64*132 floats, reused after frags are in registers
  const int t = threadIdx.x;
  const int bl = blockIdx.x / 576;
  const int rem = blockIdx.x % 576;
  const int qt = rem / 24, ct = rem % 24;
  const int bg = b0 + bl;
  {
    const uint4* sah = (const uint4*)(hhi + ((size_t)bg * 24 + qt) * 8192);
    const uint4* sal = (const uint4*)(hlo + ((size_t)bg * 24 + qt) * 8192);
    const uint4* sbh = (const uint4*)(hhi + ((size_t)bg * 24 + ct) * 8192);
    const uint4* sbl = (const uint4*)(hlo + ((size_t)bg * 24 + ct) * 8192);
    uint4* dah = (uint4*)Ah; uint4* dal = (uint4*)Al;
    uint4* dbh = (uint4*)Bh; uint4* dbl = (uint4*)Bl;
#pragma unroll
    for (int i = 0; i < 4; ++i) {
      const int idx = t + 256 * i;
      dah[idx] = sah[idx]; dal[idx] = sal[idx];
      dbh[idx] = sbh[idx]; dbl[idx] = sbl[idx];
    }
  }
  __syncthreads();
  const int w = t >> 6, ln = t & 63;
  const int wa = w >> 1, wb = w & 1;
  const int lane16 = ln & 15, quad = ln >> 4;

  short8 af[4][2][2], bf[4][2][2];
#pragma unroll
  for (int mt = 0; mt < 4; ++mt) {
#pragma unroll
    for (int kc = 0; kc < 2; ++kc) {
      const int offA = (((wa * 4 + mt) * 2 + kc) * 64 + ln) * 8;
      const int offB = (((wb * 4 + mt) * 2 + kc) * 64 + ln) * 8;
      af[mt][kc][0] = *(const short8*)&Ah[offA];
      af[mt][kc][1] = *(const short8*)&Al[offA];
      bf[mt][kc][0] = *(const short8*)&Bh[offB];
      bf[mt][kc][1] = *(const short8*)&Bl[offB];
    }
  }
  f32x4 acc[4][4];
#pragma unroll
  for (int mt = 0; mt < 4; ++mt)
#pragma unroll
    for (int nt = 0; nt < 4; ++nt) acc[mt][nt] = (f32x4){0.f, 0.f, 0.f, 0.f};
#pragma unroll
  for (int kc = 0; kc < 2; ++kc)
#pragma unroll
    for (int mt = 0; mt < 4; ++mt)
#pragma unroll
      for (int nt = 0; nt < 4; ++nt) {
        acc[mt][nt] = __builtin_amdgcn_mfma_f32_16x16x32_bf16(
            af[mt][kc][0], bf[nt][kc][0], acc[mt][nt], 0, 0, 0);
        acc[mt][nt] = __builtin_amdgcn_mfma_f32_16x16x32_bf16(
            af[mt][kc][0], bf[nt][kc][1], acc[mt][nt], 0, 0, 0);
        acc[mt][nt] = __builtin_amdgcn_mfma_f32_16x16x32_bf16(
            af[mt][kc][1], bf[nt][kc][0], acc[mt][nt], 0, 0, 0);
      }
  __syncthreads();  // staging dead; frags live in registers
  const int c4 = t & 31, rbase = t >> 5;
  const float4 xxv = *(const float4*)(xx + (size_t)bg * NN + ct * 128 + c4 * 4);
#pragma unroll
  for (int half = 0; half < 2; ++half) {
    if (wa == half) {
#pragma unroll
      for (int mt = 0; mt < 4; ++mt)
#pragma unroll
        for (int nt = 0; nt < 4; ++nt) {
          const int rloc = mt * 16 + quad * 4;
          const int cloc = wb * 64 + nt * 16 + lane16;
#pragma unroll
          for (int r = 0; r < 4; ++r) ep[(rloc + r) * 132 + cloc] = acc[mt][nt][r];
        }
    }
    __syncthreads();
#pragma unroll
    for (int rr = 0; rr < 8; ++rr) {
      const int row = rr * 8 + rbase;
      const float4 dv = *(const float4*)&ep[row * 132 + c4 * 4];
      float4 o;
      o.x = fmaf(-2.0f, dv.x, xxv.x);
      o.y = fmaf(-2.0f, dv.y, xxv.y);
      o.z = fmaf(-2.0f, dv.z, xxv.z);
      o.w = fmaf(-2.0f, dv.w, xxv.w);
      *(float4*)(dot + ((size_t)bl * NN + qt * 128 + half * 64 + row) * NN + ct * 128 + c4 * 4) = o;
    }
    __syncthreads();
  }
}

// ---------------- top-16 selection: exact two-pass threshold on d2' --------------
__global__ __launch_bounds__(256) void k_select(const float* __restrict__ dot,
                                                int* __restrict__ knn, int b0) {
  __shared__ u64 sbuf[16 * 128];  // 16 KB survivors
  __shared__ int scnt[16];
  const int t = threadIdx.x;
  const int w = t >> 6, lane = t & 63;
  const int g = lane >> 4, li = lane & 15;
  const int qslot = w * 4 + g;
  const int qi = blockIdx.x * 16 + qslot;
  const int bl = qi / NN, q = qi % NN;
  const int bg = b0 + bl;
  const float* drow = dot + ((size_t)bl * NN + q) * NN;

  float m1 = 3.402823466e+38f, m2 = 3.402823466e+38f;
  for (int it = 0; it < NN / 64; ++it) {
    const int j = it * 64 + li * 4;
    const float4 dv = *(const float4*)(drow + j);
    const float d[4] = {dv.x, dv.y, dv.z, dv.w};
#pragma unroll
    for (int c = 0; c < 4; ++c) {
      const float mx = fmaxf(m1, d[c]);
      m1 = fminf(m1, d[c]);
      m2 = fminf(m2, mx);
    }
  }
  float v = m2;
#pragma unroll
  for (int k = 2; k <= 16; k <<= 1) {
#pragma unroll
    for (int jm = k >> 1; jm >= 1; jm >>= 1) {
      const float pv = __shfl_xor(v, jm, 64);
      const bool up = ((li & k) == 0);
      const bool lower = ((li & jm) == 0);
      v = ((lower == up) ? fminf(v, pv) : fmaxf(v, pv));
    }
  }
  const float T = __shfl(v, 7, 16);

  if (li == 0) scnt[qslot] = 0;

  for (int it = 0; it < NN / 64; ++it) {
    const int j = it * 64 + li * 4;
    const float4 dv = *(const float4*)(drow + j);
    const float d[4] = {dv.x, dv.y, dv.z, dv.w};
#pragma unroll
    for (int c = 0; c < 4; ++c) {
      if (d[c] <= T) {
        const int idx = atomicAdd(&scnt[qslot], 1);
        if (idx < 128)
          sbuf[qslot * 128 + idx] = ((u64)sortkey(d[c]) << 32) | (unsigned)(j + c);
      }
    }
  }
  int cnt = scnt[qslot];
  cnt = cnt > 128 ? 128 : cnt;

  u64 s[8];
  int rank[8];
#pragma unroll
  for (int i = 0; i < 8; ++i) {
    const int pos = li + i * 16;
    s[i] = (pos < cnt) ? sbuf[qslot * 128 + pos] : ~0ull;
    rank[i] = 0;
  }
  for (int c = 0; c < cnt; ++c) {
    const u64 sv = sbuf[qslot * 128 + c];
#pragma unroll
    for (int i = 0; i < 8; ++i) rank[i] += (sv < s[i]) ? 1 : 0;
  }
  int* kout = knn + ((size_t)bg * NN + q) * KK;
#pragma unroll
  for (int i = 0; i < 8; ++i) {
    if (s[i] != ~0ull && rank[i] < KK) kout[rank[i]] = (int)(unsigned)(s[i] & 0xffffffffu);
  }
}

// ---------------- fallback exact KNN (ws too small for dot buffer) ---------------
__global__ __launch_bounds__(1024, 4) void k_knn(const float* __restrict__ h,
                                                 const float* __restrict__ xx,
                                                 int* __restrict__ knn) {
  __shared__ float tile[2 * 64 * 64];
  const int t = threadIdx.x;
  const int w = t >> 6, lane = t & 63;
  const int b = blockIdx.x / (NN / 16);
  const int i = (blockIdx.x % (NN / 16)) * 16 + w;
  const float* hb = h + (size_t)b * NN * HD;
  float4 hi[16];
  {
    const float4* hrow = (const float4*)(hb + (size_t)i * HD);
#pragma unroll
    for (int g = 0; g < 16; ++g) hi[g] = hrow[g];
  }
  const float xxi = xx[b * NN + i];
  u64 key = ~0ull, kth = ~0ull;
  int maxlane = 0;
  const int lr = t >> 4, lg = t & 15;
  const int NT = NN / 64;
  {
    float4 v = *(const float4*)(hb + (size_t)lr * HD + lg * 4);
    *(float4*)&tile[lr * 64 + ((lg ^ (lr & 15)) << 2)] = v;
  }
  for (int jt = 0; jt < NT; ++jt) {
    float4 nxt;
    if (jt + 1 < NT)
      nxt = *(const float4*)(hb + (size_t)((jt + 1) * 64 + lr) * HD + lg * 4);
    __syncthreads();
    const float* tb = tile + (jt & 1) * 4096;
    const int sw = lane & 15;
    float dotv = 0.f;
#pragma unroll
    for (int g = 0; g < 16; ++g) {
      const float4 vj = *(const float4*)&tb[lane * 64 + ((g ^ sw) << 2)];
      dotv = fmaf(hi[g].x, vj.x, dotv);
      dotv = fmaf(hi[g].y, vj.y, dotv);
      dotv = fmaf(hi[g].z, vj.z, dotv);
      dotv = fmaf(hi[g].w, vj.w, dotv);
    }
    const int j = jt * 64 + lane;
    const float d2 = (xxi + xx[b * NN + j]) - 2.0f * dotv;
    const u64 ck = ((u64)sortkey(d2) << 32) | (unsigned)j;
    u64 qual = __ballot(ck < kth);
    while (qual) {
      const int sl = __builtin_ctzll(qual);
      qual &= qual - 1;
      const u64 c = shfl64(ck, sl);
      if (c < kth) {
        if (lane == maxlane) key = c;
        u64 r = key;
#pragma unroll
        for (int m = 1; m < 16; m <<= 1) {
          const u64 o = shfl_xor64(r, m);
          r = (o > r) ? o : r;
        }
        kth = shfl64(r, 0);
        maxlane = (int)__builtin_ctzll(__ballot(key == kth));
      }
    }
    if (jt + 1 < NT)
      *(float4*)&tile[((jt + 1) & 1) * 4096 + lr * 64 + ((lg ^ (lr & 15)) << 2)] = nxt;
  }
  if (lane < 16) knn[((size_t)b * NN + i) * KK + lane] = (int)(unsigned)(key & 0xffffffffu);
}

// ---------------- base1 = h @ W1[0:64] + b1 (split-bf16 MFMA, near-fp32) ---------
__global__ __launch_bounds__(256, 2) void k_base(const unsigned short* __restrict__ hhi,
                                                 const unsigned short* __restrict__ hlo,
                                                 const unsigned short* __restrict__ w0h,
                                                 const unsigned short* __restrict__ w0l,
                                                 const float* __restrict__ b1l,
                                                 float* __restrict__ base1) {
  __shared__ unsigned short Ah[8192], Al[8192];  // 32 KB
  const int t = threadIdx.x;
  const int grp = blockIdx.x;  // 0..191: global 128-row group
  {
    const uint4* sah = (const uint4*)(hhi + (size_t)grp * 8192);
    const uint4* sal = (const uint4*)(hlo + (size_t)grp * 8192);
#pragma unroll
    for (int i = 0; i < 4; ++i) {
      ((uint4*)Ah)[t + 256 * i] = sah[t + 256 * i];
      ((uint4*)Al)[t + 256 * i] = sal[t + 256 * i];
    }
  }
  __syncthreads();
  const int w = t >> 6, lane = t & 63;
  const int lane16 = lane & 15, quad = lane >> 4;
  f32x4 acc[2][8];
#pragma unroll
  for (int mt = 0; mt < 2; ++mt)
#pragma unroll
    for (int nt = 0; nt < 8; ++nt) {
      const float bv = b1l[nt * 16 + lane16];
      acc[mt][nt] = (f32x4){bv, bv, bv, bv};
    }
#pragma unroll
  for (int kc = 0; kc < 2; ++kc)
#pragma unroll
    for (int mt = 0; mt < 2; ++mt) {
      const int offA = (((w * 2 + mt) * 2 + kc) * 64 + lane) * 8;
      const short8 ah = *(const short8*)&Ah[offA];
      const short8 al = *(const short8*)&Al[offA];
#pragma unroll
      for (int nt = 0; nt < 8; ++nt) {
        const int offB = ((nt * 2 + kc) * 64 + lane) * 8;
        const short8 bh = *(const short8*)(w0h + offB);
        const short8 bl = *(const short8*)(w0l + offB);
        acc[mt][nt] = __builtin_amdgcn_mfma_f32_16x16x32_bf16(ah, bh, acc[mt][nt], 0, 0, 0);
        acc[mt][nt] = __builtin_amdgcn_mfma_f32_16x16x32_bf16(ah, bl, acc[mt][nt], 0, 0, 0);
        acc[mt][nt] = __builtin_amdgcn_mfma_f32_16x16x32_bf16(al, bh, acc[mt][nt], 0, 0, 0);
      }
    }
#pragma unroll
  for (int mt = 0; mt < 2; ++mt)
#pragma unroll
    for (int nt = 0; nt < 8; ++nt) {
      const int row = (w * 2 + mt) * 16 + quad * 4;
      const int col = nt * 16 + lane16;
#pragma unroll
      for (int r = 0; r < 4; ++r)
        base1[((size_t)grp * 128 + row + r) * 128 + col] = acc[mt][nt][r];
    }
}

// ---------------- edge MLP, bf16 MFMA: 4 points (64 edges) per block -------------
// m1 = elu(base1[p] + bf16(x_j-x_i) @ bf16(W1[64:]));  h_out = sum_k elu(m1b@W2b + b2)
__global__ __launch_bounds__(256, 4) void k_msg3(
    const float* __restrict__ h, const int* __restrict__ knn,
    const float* __restrict__ base1, const float* __restrict__ b2l,
    const unsigned short* __restrict__ w1h, const unsigned short* __restrict__ w2h,
    float* __restrict__ hout) {
  __shared__ unsigned short A1[4096];   // 8 KB: [p4][kc2][quad4][m16][8]
  __shared__ unsigned short m1b[8192];  // 16 KB: [w4][kc4][q2_4][m16][8]
  __shared__ float hloc[256];           // 1 KB
  __shared__ float base1L[512];         // 2 KB
  const int t = threadIdx.x;
  const int b = blockIdx.x / (NN / 4);
  const int p0 = (blockIdx.x % (NN / 4)) * 4;
  const float* hb = h + (size_t)b * NN * HD;

  if (t < 64) {
    const int p = t >> 4, c4 = t & 15;
    *(float4*)&hloc[p * 64 + c4 * 4] = *(const float4*)(hb + (size_t)(p0 + p) * HD + c4 * 4);
  }
  if (t < 128)
    *(float4*)&base1L[t * 4] = *(const float4*)(base1 + ((size_t)b * NN + p0) * 128 + t * 4);
  __syncthreads();

  // gather diffs -> bf16 A-fragment order
  {
    const int e = t >> 2, qs = t & 3;
    const int p = e >> 4, m = e & 15;
    const int j = knn[((size_t)b * NN + p0 + p) * KK + m];
    const float* hj = hb + (size_t)j * HD + qs * 16;
    const int kc = qs >> 1;
#pragma unroll
    for (int half = 0; half < 2; ++half) {
      const int c0 = qs * 16 + half * 8;
      const int quad = (c0 >> 3) & 3;
      const float4 va = *(const float4*)(hj + half * 8);
      const float4 vb = *(const float4*)(hj + half * 8 + 4);
      const float4 ia = *(const float4*)&hloc[p * 64 + c0];
      const float4 ib = *(const float4*)&hloc[p * 64 + c0 + 4];
      const float d[8] = {va.x - ia.x, va.y - ia.y, va.z - ia.z, va.w - ia.w,
                          vb.x - ib.x, vb.y - ib.y, vb.z - ib.z, vb.w - ib.w};
      unsigned r8[8];
#pragma unroll
      for (int jj = 0; jj < 8; ++jj) r8[jj] = bf16rne(d[jj]);
      uint4 o;
      o.x = r8[0] | (r8[1] << 16); o.y = r8[2] | (r8[3] << 16);
      o.z = r8[4] | (r8[5] << 16); o.w = r8[6] | (r8[7] << 16);
      *(uint4*)&A1[((p * 2 + kc) * 64 + quad * 16 + m) * 8] = o;
    }
  }
  __syncthreads();

  const int w = t >> 6, lane = t & 63;
  const int lane16 = lane & 15, quad = lane >> 4;

  // GEMM1: 16 edges (point w) x 128 outs, K=64, bf16
  f32x4 acc1[8];
#pragma unroll
  for (int nt = 0; nt < 8; ++nt) {
    const float bv = base1L[w * 128 + nt * 16 + lane16];
    acc1[nt] = (f32x4){bv, bv, bv, bv};
  }
  short8 a1[2];
#pragma unroll
  for (int kc = 0; kc < 2; ++kc) a1[kc] = *(const short8*)&A1[((w * 2 + kc) * 64 + lane) * 8];
#pragma unroll
  for (int kc = 0; kc < 2; ++kc)
#pragma unroll
    for (int nt = 0; nt < 8; ++nt) {
      const short8 bh = *(const short8*)(w1h + ((nt * 2 + kc) * 64 + lane) * 8);
      acc1[nt] = __builtin_amdgcn_mfma_f32_16x16x32_bf16(a1[kc], bh, acc1[nt], 0, 0, 0);
    }
  // m1 -> elu -> bf16 -> LDS in A-fragment order for GEMM2
#pragma unroll
  for (int nt = 0; nt < 8; ++nt) {
    const int c = nt * 16 + lane16;
    const int boff = w * 2048 + (c >> 5) * 512 + ((c >> 3) & 3) * 128 + (c & 7);
#pragma unroll
    for (int r = 0; r < 4; ++r)
      m1b[boff + (quad * 4 + r) * 8] = bf16rne(elu_f(acc1[nt][r]));
  }
  __syncthreads();

  // GEMM2: 16 edges x 64 outs, K=128, bf16
  f32x4 acc2[4];
#pragma unroll
  for (int nt = 0; nt < 4; ++nt) {
    const float bv = b2l[nt * 16 + lane16];
    acc2[nt] = (f32x4){bv, bv, bv, bv};
  }
#pragma unroll
  for (int kc = 0; kc < 4; ++kc) {
    const short8 a2 = *(const short8*)&m1b[w * 2048 + kc * 512 + quad * 128 + lane16 * 8];
#pragma unroll
    for (int nt = 0; nt < 4; ++nt) {
      const short8 bh = *(const short8*)(w2h + ((nt * 4 + kc) * 64 + lane) * 8);
      acc2[nt] = __builtin_amdgcn_mfma_f32_16x16x32_bf16(a2, bh, acc2[nt], 0, 0, 0);
    }
  }
  // epilogue: elu then sum over the 16 edges of point w
#pragma unroll
  for (int nt = 0; nt < 4; ++nt) {
    float s = elu_f(acc2[nt][0]) + elu_f(acc2[nt][1]) + elu_f(acc2[nt][2]) + elu_f(acc2[nt][3]);
    s += __shfl_xor(s, 16, 64);
    s += __shfl_xor(s, 32, 64);
    if (quad == 0) hout[((size_t)b * NN + p0 + w) * HD + nt * 16 + lane16] = s;
  }
}

// ---------------- parallel max-pool: 24 segments of 128 rows per batch -----------
__global__ void k_pool(const float* __restrict__ h, float* __restrict__ part) {
  __shared__ float red[4][64];
  const int t = threadIdx.x;
  const int gidx = blockIdx.x;  // 0..NB*24-1
  const int b = gidx / 24, seg = gidx % 24;
  const int q = t >> 6, d = t & 63;
  const float* hb = h + ((size_t)b * NN + seg * 128) * HD;
  float m = -3.402823466e+38f;
  for (int n = q; n < 128; n += 4) m = fmaxf(m, hb[(size_t)n * HD + d]);
  red[q][d] = m;
  __syncthreads();
  if (t < 64)
    part[(size_t)gidx * HD + t] =
        fmaxf(fmaxf(red[0][t], red[1][t]), fmaxf(red[2][t], red[3][t]));
}

// ---------------- final reduce + head MLP, one block per batch ----------------
__global__ void k_head2(const float* __restrict__ part, const float* __restrict__ Wo1,
                        const float* __restrict__ bo1, const float* __restrict__ Wo2,
                        const float* __restrict__ bo2, const float* __restrict__ Wo3,
                        const float* __restrict__ bo3, float* __restrict__ out) {
  __shared__ float pooled[64];
  __shared__ float o1[64];
  __shared__ float o2s[64];
  const int t = threadIdx.x;
  const int b = blockIdx.x;
  if (t < 64) {
    float m = -3.402823466e+38f;
    for (int g = 0; g < 24; ++g) m = fmaxf(m, part[((size_t)b * 24 + g) * HD + t]);
    pooled[t] = m;
  }
  __syncthreads();
  if (t < 64) {
    float a = bo1[t];
    for (int c = 0; c < 64; ++c) a = fmaf(pooled[c], Wo1[c * 64 + t], a);
    o1[t] = elu_f(a);
  }
  __syncthreads();
  if (t < 64) {
    float a = bo2[t];
    for (int c = 0; c < 64; ++c) a = fmaf(o1[c], Wo2[c * 64 + t], a);
    o2s[t] = elu_f(a);
  }
  __syncthreads();
  if (t < 64) {
    float v = o2s[t] * Wo3[t];
#pragma unroll
    for (int mm = 32; mm >= 1; mm >>= 1) v += __shfl_xor(v, mm, 64);
    if (t == 0) out[b] = v + bo3[0];
  }
}

extern "C" void kernel_launch(void* const* d_in, const int* in_sizes, int n_in,
                              void* d_out, int out_size, void* d_ws, size_t ws_size,
                              hipStream_t stream) {
  const float* x   = (const float*)d_in[0];
  const float* dn  = (const float*)d_in[1];
  const float* Win = (const float*)d_in[2];
  const float* bin = (const float*)d_in[3];
  const float* W1  = (const float*)d_in[4];
  const float* b1  = (const float*)d_in[5];
  const float* W2  = (const float*)d_in[6];
  const float* b2  = (const float*)d_in[7];
  const float* Wo1 = (const float*)d_in[8];
  const float* bo1 = (const float*)d_in[9];
  const float* Wo2 = (const float*)d_in[10];
  const float* bo2 = (const float*)d_in[11];
  const float* Wo3 = (const float*)d_in[12];
  const float* bo3 = (const float*)d_in[13];
  float* out = (float*)d_out;

  char* p = (char*)d_ws;
  const size_t hbytes = (size_t)NB * NN * HD * 4;  // 6291456
  float* h0 = (float*)p; p += hbytes;
  float* h1 = (float*)p; p += hbytes;
  float* xx = (float*)p; p += (size_t)NB * NN * 4;
  int* knn  = (int*)p;   p += (size_t)NB * NN * KK * 4;
  unsigned short* hhi = (unsigned short*)p; p += (size_t)NB * NN * HD * 2;
  unsigned short* hlo = (unsigned short*)p; p += (size_t)NB * NN * HD * 2;
  unsigned short* w0h = (unsigned short*)p; p += (size_t)NL * 8192 * 2;
  unsigned short* w0l = (unsigned short*)p; p += (size_t)NL * 8192 * 2;
  unsigned short* w1h = (unsigned short*)p; p += (size_t)NL * 8192 * 2;
  unsigned short* w2h = (unsigned short*)p; p += (size_t)NL * 8192 * 2;
  float* part = (float*)p; p += (size_t)NB * 24 * HD * 4;
  float* dotb = (float*)p;                               // dot chunks
  float* base1 = dotb;                                   // union: base1 used after select
  const size_t used = (size_t)(p - (char*)d_ws);         // ~20.7 MB
  const size_t per_batch = (size_t)NN * NN * 4;          // 37.75 MB
  int nc = 0;
  if (ws_size > used) {
    size_t cap = (ws_size - used) / per_batch;
    nc = cap > 8 ? 8 : (int)cap;
  }

  const int rows = NB * NN;
  k_embed<<<rows / 4, 256, 0, stream>>>(x, dn, Win, bin, h0);
  k_packw<<<NL * 3072 / 256, 256, 0, stream>>>(W1, W2, w0h, w0l, w1h, w2h);
  float* hin = h0;
  float* hbuf = h1;
  for (int l = 0; l < NL; ++l) {
    k_norms<<<rows / 4, 256, 0, stream>>>(hin, xx);
    k_split<<<rows * HD / 8 / 256, 256, 0, stream>>>(hin, hhi, hlo);
    if (nc >= 1) {
      for (int c0 = 0; c0 < NB; c0 += nc) {
        const int ncc = (NB - c0) < nc ? (NB - c0) : nc;
        k_gram<<<ncc * 576, 256, 0, stream>>>(hhi, hlo, xx, dotb, c0);
        k_select<<<ncc * (NN / 16), 256, 0, stream>>>(dotb, knn, c0);
      }
    } else {
      k_knn<<<rows / 16, 1024, 0, stream>>>(hin, xx, knn);
    }
    // base1 aliases dotb (select is done with it)
    k_base<<<rows / 128, 256, 0, stream>>>(hhi, hlo, w0h + (size_t)l * 8192,
                                           w0l + (size_t)l * 8192, b1 + l * 128, base1);
    k_msg3<<<rows / 4, 256, 0, stream>>>(hin, knn, base1, b2 + l * 64,
                                         w1h + (size_t)l * 8192, w2h + (size_t)l * 8192,
                                         hbuf);
    float* tmp = hin; hin = hbuf; hbuf = tmp;
  }
  k_pool<<<NB * 24, 256, 0, stream>>>(hin, part);
  k_head2<<<NB, 256, 0, stream>>>(part, Wo1, bo1, Wo2, bo2, Wo3, bo3, out);
}

// Round 7
// 522.113 us; speedup vs baseline: 4.0067x; 1.0836x over previous
//
#include <hip/hip_runtime.h>
#include <cstdint>

#define NB 8
#define NN 3072
#define HD 64
#define KK 16
#define NL 2

typedef unsigned long long u64;
typedef __attribute__((ext_vector_type(8))) short short8;
typedef __attribute__((ext_vector_type(4))) float f32x4;

__device__ __forceinline__ float elu_f(float x) {
  return x > 0.0f ? x : __expf(x) - 1.0f;  // v_exp-based; abs err ~1e-7
}

__device__ __forceinline__ unsigned sortkey(float f) {
  unsigned u = __float_as_uint(f);
  unsigned m = ((unsigned)((int)u >> 31)) | 0x80000000u;
  return u ^ m;  // monotone float->uint map
}

__device__ __forceinline__ u64 shfl64(u64 v, int src) {
  int lo = __shfl((int)(unsigned)v, src, 64);
  int hi = __shfl((int)(unsigned)(v >> 32), src, 64);
  return ((u64)(unsigned)hi << 32) | (unsigned)lo;
}
__device__ __forceinline__ u64 shfl_xor64(u64 v, int mask) {
  int lo = __shfl_xor((int)(unsigned)v, mask, 64);
  int hi = __shfl_xor((int)(unsigned)(v >> 32), mask, 64);
  return ((u64)(unsigned)hi << 32) | (unsigned)lo;
}

__device__ __forceinline__ void split_bf16(float f, unsigned& hb, unsigned& lb) {
  unsigned u = __float_as_uint(f);
  hb = (u + 0x7fffu + ((u >> 16) & 1u)) >> 16;  // RNE f32->bf16
  float hif = __uint_as_float(hb << 16);
  float lo = f - hif;
  unsigned ul = __float_as_uint(lo);
  lb = (ul + 0x7fffu + ((ul >> 16) & 1u)) >> 16;
}

__device__ __forceinline__ unsigned short bf16rne(float f) {
  unsigned u = __float_as_uint(f);
  return (unsigned short)((u + 0x7fffu + ((u >> 16) & 1u)) >> 16);
}

// ---------------- embed: h = elu(x*datanorm @ W_in + b_in) ----------------
__global__ void k_embed(const float* __restrict__ x, const float* __restrict__ dn,
                        const float* __restrict__ Win, const float* __restrict__ bin,
                        float* __restrict__ h) {
  const int t = threadIdx.x;
  const int row = blockIdx.x * 4 + (t >> 6);
  const int d = t & 63;
  const float* xr = x + (size_t)row * 3;
  float a = bin[d];
#pragma unroll
  for (int c = 0; c < 3; ++c) a = fmaf(xr[c] * dn[c], Win[c * HD + d], a);
  h[(size_t)row * HD + d] = elu_f(a);
}

// ---------------- row squared norms ----------------
__global__ void k_norms(const float* __restrict__ h, float* __restrict__ xx) {
  const int t = threadIdx.x;
  const int row = blockIdx.x * 4 + (t >> 6);
  const int lane = t & 63;
  float v = h[(size_t)row * HD + lane];
  float s = v * v;
#pragma unroll
  for (int m = 32; m >= 1; m >>= 1) s += __shfl_xor(s, m, 64);
  if (lane == 0) xx[row] = s;
}

// ---------------- split h (fp32) into bf16 hi/lo packed in MFMA fragment order ----
__global__ void k_split(const float* __restrict__ h, unsigned short* __restrict__ hhi,
                        unsigned short* __restrict__ hlo) {
  const int C = blockIdx.x * 256 + threadIdx.x;  // one 8-elem chunk per thread
  const int Rg = C >> 10;                        // 128-row block index
  const int within = C & 1023;
  const int rt16 = within >> 7;
  const int kc = (within >> 6) & 1;
  const int quad = (within >> 4) & 3;
  const int row = within & 15;
  const int r = Rg * 128 + rt16 * 16 + row;
  const int k0 = kc * 32 + quad * 8;
  const float* src = h + (size_t)r * HD + k0;
  unsigned hh[8], ll[8];
#pragma unroll
  for (int j = 0; j < 8; ++j) split_bf16(src[j], hh[j], ll[j]);
  uint4 oh, ol;
  oh.x = hh[0] | (hh[1] << 16); oh.y = hh[2] | (hh[3] << 16);
  oh.z = hh[4] | (hh[5] << 16); oh.w = hh[6] | (hh[7] << 16);
  ol.x = ll[0] | (ll[1] << 16); ol.y = ll[2] | (ll[3] << 16);
  ol.z = ll[4] | (ll[5] << 16); ol.w = ll[6] | (ll[7] << 16);
  *(uint4*)(hhi + (size_t)C * 8) = oh;
  *(uint4*)(hlo + (size_t)C * 8) = ol;
}

// ---- pack weights into MFMA B-fragment order: W1[0:64] hi+lo, W1[64:128] hi, W2 hi
__global__ void k_packw(const float* __restrict__ W1, const float* __restrict__ W2,
                        unsigned short* __restrict__ w0h, unsigned short* __restrict__ w0l,
                        unsigned short* __restrict__ w1h, unsigned short* __restrict__ w2h) {
  const int cid = blockIdx.x * 256 + threadIdx.x;  // 6144 chunks
  const int l = cid / 3072;
  const int r = cid % 3072;
  const int lane = r & 63;
  if (r < 1024) {  // W1 base part (K=0..63), hi+lo
    const int c = r;
    const int nt = c >> 7, kc = (c >> 6) & 1;
    const int k0 = kc * 32 + (lane >> 4) * 8;
    const int n = nt * 16 + (lane & 15);
    unsigned hh[8], ll[8];
#pragma unroll
    for (int j = 0; j < 8; ++j) split_bf16(W1[(size_t)l * 16384 + (k0 + j) * 128 + n], hh[j], ll[j]);
    unsigned short* dh = w0h + ((size_t)l * 1024 + c) * 8;
    unsigned short* dl = w0l + ((size_t)l * 1024 + c) * 8;
#pragma unroll
    for (int j = 0; j < 8; ++j) { dh[j] = (unsigned short)hh[j]; dl[j] = (unsigned short)ll[j]; }
  } else if (r < 2048) {  // W1 diff part (K=64..127), hi only
    const int c = r - 1024;
    const int nt = c >> 7, kc = (c >> 6) & 1;
    const int k0 = 64 + kc * 32 + (lane >> 4) * 8;
    const int n = nt * 16 + (lane & 15);
    unsigned short* dh = w1h + ((size_t)l * 1024 + c) * 8;
#pragma unroll
    for (int j = 0; j < 8; ++j) dh[j] = bf16rne(W1[(size_t)l * 16384 + (k0 + j) * 128 + n]);
  } else {  // W2, hi only
    const int c = r - 2048;
    const int nt = c >> 8, kc = (c >> 6) & 3;
    const int k0 = kc * 32 + (lane >> 4) * 8;
    const int n = nt * 16 + (lane & 15);
    unsigned short* dh = w2h + ((size_t)l * 1024 + c) * 8;
#pragma unroll
    for (int j = 0; j < 8; ++j) dh[j] = bf16rne(W2[(size_t)l * 8192 + (k0 + j) * 64 + n]);
  }
}

// ---------------- Gram + d2' epilogue + per-(row, ct-block) min2 stats -----------
__global__ __launch_bounds__(256, 2) void k_gram(const unsigned short* __restrict__ hhi,
                                                 const unsigned short* __restrict__ hlo,
                                                 const float* __restrict__ xx,
                                                 float* __restrict__ dot,
                                                 float* __restrict__ bmin2, int b0) {
  __shared__ __align__(16) unsigned char smem[65536];  // staging (64KB) / epilogue (33.8KB)
  unsigned short* Ah = (unsigned short*)smem;
  unsigned short* Al = Ah + 8192;
  unsigned short* Bh = Al + 8192;
  unsigned short* Bl = Bh + 8192;
  float* ep = (float*)smem;  // 64*132 floats, reused after frags are in registers
  const int t = threadIdx.x;
  const int bl = blockIdx.x / 576;
  const int rem = blockIdx.x % 576;
  const int qt = rem / 24, ct = rem % 24;
  const int bg = b0 + bl;
  {
    const uint4* sah = (const uint4*)(hhi + ((size_t)bg * 24 + qt) * 8192);
    const uint4* sal = (const uint4*)(hlo + ((size_t)bg * 24 + qt) * 8192);
    const uint4* sbh = (const uint4*)(hhi + ((size_t)bg * 24 + ct) * 8192);
    const uint4* sbl = (const uint4*)(hlo + ((size_t)bg * 24 + ct) * 8192);
    uint4* dah = (uint4*)Ah; uint4* dal = (uint4*)Al;
    uint4* dbh = (uint4*)Bh; uint4* dbl = (uint4*)Bl;
#pragma unroll
    for (int i = 0; i < 4; ++i) {
      const int idx = t + 256 * i;
      dah[idx] = sah[idx]; dal[idx] = sal[idx];
      dbh[idx] = sbh[idx]; dbl[idx] = sbl[idx];
    }
  }
  __syncthreads();
  const int w = t >> 6, ln = t & 63;
  const int wa = w >> 1, wb = w & 1;
  const int lane16 = ln & 15, quad = ln >> 4;

  short8 af[4][2][2], bf[4][2][2];
#pragma unroll
  for (int mt = 0; mt < 4; ++mt) {
#pragma unroll
    for (int kc = 0; kc < 2; ++kc) {
      const int offA = (((wa * 4 + mt) * 2 + kc) * 64 + ln) * 8;
      const int offB = (((wb * 4 + mt) * 2 + kc) * 64 + ln) * 8;
      af[mt][kc][0] = *(const short8*)&Ah[offA];
      af[mt][kc][1] = *(const short8*)&Al[offA];
      bf[mt][kc][0] = *(const short8*)&Bh[offB];
      bf[mt][kc][1] = *(const short8*)&Bl[offB];
    }
  }
  f32x4 acc[4][4];
#pragma unroll
  for (int mt = 0; mt < 4; ++mt)
#pragma unroll
    for (int nt = 0; nt < 4; ++nt) acc[mt][nt] = (f32x4){0.f, 0.f, 0.f, 0.f};
#pragma unroll
  for (int kc = 0; kc < 2; ++kc)
#pragma unroll
    for (int mt = 0; mt < 4; ++mt)
#pragma unroll
      for (int nt = 0; nt < 4; ++nt) {
        acc[mt][nt] = __builtin_amdgcn_mfma_f32_16x16x32_bf16(
            af[mt][kc][0], bf[nt][kc][0], acc[mt][nt], 0, 0, 0);
        acc[mt][nt] = __builtin_amdgcn_mfma_f32_16x16x32_bf16(
            af[mt][kc][0], bf[nt][kc][1], acc[mt][nt], 0, 0, 0);
        acc[mt][nt] = __builtin_amdgcn_mfma_f32_16x16x32_bf16(
            af[mt][kc][1], bf[nt][kc][0], acc[mt][nt], 0, 0, 0);
      }
  __syncthreads();  // staging dead; frags live in registers
  const int c4 = t & 31, rbase = t >> 5;
  const float4 xxv = *(const float4*)(xx + (size_t)bg * NN + ct * 128 + c4 * 4);
#pragma unroll
  for (int half = 0; half < 2; ++half) {
    if (wa == half) {
#pragma unroll
      for (int mt = 0; mt < 4; ++mt)
#pragma unroll
        for (int nt = 0; nt < 4; ++nt) {
          const int rloc = mt * 16 + quad * 4;
          const int cloc = wb * 64 + nt * 16 + lane16;
#pragma unroll
          for (int r = 0; r < 4; ++r) ep[(rloc + r) * 132 + cloc] = acc[mt][nt][r];
        }
    }
    __syncthreads();
#pragma unroll
    for (int rr = 0; rr < 8; ++rr) {
      const int row = rr * 8 + rbase;
      const float4 dv = *(const float4*)&ep[row * 132 + c4 * 4];
      float4 o;
      o.x = fmaf(-2.0f, dv.x, xxv.x);
      o.y = fmaf(-2.0f, dv.y, xxv.y);
      o.z = fmaf(-2.0f, dv.z, xxv.z);
      o.w = fmaf(-2.0f, dv.w, xxv.w);
      *(float4*)(dot + ((size_t)bl * NN + qt * 128 + half * 64 + row) * NN + ct * 128 + c4 * 4) = o;
      // per-row min2 over this 128-col block (for the select threshold)
      const float lo1 = fminf(o.x, o.y), hi1 = fmaxf(o.x, o.y);
      const float lo2 = fminf(o.z, o.w), hi2 = fmaxf(o.z, o.w);
      float m1 = fminf(lo1, lo2);
      float m2 = fminf(fmaxf(lo1, lo2), fminf(hi1, hi2));
#pragma unroll
      for (int mask = 1; mask <= 16; mask <<= 1) {
        const float o1 = __shfl_xor(m1, mask, 64);
        const float o2 = __shfl_xor(m2, mask, 64);
        const float nm1 = fminf(m1, o1);
        const float nm2 = fminf(fmaxf(m1, o1), fminf(m2, o2));
        m1 = nm1; m2 = nm2;
      }
      if (c4 == 0)
        bmin2[((size_t)bl * NN + qt * 128 + half * 64 + row) * 24 + ct] = m2;
    }
    __syncthreads();
  }
}

// ---------------- top-16 selection: stats-based threshold + single-pass compact --
// T = 8th-smallest of the 24 per-col-block min2 stats => count(d<=T) >= 16, exact.
__global__ __launch_bounds__(256) void k_select(const float* __restrict__ dot,
                                                const float* __restrict__ bmin2,
                                                int* __restrict__ knn, int b0) {
  __shared__ u64 sbuf[16 * 128];  // 16 KB survivors
  __shared__ int scnt[16];
  __shared__ float tst[16][32];
  __shared__ float tsh[16];
  const int t = threadIdx.x;
  const int w = t >> 6, lane = t & 63;
  const int g = lane >> 4, li = lane & 15;
  const int qslot = w * 4 + g;
  const int qi = blockIdx.x * 16 + qslot;
  const int bl = qi / NN, q = qi % NN;
  const int bg = b0 + bl;
  const float* drow = dot + ((size_t)bl * NN + q) * NN;

  // threshold from block stats: stable-rank pick of the 8th smallest of 24
  {
    const float* bst = bmin2 + ((size_t)bl * NN + q) * 24;
    const float v0 = bst[li];
    const float v1 = (li < 8) ? bst[16 + li] : 3.402823466e+38f;
    tst[qslot][li] = v0;
    tst[qslot][16 + li] = v1;  // same-wave LDS: ordered, no barrier needed
    int r0 = 0, r1 = 0;
    for (int s = 0; s < 24; ++s) {
      const float vs = tst[qslot][s];
      r0 += (vs < v0) || (vs == v0 && s < li);
      r1 += (vs < v1) || (vs == v1 && s < 16 + li);
    }
    if (r0 == 7) tsh[qslot] = v0;
    if (r1 == 7) tsh[qslot] = v1;
    if (li == 0) scnt[qslot] = 0;
  }
  const float T = tsh[qslot];

  // single pass: compact survivors
  for (int it = 0; it < NN / 64; ++it) {
    const int j = it * 64 + li * 4;
    const float4 dv = *(const float4*)(drow + j);
    const float d[4] = {dv.x, dv.y, dv.z, dv.w};
#pragma unroll
    for (int c = 0; c < 4; ++c) {
      if (d[c] <= T) {
        const int idx = atomicAdd(&scnt[qslot], 1);
        if (idx < 128)
          sbuf[qslot * 128 + idx] = ((u64)sortkey(d[c]) << 32) | (unsigned)(j + c);
      }
    }
  }
  int cnt = scnt[qslot];
  cnt = cnt > 128 ? 128 : cnt;

  // rank-by-count: lane li owns survivors li, li+16, ... (<=8)
  u64 s[8];
  int rank[8];
#pragma unroll
  for (int i = 0; i < 8; ++i) {
    const int pos = li + i * 16;
    s[i] = (pos < cnt) ? sbuf[qslot * 128 + pos] : ~0ull;
    rank[i] = 0;
  }
  for (int c = 0; c < cnt; ++c) {
    const u64 sv = sbuf[qslot * 128 + c];
#pragma unroll
    for (int i = 0; i < 8; ++i) rank[i] += (sv < s[i]) ? 1 : 0;
  }
  int* kout = knn + ((size_t)bg * NN + q) * KK;
#pragma unroll
  for (int i = 0; i < 8; ++i) {
    if (s[i] != ~0ull && rank[i] < KK) kout[rank[i]] = (int)(unsigned)(s[i] & 0xffffffffu);
  }
}

// ---------------- fallback exact KNN (ws too small for dot buffer) ---------------
__global__ __launch_bounds__(1024, 4) void k_knn(const float* __restrict__ h,
                                                 const float* __restrict__ xx,
                                                 int* __restrict__ knn) {
  __shared__ float tile[2 * 64 * 64];
  const int t = threadIdx.x;
  const int w = t >> 6, lane = t & 63;
  const int b = blockIdx.x / (NN / 16);
  const int i = (blockIdx.x % (NN / 16)) * 16 + w;
  const float* hb = h + (size_t)b * NN * HD;
  float4 hi[16];
  {
    const float4* hrow = (const float4*)(hb + (size_t)i * HD);
#pragma unroll
    for (int g = 0; g < 16; ++g) hi[g] = hrow[g];
  }
  const float xxi = xx[b * NN + i];
  u64 key = ~0ull, kth = ~0ull;
  int maxlane = 0;
  const int lr = t >> 4, lg = t & 15;
  const int NT = NN / 64;
  {
    float4 v = *(const float4*)(hb + (size_t)lr * HD + lg * 4);
    *(float4*)&tile[lr * 64 + ((lg ^ (lr & 15)) << 2)] = v;
  }
  for (int jt = 0; jt < NT; ++jt) {
    float4 nxt;
    if (jt + 1 < NT)
      nxt = *(const float4*)(hb + (size_t)((jt + 1) * 64 + lr) * HD + lg * 4);
    __syncthreads();
    const float* tb = tile + (jt & 1) * 4096;
    const int sw = lane & 15;
    float dotv = 0.f;
#pragma unroll
    for (int g = 0; g < 16; ++g) {
      const float4 vj = *(const float4*)&tb[lane * 64 + ((g ^ sw) << 2)];
      dotv = fmaf(hi[g].x, vj.x, dotv);
      dotv = fmaf(hi[g].y, vj.y, dotv);
      dotv = fmaf(hi[g].z, vj.z, dotv);
      dotv = fmaf(hi[g].w, vj.w, dotv);
    }
    const int j = jt * 64 + lane;
    const float d2 = (xxi + xx[b * NN + j]) - 2.0f * dotv;
    const u64 ck = ((u64)sortkey(d2) << 32) | (unsigned)j;
    u64 qual = __ballot(ck < kth);
    while (qual) {
      const int sl = __builtin_ctzll(qual);
      qual &= qual - 1;
      const u64 c = shfl64(ck, sl);
      if (c < kth) {
        if (lane == maxlane) key = c;
        u64 r = key;
#pragma unroll
        for (int m = 1; m < 16; m <<= 1) {
          const u64 o = shfl_xor64(r, m);
          r = (o > r) ? o : r;
        }
        kth = shfl64(r, 0);
        maxlane = (int)__builtin_ctzll(__ballot(key == kth));
      }
    }
    if (jt + 1 < NT)
      *(float4*)&tile[((jt + 1) & 1) * 4096 + lr * 64 + ((lg ^ (lr & 15)) << 2)] = nxt;
  }
  if (lane < 16) knn[((size_t)b * NN + i) * KK + lane] = (int)(unsigned)(key & 0xffffffffu);
}

// ---------------- base1 = h @ W1[0:64] + b1 (split-bf16 MFMA, near-fp32) ---------
__global__ __launch_bounds__(256, 2) void k_base(const unsigned short* __restrict__ hhi,
                                                 const unsigned short* __restrict__ hlo,
                                                 const unsigned short* __restrict__ w0h,
                                                 const unsigned short* __restrict__ w0l,
                                                 const float* __restrict__ b1l,
                                                 float* __restrict__ base1) {
  __shared__ unsigned short Ah[8192], Al[8192];  // 32 KB
  const int t = threadIdx.x;
  const int grp = blockIdx.x;  // 0..191: global 128-row group
  {
    const uint4* sah = (const uint4*)(hhi + (size_t)grp * 8192);
    const uint4* sal = (const uint4*)(hlo + (size_t)grp * 8192);
#pragma unroll
    for (int i = 0; i < 4; ++i) {
      ((uint4*)Ah)[t + 256 * i] = sah[t + 256 * i];
      ((uint4*)Al)[t + 256 * i] = sal[t + 256 * i];
    }
  }
  __syncthreads();
  const int w = t >> 6, lane = t & 63;
  const int lane16 = lane & 15, quad = lane >> 4;
  f32x4 acc[2][8];
#pragma unroll
  for (int mt = 0; mt < 2; ++mt)
#pragma unroll
    for (int nt = 0; nt < 8; ++nt) {
      const float bv = b1l[nt * 16 + lane16];
      acc[mt][nt] = (f32x4){bv, bv, bv, bv};
    }
#pragma unroll
  for (int kc = 0; kc < 2; ++kc)
#pragma unroll
    for (int mt = 0; mt < 2; ++mt) {
      const int offA = (((w * 2 + mt) * 2 + kc) * 64 + lane) * 8;
      const short8 ah = *(const short8*)&Ah[offA];
      const short8 al = *(const short8*)&Al[offA];
#pragma unroll
      for (int nt = 0; nt < 8; ++nt) {
        const int offB = ((nt * 2 + kc) * 64 + lane) * 8;
        const short8 bh = *(const short8*)(w0h + offB);
        const short8 bl = *(const short8*)(w0l + offB);
        acc[mt][nt] = __builtin_amdgcn_mfma_f32_16x16x32_bf16(ah, bh, acc[mt][nt], 0, 0, 0);
        acc[mt][nt] = __builtin_amdgcn_mfma_f32_16x16x32_bf16(ah, bl, acc[mt][nt], 0, 0, 0);
        acc[mt][nt] = __builtin_amdgcn_mfma_f32_16x16x32_bf16(al, bh, acc[mt][nt], 0, 0, 0);
      }
    }
#pragma unroll
  for (int mt = 0; mt < 2; ++mt)
#pragma unroll
    for (int nt = 0; nt < 8; ++nt) {
      const int row = (w * 2 + mt) * 16 + quad * 4;
      const int col = nt * 16 + lane16;
#pragma unroll
      for (int r = 0; r < 4; ++r)
        base1[((size_t)grp * 128 + row + r) * 128 + col] = acc[mt][nt][r];
    }
}

// ---------------- edge MLP, bf16 MFMA: 4 points (64 edges) per block -------------
__global__ __launch_bounds__(256, 4) void k_msg3(
    const float* __restrict__ h, const int* __restrict__ knn,
    const float* __restrict__ base1, const float* __restrict__ b2l,
    const unsigned short* __restrict__ w1h, const unsigned short* __restrict__ w2h,
    float* __restrict__ hout) {
  __shared__ unsigned short A1[4096];   // 8 KB: [p4][kc2][quad4][m16][8]
  __shared__ unsigned short m1b[8192];  // 16 KB: [w4][kc4][q2_4][m16][8]
  __shared__ float hloc[256];           // 1 KB
  __shared__ float base1L[512];         // 2 KB
  const int t = threadIdx.x;
  const int b = blockIdx.x / (NN / 4);
  const int p0 = (blockIdx.x % (NN / 4)) * 4;
  const float* hb = h + (size_t)b * NN * HD;

  if (t < 64) {
    const int p = t >> 4, c4 = t & 15;
    *(float4*)&hloc[p * 64 + c4 * 4] = *(const float4*)(hb + (size_t)(p0 + p) * HD + c4 * 4);
  }
  if (t < 128)
    *(float4*)&base1L[t * 4] = *(const float4*)(base1 + ((size_t)b * NN + p0) * 128 + t * 4);
  __syncthreads();

  // gather diffs -> bf16 A-fragment order
  {
    const int e = t >> 2, qs = t & 3;
    const int p = e >> 4, m = e & 15;
    const int j = knn[((size_t)b * NN + p0 + p) * KK + m];
    const float* hj = hb + (size_t)j * HD + qs * 16;
    const int kc = qs >> 1;
#pragma unroll
    for (int half = 0; half < 2; ++half) {
      const int c0 = qs * 16 + half * 8;
      const int quad = (c0 >> 3) & 3;
      const float4 va = *(const float4*)(hj + half * 8);
      const float4 vb = *(const float4*)(hj + half * 8 + 4);
      const float4 ia = *(const float4*)&hloc[p * 64 + c0];
      const float4 ib = *(const float4*)&hloc[p * 64 + c0 + 4];
      const float d[8] = {va.x - ia.x, va.y - ia.y, va.z - ia.z, va.w - ia.w,
                          vb.x - ib.x, vb.y - ib.y, vb.z - ib.z, vb.w - ib.w};
      unsigned r8[8];
#pragma unroll
      for (int jj = 0; jj < 8; ++jj) r8[jj] = bf16rne(d[jj]);
      uint4 o;
      o.x = r8[0] | (r8[1] << 16); o.y = r8[2] | (r8[3] << 16);
      o.z = r8[4] | (r8[5] << 16); o.w = r8[6] | (r8[7] << 16);
      *(uint4*)&A1[((p * 2 + kc) * 64 + quad * 16 + m) * 8] = o;
    }
  }
  __syncthreads();

  const int w = t >> 6, lane = t & 63;
  const int lane16 = lane & 15, quad = lane >> 4;

  // GEMM1: 16 edges (point w) x 128 outs, K=64, bf16
  f32x4 acc1[8];
#pragma unroll
  for (int nt = 0; nt < 8; ++nt) {
    const float bv = base1L[w * 128 + nt * 16 + lane16];
    acc1[nt] = (f32x4){bv, bv, bv, bv};
  }
  short8 a1[2];
#pragma unroll
  for (int kc = 0; kc < 2; ++kc) a1[kc] = *(const short8*)&A1[((w * 2 + kc) * 64 + lane) * 8];
#pragma unroll
  for (int kc = 0; kc < 2; ++kc)
#pragma unroll
    for (int nt = 0; nt < 8; ++nt) {
      const short8 bh = *(const short8*)(w1h + ((nt * 2 + kc) * 64 + lane) * 8);
      acc1[nt] = __builtin_amdgcn_mfma_f32_16x16x32_bf16(a1[kc], bh, acc1[nt], 0, 0, 0);
    }
  // m1 -> elu -> bf16 -> LDS in A-fragment order for GEMM2
#pragma unroll
  for (int nt = 0; nt < 8; ++nt) {
    const int c = nt * 16 + lane16;
    const int boff = w * 2048 + (c >> 5) * 512 + ((c >> 3) & 3) * 128 + (c & 7);
#pragma unroll
    for (int r = 0; r < 4; ++r)
      m1b[boff + (quad * 4 + r) * 8] = bf16rne(elu_f(acc1[nt][r]));
  }
  __syncthreads();

  // GEMM2: 16 edges x 64 outs, K=128, bf16
  f32x4 acc2[4];
#pragma unroll
  for (int nt = 0; nt < 4; ++nt) {
    const float bv = b2l[nt * 16 + lane16];
    acc2[nt] = (f32x4){bv, bv, bv, bv};
  }
#pragma unroll
  for (int kc = 0; kc < 4; ++kc) {
    const short8 a2 = *(const short8*)&m1b[w * 2048 + kc * 512 + quad * 128 + lane16 * 8];
#pragma unroll
    for (int nt = 0; nt < 4; ++nt) {
      const short8 bh = *(const short8*)(w2h + ((nt * 4 + kc) * 64 + lane) * 8);
      acc2[nt] = __builtin_amdgcn_mfma_f32_16x16x32_bf16(a2, bh, acc2[nt], 0, 0, 0);
    }
  }
  // epilogue: elu then sum over the 16 edges of point w
#pragma unroll
  for (int nt = 0; nt < 4; ++nt) {
    float s = elu_f(acc2[nt][0]) + elu_f(acc2[nt][1]) + elu_f(acc2[nt][2]) + elu_f(acc2[nt][3]);
    s += __shfl_xor(s, 16, 64);
    s += __shfl_xor(s, 32, 64);
    if (quad == 0) hout[((size_t)b * NN + p0 + w) * HD + nt * 16 + lane16] = s;
  }
}

// ---------------- parallel max-pool: 24 segments of 128 rows per batch -----------
__global__ void k_pool(const float* __restrict__ h, float* __restrict__ part) {
  __shared__ float red[4][64];
  const int t = threadIdx.x;
  const int gidx = blockIdx.x;  // 0..NB*24-1
  const int b = gidx / 24, seg = gidx % 24;
  const int q = t >> 6, d = t & 63;
  const float* hb = h + ((size_t)b * NN + seg * 128) * HD;
  float m = -3.402823466e+38f;
  for (int n = q; n < 128; n += 4) m = fmaxf(m, hb[(size_t)n * HD + d]);
  red[q][d] = m;
  __syncthreads();
  if (t < 64)
    part[(size_t)gidx * HD + t] =
        fmaxf(fmaxf(red[0][t], red[1][t]), fmaxf(red[2][t], red[3][t]));
}

// ---------------- final reduce + head MLP, one block per batch ----------------
__global__ void k_head2(const float* __restrict__ part, const float* __restrict__ Wo1,
                        const float* __restrict__ bo1, const float* __restrict__ Wo2,
                        const float* __restrict__ bo2, const float* __restrict__ Wo3,
                        const float* __restrict__ bo3, float* __restrict__ out) {
  __shared__ float pooled[64];
  __shared__ float o1[64];
  __shared__ float o2s[64];
  const int t = threadIdx.x;
  const int b = blockIdx.x;
  if (t < 64) {
    float m = -3.402823466e+38f;
    for (int g = 0; g < 24; ++g) m = fmaxf(m, part[((size_t)b * 24 + g) * HD + t]);
    pooled[t] = m;
  }
  __syncthreads();
  if (t < 64) {
    float a = bo1[t];
    for (int c = 0; c < 64; ++c) a = fmaf(pooled[c], Wo1[c * 64 + t], a);
    o1[t] = elu_f(a);
  }
  __syncthreads();
  if (t < 64) {
    float a = bo2[t];
    for (int c = 0; c < 64; ++c) a = fmaf(o1[c], Wo2[c * 64 + t], a);
    o2s[t] = elu_f(a);
  }
  __syncthreads();
  if (t < 64) {
    float v = o2s[t] * Wo3[t];
#pragma unroll
    for (int mm = 32; mm >= 1; mm >>= 1) v += __shfl_xor(v, mm, 64);
    if (t == 0) out[b] = v + bo3[0];
  }
}

extern "C" void kernel_launch(void* const* d_in, const int* in_sizes, int n_in,
                              void* d_out, int out_size, void* d_ws, size_t ws_size,
                              hipStream_t stream) {
  const float* x   = (const float*)d_in[0];
  const float* dn  = (const float*)d_in[1];
  const float* Win = (const float*)d_in[2];
  const float* bin = (const float*)d_in[3];
  const float* W1  = (const float*)d_in[4];
  const float* b1  = (const float*)d_in[5];
  const float* W2  = (const float*)d_in[6];
  const float* b2  = (const float*)d_in[7];
  const float* Wo1 = (const float*)d_in[8];
  const float* bo1 = (const float*)d_in[9];
  const float* Wo2 = (const float*)d_in[10];
  const float* bo2 = (const float*)d_in[11];
  const float* Wo3 = (const float*)d_in[12];
  const float* bo3 = (const float*)d_in[13];
  float* out = (float*)d_out;

  char* p = (char*)d_ws;
  const size_t hbytes = (size_t)NB * NN * HD * 4;  // 6291456
  float* h0 = (float*)p; p += hbytes;
  float* h1 = (float*)p; p += hbytes;
  float* xx = (float*)p; p += (size_t)NB * NN * 4;
  int* knn  = (int*)p;   p += (size_t)NB * NN * KK * 4;
  unsigned short* hhi = (unsigned short*)p; p += (size_t)NB * NN * HD * 2;
  unsigned short* hlo = (unsigned short*)p; p += (size_t)NB * NN * HD * 2;
  unsigned short* w0h = (unsigned short*)p; p += (size_t)NL * 8192 * 2;
  unsigned short* w0l = (unsigned short*)p; p += (size_t)NL * 8192 * 2;
  unsigned short* w1h = (unsigned short*)p; p += (size_t)NL * 8192 * 2;
  unsigned short* w2h = (unsigned short*)p; p += (size_t)NL * 8192 * 2;
  float* part = (float*)p; p += (size_t)NB * 24 * HD * 4;
  float* bmin2 = (float*)p; p += (size_t)NB * NN * 24 * 4;  // 2.36 MB stats
  float* dotb = (float*)p;                               // dot chunks
  float* base1 = dotb;                                   // union: base1 used after select
  const size_t used = (size_t)(p - (char*)d_ws);         // ~23 MB
  const size_t per_batch = (size_t)NN * NN * 4;          // 37.75 MB
  int nc = 0;
  if (ws_size > used) {
    size_t cap = (ws_size - used) / per_batch;
    nc = cap > 8 ? 8 : (int)cap;
  }

  const int rows = NB * NN;
  k_embed<<<rows / 4, 256, 0, stream>>>(x, dn, Win, bin, h0);
  k_packw<<<NL * 3072 / 256, 256, 0, stream>>>(W1, W2, w0h, w0l, w1h, w2h);
  float* hin = h0;
  float* hbuf = h1;
  for (int l = 0; l < NL; ++l) {
    k_norms<<<rows / 4, 256, 0, stream>>>(hin, xx);
    k_split<<<rows * HD / 8 / 256, 256, 0, stream>>>(hin, hhi, hlo);
    if (nc >= 1) {
      for (int c0 = 0; c0 < NB; c0 += nc) {
        const int ncc = (NB - c0) < nc ? (NB - c0) : nc;
        k_gram<<<ncc * 576, 256, 0, stream>>>(hhi, hlo, xx, dotb, bmin2, c0);
        k_select<<<ncc * (NN / 16), 256, 0, stream>>>(dotb, bmin2, knn, c0);
      }
    } else {
      k_knn<<<rows / 16, 1024, 0, stream>>>(hin, xx, knn);
    }
    // base1 aliases dotb (select is done with it)
    k_base<<<rows / 128, 256, 0, stream>>>(hhi, hlo, w0h + (size_t)l * 8192,
                                           w0l + (size_t)l * 8192, b1 + l * 128, base1);
    k_msg3<<<rows / 4, 256, 0, stream>>>(hin, knn, base1, b2 + l * 64,
                                         w1h + (size_t)l * 8192, w2h + (size_t)l * 8192,
                                         hbuf);
    float* tmp = hin; hin = hbuf; hbuf = tmp;
  }
  k_pool<<<NB * 24, 256, 0, stream>>>(hin, part);
  k_head2<<<NB, 256, 0, stream>>>(part, Wo1, bo1, Wo2, bo2, Wo3, bo3, out);
}